// Round 1
// baseline (687.801 us; speedup 1.0000x reference)
//
#include <hip/hip_runtime.h>
#include <hip/hip_bf16.h>

#define NN 32768
#define GG 128
#define LL 256
#define CC 128
#define EE 524288
#define DSTATE 16

// ---------------------------------------------------------------- scatter
__global__ __launch_bounds__(256) void scatter_kernel(const int* __restrict__ ei,
    const float* __restrict__ x, float* __restrict__ agg)
{
    int t = blockIdx.x * 256 + threadIdx.x;   // E*128 threads
    int e = t >> 7;
    int c = t & 127;
    int src = ei[e];
    int dst = ei[EE + e];
    atomicAdd(&agg[(size_t)dst * CC + c], x[(size_t)src * CC + c]);
}

// ---------------------------------------------------------------- generic fp32 GEMM
// out[r][o] = sum_k A'[r][k] * W[o][k] (+bias) (relu) (+resid) ; optional bn-stats
// A' = APREP ? (1+eps)*A + A2 : A
// Block: 256 thr, tile 128 rows x 128 cols, thread tile 8x8 (cols split 4+4).
template<int K, int COLS_VALID, bool APREP, bool RELU, bool HAS_BIAS, bool HAS_RESID, bool STATS>
__global__ __launch_bounds__(256)
void gemm_kernel(const float* __restrict__ A, int lda,
                 const float* __restrict__ A2, const float* __restrict__ epsp,
                 const float* __restrict__ W,
                 const float* __restrict__ bias,
                 const float* __restrict__ resid,
                 float* __restrict__ out, int ldo,
                 float* ssum, float* ssq)
{
    __shared__ alignas(16) float At[16 * 128];
    __shared__ alignas(16) float Wt[16 * 128];
    __shared__ float sred[256];
    const int tid = threadIdx.x;
    const int R0 = blockIdx.x * 128;
    const int by = blockIdx.y;
    const int tr = tid >> 4, tc = tid & 15;
    const int r_s = tid >> 1;
    const int kq = (tid & 1) * 8;
    const float e1 = APREP ? (1.0f + epsp[0]) : 0.0f;

    float acc[8][8];
#pragma unroll
    for (int i = 0; i < 8; i++)
#pragma unroll
        for (int j = 0; j < 8; j++) acc[i][j] = 0.f;

    const int o_g = by * 128 + r_s;
    const float* wrow = W + (size_t)o_g * K;
    const float* arow = A + (size_t)(R0 + r_s) * lda;
    const float* a2row = APREP ? (A2 + (size_t)(R0 + r_s) * (size_t)CC) : nullptr;

    for (int kc = 0; kc < K; kc += 16) {
        float av[8], wv[8];
        {
            float4 t0 = *(const float4*)(arow + kc + kq);
            float4 t1 = *(const float4*)(arow + kc + kq + 4);
            av[0]=t0.x; av[1]=t0.y; av[2]=t0.z; av[3]=t0.w;
            av[4]=t1.x; av[5]=t1.y; av[6]=t1.z; av[7]=t1.w;
        }
        if (APREP) {
            float4 u0 = *(const float4*)(a2row + kc + kq);
            float4 u1 = *(const float4*)(a2row + kc + kq + 4);
            av[0]=fmaf(e1,av[0],u0.x); av[1]=fmaf(e1,av[1],u0.y);
            av[2]=fmaf(e1,av[2],u0.z); av[3]=fmaf(e1,av[3],u0.w);
            av[4]=fmaf(e1,av[4],u1.x); av[5]=fmaf(e1,av[5],u1.y);
            av[6]=fmaf(e1,av[6],u1.z); av[7]=fmaf(e1,av[7],u1.w);
        }
        if (COLS_VALID == 128 || o_g < COLS_VALID) {
            float4 w0 = *(const float4*)(wrow + kc + kq);
            float4 w1 = *(const float4*)(wrow + kc + kq + 4);
            wv[0]=w0.x; wv[1]=w0.y; wv[2]=w0.z; wv[3]=w0.w;
            wv[4]=w1.x; wv[5]=w1.y; wv[6]=w1.z; wv[7]=w1.w;
        } else {
#pragma unroll
            for (int j = 0; j < 8; j++) wv[j] = 0.f;
        }
        __syncthreads();
#pragma unroll
        for (int j = 0; j < 8; j++) {
            At[(kq + j) * 128 + r_s] = av[j];
            Wt[(kq + j) * 128 + r_s] = wv[j];
        }
        __syncthreads();
#pragma unroll
        for (int kk = 0; kk < 16; kk++) {
            const float4* At4 = (const float4*)(At + kk * 128);
            const float4* Wt4 = (const float4*)(Wt + kk * 128);
            float4 a0 = At4[tr * 2], a1 = At4[tr * 2 + 1];
            float4 b0 = Wt4[tc],     b1 = Wt4[tc + 16];
            float a[8] = {a0.x,a0.y,a0.z,a0.w,a1.x,a1.y,a1.z,a1.w};
            float b[8] = {b0.x,b0.y,b0.z,b0.w,b1.x,b1.y,b1.z,b1.w};
#pragma unroll
            for (int i = 0; i < 8; i++)
#pragma unroll
                for (int j = 0; j < 8; j++)
                    acc[i][j] = fmaf(a[i], b[j], acc[i][j]);
        }
    }

    const int c0 = by * 128 + tc * 4;
    const int c1 = c0 + 64;
    float bias0[4] = {0,0,0,0}, bias1[4] = {0,0,0,0};
    if (HAS_BIAS) {
        float4 bb0 = *(const float4*)(bias + c0);
        float4 bb1 = *(const float4*)(bias + c1);
        bias0[0]=bb0.x; bias0[1]=bb0.y; bias0[2]=bb0.z; bias0[3]=bb0.w;
        bias1[0]=bb1.x; bias1[1]=bb1.y; bias1[2]=bb1.z; bias1[3]=bb1.w;
    }
    const bool st0 = (COLS_VALID == 128) || (tc * 4 < COLS_VALID);
    const bool st1 = (COLS_VALID == 128) || (64 + tc * 4 < COLS_VALID);

#pragma unroll
    for (int i = 0; i < 8; i++) {
        int r = R0 + tr * 8 + i;
        float v[8];
#pragma unroll
        for (int j = 0; j < 8; j++) {
            v[j] = acc[i][j] + ((j < 4) ? bias0[j] : bias1[j - 4]);
            if (RELU) v[j] = fmaxf(v[j], 0.f);
        }
        if (HAS_RESID) {
            float4 rv0 = *(const float4*)(resid + (size_t)r * CC + tc * 4);
            float4 rv1 = *(const float4*)(resid + (size_t)r * CC + 64 + tc * 4);
            v[0]+=rv0.x; v[1]+=rv0.y; v[2]+=rv0.z; v[3]+=rv0.w;
            v[4]+=rv1.x; v[5]+=rv1.y; v[6]+=rv1.z; v[7]+=rv1.w;
        }
        if (st0) *(float4*)(out + (size_t)r * ldo + c0) = make_float4(v[0],v[1],v[2],v[3]);
        if (st1) *(float4*)(out + (size_t)r * ldo + c1) = make_float4(v[4],v[5],v[6],v[7]);
        if (STATS) {
#pragma unroll
            for (int j = 0; j < 8; j++) acc[i][j] = v[j];
        }
    }

    if (STATS) {
        __syncthreads();
        if (tid < 128) { sred[tid] = 0.f; sred[tid + 128] = 0.f; }
        __syncthreads();
#pragma unroll
        for (int j = 0; j < 8; j++) {
            int cl = (j < 4) ? (tc * 4 + j) : (64 + tc * 4 + (j - 4));
            float s = 0.f, q = 0.f;
#pragma unroll
            for (int i = 0; i < 8; i++) { float v = acc[i][j]; s += v; q += v * v; }
            atomicAdd(&sred[cl], s);
            atomicAdd(&sred[128 + cl], q);
        }
        __syncthreads();
        if (tid < 128) {
            atomicAdd(&ssum[tid], sred[tid]);
            atomicAdd(&ssq[tid], sred[128 + tid]);
        }
    }
}

// ---------------------------------------------------------------- depthwise causal conv + silu
__global__ __launch_bounds__(256) void conv_kernel(const float* __restrict__ xz,
    const float* __restrict__ cw, const float* __restrict__ cb, float* __restrict__ xsp)
{
    int t = blockIdx.x * 256 + threadIdx.x;   // N*128
    int n = t >> 7, c = t & 127;
    int l = n & (LL - 1);
    float4 w = *(const float4*)(cw + c * 4);
    float v = cb[c];
    v = fmaf(xz[(size_t)n * 256 + c], w.w, v);
    if (l >= 1) v = fmaf(xz[(size_t)(n - 1) * 256 + c], w.z, v);
    if (l >= 2) v = fmaf(xz[(size_t)(n - 2) * 256 + c], w.y, v);
    if (l >= 3) v = fmaf(xz[(size_t)(n - 3) * 256 + c], w.x, v);
    xsp[t] = v / (1.f + __expf(-v));
}

// ---------------------------------------------------------------- dt = softplus(dtr @ dtw^T + b)
__global__ __launch_bounds__(256) void dt_kernel(const float* __restrict__ xdbl,
    const float* __restrict__ dtw, const float* __restrict__ dtb, float* __restrict__ dt)
{
    __shared__ float wT[8 * 128];
    __shared__ float rbuf[16];
    int tid = threadIdx.x;
    for (int i = tid; i < 1024; i += 256) {
        int d = i >> 3, r = i & 7;
        wT[r * 128 + d] = dtw[i];
    }
    int n0 = blockIdx.x * 2;
    if (tid < 16) rbuf[tid] = xdbl[(size_t)(n0 + (tid >> 3)) * 48 + (tid & 7)];
    __syncthreads();
    int rr = tid >> 7, d = tid & 127;
    float acc = dtb[d];
#pragma unroll
    for (int r = 0; r < 8; r++) acc = fmaf(rbuf[rr * 8 + r], wT[r * 128 + d], acc);
    float sp = (acc > 20.f) ? acc : log1pf(__expf(acc));
    dt[(size_t)(n0 + rr) * 128 + d] = sp;
}

// ---------------------------------------------------------------- selective scan + gating
// grid: 256 blocks (g = b/2, ch = b&1); block 256 thr: c_local = tid/4, sp = tid&3
__global__ __launch_bounds__(256) void scan_kernel(const float* __restrict__ xdbl,
    const float* __restrict__ dt, const float* __restrict__ xsp,
    const float* __restrict__ xz, const float* __restrict__ Alog,
    const float* __restrict__ Dp, float* __restrict__ y2)
{
    __shared__ float BC[256 * 32];
    int g = blockIdx.x >> 1, ch = blockIdx.x & 1;
    int tid = threadIdx.x;
    for (int i = tid; i < 8192; i += 256)
        BC[i] = xdbl[(size_t)(g * 256 + (i >> 5)) * 48 + 8 + (i & 31)];
    int cl = tid >> 2, sp = tid & 3;
    int c = ch * 64 + cl;
    float ae[4];
#pragma unroll
    for (int j = 0; j < 4; j++) ae[j] = -__expf(Alog[c * 16 + sp * 4 + j]);
    float dpc = Dp[c];
    float h0 = 0, h1 = 0, h2 = 0, h3 = 0;
    __syncthreads();
    const float* dtg = dt  + (size_t)g * 256 * 128 + c;
    const float* xg  = xsp + (size_t)g * 256 * 128 + c;
    const float* zg  = xz  + (size_t)g * 256 * 256 + 128 + c;
    float* yg = y2 + (size_t)g * 256 * 128 + c;
    for (int t = 0; t < 256; t++) {
        float dtv = dtg[t * 128];
        float xv  = xg[t * 128];
        float zv  = zg[t * 256];
        float u = dtv * xv;
        const float* bc = BC + t * 32 + sp * 4;
        h0 = fmaf(__expf(dtv * ae[0]), h0, u * bc[0]);
        h1 = fmaf(__expf(dtv * ae[1]), h1, u * bc[1]);
        h2 = fmaf(__expf(dtv * ae[2]), h2, u * bc[2]);
        h3 = fmaf(__expf(dtv * ae[3]), h3, u * bc[3]);
        float y = h0 * bc[16] + h1 * bc[17] + h2 * bc[18] + h3 * bc[19];
        y += __shfl_xor(y, 1);
        y += __shfl_xor(y, 2);
        if (sp == 0) {
            float yo = fmaf(dpc, xv, y);
            yg[t * 128] = yo * (zv / (1.f + __expf(-zv)));
        }
    }
}

// ---------------------------------------------------------------- norm (h1,h2) + combine
__global__ __launch_bounds__(256) void norm12_kernel(const float* p1,
    const float* p2, const float* stats,
    const float* g1, const float* be1, const float* g2, const float* be2,
    float* h2out, float* out12)
{
    __shared__ float sc[512];
    int tid = threadIdx.x;
    if (tid < 128) {
        int c = tid;
        const float inv = 1.0f / NN;
        float m1 = stats[c] * inv;
        float v1 = fmaxf(stats[128 + c] * inv - m1 * m1, 0.f);
        float i1 = rsqrtf(v1 + 1e-5f);
        sc[c] = g1[c] * i1; sc[128 + c] = be1[c] - m1 * g1[c] * i1;
        float m2 = stats[256 + c] * inv;
        float v2 = fmaxf(stats[384 + c] * inv - m2 * m2, 0.f);
        float i2 = rsqrtf(v2 + 1e-5f);
        sc[256 + c] = g2[c] * i2; sc[384 + c] = be2[c] - m2 * g2[c] * i2;
    }
    __syncthreads();
    int c = tid & 127;
    float s1 = sc[c], t1 = sc[128 + c], s2 = sc[256 + c], t2 = sc[384 + c];
    for (int i = tid; i < 4096; i += 256) {
        size_t idx = (size_t)blockIdx.x * 4096 + i;
        float a = fmaf(p1[idx], s1, t1);
        float b = fmaf(p2[idx], s2, t2);
        h2out[idx] = b;
        out12[idx] = a + b;
    }
}

// ---------------------------------------------------------------- final norm
__global__ __launch_bounds__(256) void norm3_kernel(const float* p3,
    const float* stats, const float* g3, const float* be3, float* outp)
{
    __shared__ float sc[256];
    int tid = threadIdx.x;
    if (tid < 128) {
        int c = tid;
        const float inv = 1.0f / NN;
        float m = stats[512 + c] * inv;
        float v = fmaxf(stats[640 + c] * inv - m * m, 0.f);
        float iv = rsqrtf(v + 1e-5f);
        sc[c] = g3[c] * iv; sc[128 + c] = be3[c] - m * g3[c] * iv;
    }
    __syncthreads();
    int c = tid & 127;
    float s = sc[c], t = sc[128 + c];
    for (int i = tid; i < 4096; i += 256) {
        size_t idx = (size_t)blockIdx.x * 4096 + i;
        outp[idx] = fmaf(p3[idx], s, t);
    }
}

extern "C" void kernel_launch(void* const* d_in, const int* in_sizes, int n_in,
                              void* d_out, int out_size, void* d_ws, size_t ws_size,
                              hipStream_t stream)
{
    (void)in_sizes; (void)n_in; (void)out_size; (void)ws_size;
    const float* x    = (const float*)d_in[0];
    const int*   ei   = (const int*)d_in[1];
    const float* eps  = (const float*)d_in[3];
    const float* gw1  = (const float*)d_in[4];
    const float* gb1  = (const float*)d_in[5];
    const float* gw2  = (const float*)d_in[6];
    const float* gb2  = (const float*)d_in[7];
    const float* ipw  = (const float*)d_in[8];
    const float* cw   = (const float*)d_in[9];
    const float* cb   = (const float*)d_in[10];
    const float* xpw  = (const float*)d_in[11];
    const float* dtw  = (const float*)d_in[12];
    const float* dtb  = (const float*)d_in[13];
    const float* Alog = (const float*)d_in[14];
    const float* Dp   = (const float*)d_in[15];
    const float* opw  = (const float*)d_in[16];
    const float* mw1  = (const float*)d_in[17];
    const float* mb1  = (const float*)d_in[18];
    const float* mw2  = (const float*)d_in[19];
    const float* mb2  = (const float*)d_in[20];
    const float* g1   = (const float*)d_in[21];
    const float* be1  = (const float*)d_in[22];
    const float* g2   = (const float*)d_in[23];
    const float* be2  = (const float*)d_in[24];
    const float* g3   = (const float*)d_in[25];
    const float* be3  = (const float*)d_in[26];

    float* outp = (float*)d_out;                       // [N*C] final out
    float* h2o  = outp + (size_t)NN * CC;              // [N*C] h2

    float* ws   = (float*)d_ws;
    float* xz   = ws;                                  // N*256 (later t2)
    float* agg  = xz + (size_t)NN * 256;               // N*128 (later p3)
    float* s2b  = agg + (size_t)NN * 128;              // t1 -> xs_post
    float* s3b  = s2b + (size_t)NN * 128;              // dt
    float* s4b  = s3b + (size_t)NN * 128;              // y2 -> out12
    float* xdbl = s4b + (size_t)NN * 128;              // N*48
    float* stats = xdbl + (size_t)NN * 48;             // 768 floats
    float* p1 = outp;   // GIN pre-norm lives in d_out (overwritten by norm3)
    float* p2 = h2o;    // mamba pre-norm lives in d_out h2 slot (normed in place)
    float* p3 = agg;
    float* t1 = s2b, *xsp = s2b;
    float* dtb_buf = s3b;
    float* y2 = s4b, *out12 = s4b;
    float* t2 = xz;

    hipMemsetAsync(agg, 0, (size_t)NN * CC * sizeof(float), stream);
    hipMemsetAsync(stats, 0, 768 * sizeof(float), stream);

    scatter_kernel<<<dim3((EE * CC) / 256), 256, 0, stream>>>(ei, x, agg);

    // GIN MLP: t1 = relu(((1+eps)x+agg) @ gw1^T + gb1); p1 = t1 @ gw2^T + gb2 + x  (stats S1)
    gemm_kernel<128,128,true, true, true, false,false><<<dim3(256,1),256,0,stream>>>(
        x, 128, agg, eps, gw1, gb1, nullptr, t1, 128, nullptr, nullptr);
    gemm_kernel<128,128,false,false,true, true, true ><<<dim3(256,1),256,0,stream>>>(
        t1, 128, nullptr, nullptr, gw2, gb2, x, p1, 128, stats + 0, stats + 128);

    // Mamba: xz = x @ in_proj^T
    gemm_kernel<128,128,false,false,false,false,false><<<dim3(256,2),256,0,stream>>>(
        x, 128, nullptr, nullptr, ipw, nullptr, nullptr, xz, 256, nullptr, nullptr);
    conv_kernel<<<dim3((NN * CC) / 256), 256, 0, stream>>>(xz, cw, cb, xsp);
    gemm_kernel<128,40, false,false,false,false,false><<<dim3(256,1),256,0,stream>>>(
        xsp, 128, nullptr, nullptr, xpw, nullptr, nullptr, xdbl, 48, nullptr, nullptr);
    dt_kernel<<<dim3(NN / 2), 256, 0, stream>>>(xdbl, dtw, dtb, dtb_buf);
    scan_kernel<<<dim3(256), 256, 0, stream>>>(xdbl, dtb_buf, xsp, xz, Alog, Dp, y2);
    gemm_kernel<128,128,false,false,false,true, true ><<<dim3(256,1),256,0,stream>>>(
        y2, 128, nullptr, nullptr, opw, nullptr, x, p2, 128, stats + 256, stats + 384);

    // h1 = bn(p1), h2 = bn(p2) -> h2o ; out12 = h1+h2
    norm12_kernel<<<dim3(1024), 256, 0, stream>>>(p1, p2, stats, g1, be1, g2, be2, h2o, out12);

    // MLP: t2 = relu(out12 @ mw1^T + mb1); p3 = t2 @ mw2^T + mb2 + out12 (stats S3)
    gemm_kernel<128,128,false,true, true, false,false><<<dim3(256,2),256,0,stream>>>(
        out12, 128, nullptr, nullptr, mw1, mb1, nullptr, t2, 256, nullptr, nullptr);
    gemm_kernel<256,128,false,false,true, true, true ><<<dim3(256,1),256,0,stream>>>(
        t2, 256, nullptr, nullptr, mw2, mb2, out12, p3, 128, stats + 512, stats + 640);

    norm3_kernel<<<dim3(1024), 256, 0, stream>>>(p3, stats, g3, be3, outp);
}

// Round 2
// 589.546 us; speedup vs baseline: 1.1667x; 1.1667x over previous
//
#include <hip/hip_runtime.h>
#include <hip/hip_bf16.h>

#define NN 32768
#define GG 128
#define LL 256
#define CC 128
#define EE 524288
#define DSTATE 16

// ---------------------------------------------------------------- edge histogram
__global__ __launch_bounds__(256) void hist_kernel(const int* __restrict__ ei,
    int* __restrict__ cnt)
{
    int e = blockIdx.x * 256 + threadIdx.x;
    atomicAdd(&cnt[ei[EE + e]], 1);
}

// ---------------------------------------------------------------- exclusive scan of 32768 counts
__global__ __launch_bounds__(1024) void scan32k_kernel(const int* __restrict__ cnt,
    int* __restrict__ base, int* __restrict__ cursor)
{
    __shared__ int part[1024];
    int tid = threadIdx.x;
    int local[32];
    int s = 0;
#pragma unroll
    for (int j = 0; j < 32; j++) { local[j] = cnt[tid * 32 + j]; s += local[j]; }
    part[tid] = s;
    __syncthreads();
    for (int off = 1; off < 1024; off <<= 1) {
        int v = (tid >= off) ? part[tid - off] : 0;
        __syncthreads();
        part[tid] += v;
        __syncthreads();
    }
    int run = part[tid] - s;   // exclusive prefix of this thread's chunk
#pragma unroll
    for (int j = 0; j < 32; j++) {
        base[tid * 32 + j] = run;
        cursor[tid * 32 + j] = run;
        run += local[j];
    }
    if (tid == 0) base[NN] = EE;
}

// ---------------------------------------------------------------- permute srcs into dst-sorted order
__global__ __launch_bounds__(256) void permute_kernel(const int* __restrict__ ei,
    int* __restrict__ cursor, int* __restrict__ perm)
{
    int e = blockIdx.x * 256 + threadIdx.x;
    int dst = ei[EE + e];
    int pos = atomicAdd(&cursor[dst], 1);
    perm[pos] = ei[e];
}

// ---------------------------------------------------------------- gather-sum per node (CSR)
__global__ __launch_bounds__(256) void gather_kernel(const int* __restrict__ perm,
    const int* __restrict__ base, const float* __restrict__ x, float* __restrict__ agg)
{
    int node = blockIdx.x * 2 + (threadIdx.x >> 7);
    int c = threadIdx.x & 127;
    int b0 = base[node], b1 = base[node + 1];
    float s = 0.f, t = 0.f;
    int i = b0;
    for (; i + 1 < b1; i += 2) {
        int s1 = perm[i], s2 = perm[i + 1];
        s += x[(size_t)s1 * CC + c];
        t += x[(size_t)s2 * CC + c];
    }
    if (i < b1) s += x[(size_t)perm[i] * CC + c];
    agg[(size_t)node * CC + c] = s + t;
}

// ---------------------------------------------------------------- generic fp32 GEMM
// out[r][o] = sum_k A'[r][k] * W[o][k] (+bias) (relu) (+resid) ; optional bn-stats
// A' = APREP ? (1+eps)*A + A2 : A
// Block: 256 thr, tile 128 rows x 128 cols, thread tile 8x8 (cols split 4+4).
template<int K, int COLS_VALID, bool APREP, bool RELU, bool HAS_BIAS, bool HAS_RESID, bool STATS>
__global__ __launch_bounds__(256)
void gemm_kernel(const float* __restrict__ A, int lda,
                 const float* __restrict__ A2, const float* __restrict__ epsp,
                 const float* __restrict__ W,
                 const float* __restrict__ bias,
                 const float* __restrict__ resid,
                 float* __restrict__ out, int ldo,
                 float* ssum, float* ssq)
{
    __shared__ alignas(16) float At[16 * 128];
    __shared__ alignas(16) float Wt[16 * 128];
    __shared__ float sred[256];
    const int tid = threadIdx.x;
    const int R0 = blockIdx.x * 128;
    const int by = blockIdx.y;
    const int tr = tid >> 4, tc = tid & 15;
    const int r_s = tid >> 1;
    const int kq = (tid & 1) * 8;
    const float e1 = APREP ? (1.0f + epsp[0]) : 0.0f;

    float acc[8][8];
#pragma unroll
    for (int i = 0; i < 8; i++)
#pragma unroll
        for (int j = 0; j < 8; j++) acc[i][j] = 0.f;

    const int o_g = by * 128 + r_s;
    const float* wrow = W + (size_t)o_g * K;
    const float* arow = A + (size_t)(R0 + r_s) * lda;
    const float* a2row = APREP ? (A2 + (size_t)(R0 + r_s) * (size_t)CC) : nullptr;

    for (int kc = 0; kc < K; kc += 16) {
        float av[8], wv[8];
        {
            float4 t0 = *(const float4*)(arow + kc + kq);
            float4 t1 = *(const float4*)(arow + kc + kq + 4);
            av[0]=t0.x; av[1]=t0.y; av[2]=t0.z; av[3]=t0.w;
            av[4]=t1.x; av[5]=t1.y; av[6]=t1.z; av[7]=t1.w;
        }
        if (APREP) {
            float4 u0 = *(const float4*)(a2row + kc + kq);
            float4 u1 = *(const float4*)(a2row + kc + kq + 4);
            av[0]=fmaf(e1,av[0],u0.x); av[1]=fmaf(e1,av[1],u0.y);
            av[2]=fmaf(e1,av[2],u0.z); av[3]=fmaf(e1,av[3],u0.w);
            av[4]=fmaf(e1,av[4],u1.x); av[5]=fmaf(e1,av[5],u1.y);
            av[6]=fmaf(e1,av[6],u1.z); av[7]=fmaf(e1,av[7],u1.w);
        }
        if (COLS_VALID == 128 || o_g < COLS_VALID) {
            float4 w0 = *(const float4*)(wrow + kc + kq);
            float4 w1 = *(const float4*)(wrow + kc + kq + 4);
            wv[0]=w0.x; wv[1]=w0.y; wv[2]=w0.z; wv[3]=w0.w;
            wv[4]=w1.x; wv[5]=w1.y; wv[6]=w1.z; wv[7]=w1.w;
        } else {
#pragma unroll
            for (int j = 0; j < 8; j++) wv[j] = 0.f;
        }
        __syncthreads();
#pragma unroll
        for (int j = 0; j < 8; j++) {
            At[(kq + j) * 128 + r_s] = av[j];
            Wt[(kq + j) * 128 + r_s] = wv[j];
        }
        __syncthreads();
#pragma unroll
        for (int kk = 0; kk < 16; kk++) {
            const float4* At4 = (const float4*)(At + kk * 128);
            const float4* Wt4 = (const float4*)(Wt + kk * 128);
            float4 a0 = At4[tr * 2], a1 = At4[tr * 2 + 1];
            float4 b0 = Wt4[tc],     b1 = Wt4[tc + 16];
            float a[8] = {a0.x,a0.y,a0.z,a0.w,a1.x,a1.y,a1.z,a1.w};
            float b[8] = {b0.x,b0.y,b0.z,b0.w,b1.x,b1.y,b1.z,b1.w};
#pragma unroll
            for (int i = 0; i < 8; i++)
#pragma unroll
                for (int j = 0; j < 8; j++)
                    acc[i][j] = fmaf(a[i], b[j], acc[i][j]);
        }
    }

    const int c0 = by * 128 + tc * 4;
    const int c1 = c0 + 64;
    float bias0[4] = {0,0,0,0}, bias1[4] = {0,0,0,0};
    if (HAS_BIAS) {
        float4 bb0 = *(const float4*)(bias + c0);
        float4 bb1 = *(const float4*)(bias + c1);
        bias0[0]=bb0.x; bias0[1]=bb0.y; bias0[2]=bb0.z; bias0[3]=bb0.w;
        bias1[0]=bb1.x; bias1[1]=bb1.y; bias1[2]=bb1.z; bias1[3]=bb1.w;
    }
    const bool st0 = (COLS_VALID == 128) || (tc * 4 < COLS_VALID);
    const bool st1 = (COLS_VALID == 128) || (64 + tc * 4 < COLS_VALID);

#pragma unroll
    for (int i = 0; i < 8; i++) {
        int r = R0 + tr * 8 + i;
        float v[8];
#pragma unroll
        for (int j = 0; j < 8; j++) {
            v[j] = acc[i][j] + ((j < 4) ? bias0[j] : bias1[j - 4]);
            if (RELU) v[j] = fmaxf(v[j], 0.f);
        }
        if (HAS_RESID) {
            float4 rv0 = *(const float4*)(resid + (size_t)r * CC + tc * 4);
            float4 rv1 = *(const float4*)(resid + (size_t)r * CC + 64 + tc * 4);
            v[0]+=rv0.x; v[1]+=rv0.y; v[2]+=rv0.z; v[3]+=rv0.w;
            v[4]+=rv1.x; v[5]+=rv1.y; v[6]+=rv1.z; v[7]+=rv1.w;
        }
        if (st0) *(float4*)(out + (size_t)r * ldo + c0) = make_float4(v[0],v[1],v[2],v[3]);
        if (st1) *(float4*)(out + (size_t)r * ldo + c1) = make_float4(v[4],v[5],v[6],v[7]);
        if (STATS) {
#pragma unroll
            for (int j = 0; j < 8; j++) acc[i][j] = v[j];
        }
    }

    if (STATS) {
        __syncthreads();
        if (tid < 128) { sred[tid] = 0.f; sred[tid + 128] = 0.f; }
        __syncthreads();
#pragma unroll
        for (int j = 0; j < 8; j++) {
            int cl = (j < 4) ? (tc * 4 + j) : (64 + tc * 4 + (j - 4));
            float s = 0.f, q = 0.f;
#pragma unroll
            for (int i = 0; i < 8; i++) { float v = acc[i][j]; s += v; q += v * v; }
            atomicAdd(&sred[cl], s);
            atomicAdd(&sred[128 + cl], q);
        }
        __syncthreads();
        if (tid < 128) {
            atomicAdd(&ssum[tid], sred[tid]);
            atomicAdd(&ssq[tid], sred[128 + tid]);
        }
    }
}

// ---------------------------------------------------------------- depthwise causal conv + silu
__global__ __launch_bounds__(256) void conv_kernel(const float* __restrict__ xz,
    const float* __restrict__ cw, const float* __restrict__ cb, float* __restrict__ xsp)
{
    int t = blockIdx.x * 256 + threadIdx.x;   // N*128
    int n = t >> 7, c = t & 127;
    int l = n & (LL - 1);
    float4 w = *(const float4*)(cw + c * 4);
    float v = cb[c];
    v = fmaf(xz[(size_t)n * 256 + c], w.w, v);
    if (l >= 1) v = fmaf(xz[(size_t)(n - 1) * 256 + c], w.z, v);
    if (l >= 2) v = fmaf(xz[(size_t)(n - 2) * 256 + c], w.y, v);
    if (l >= 3) v = fmaf(xz[(size_t)(n - 3) * 256 + c], w.x, v);
    xsp[t] = v / (1.f + __expf(-v));
}

// ---------------------------------------------------------------- dt = softplus(dtr @ dtw^T + b)
__global__ __launch_bounds__(256) void dt_kernel(const float* __restrict__ xdbl,
    const float* __restrict__ dtw, const float* __restrict__ dtb, float* __restrict__ dt)
{
    __shared__ float wT[8 * 128];
    __shared__ float rbuf[16];
    int tid = threadIdx.x;
    for (int i = tid; i < 1024; i += 256) {
        int d = i >> 3, r = i & 7;
        wT[r * 128 + d] = dtw[i];
    }
    int n0 = blockIdx.x * 2;
    if (tid < 16) rbuf[tid] = xdbl[(size_t)(n0 + (tid >> 3)) * 48 + (tid & 7)];
    __syncthreads();
    int rr = tid >> 7, d = tid & 127;
    float acc = dtb[d];
#pragma unroll
    for (int r = 0; r < 8; r++) acc = fmaf(rbuf[rr * 8 + r], wT[r * 128 + d], acc);
    float sp = (acc > 20.f) ? acc : log1pf(__expf(acc));
    dt[(size_t)(n0 + rr) * 128 + d] = sp;
}

// ---------------------------------------------------------------- selective scan + gating
// grid: 256 blocks (g = b/2, ch = b&1); block 256 thr: c_local = tid/4, sp = tid&3
__global__ __launch_bounds__(256) void scan_kernel(const float* __restrict__ xdbl,
    const float* __restrict__ dt, const float* __restrict__ xsp,
    const float* __restrict__ xz, const float* __restrict__ Alog,
    const float* __restrict__ Dp, float* __restrict__ y2)
{
    __shared__ float BC[256 * 32];
    int g = blockIdx.x >> 1, ch = blockIdx.x & 1;
    int tid = threadIdx.x;
    for (int i = tid; i < 8192; i += 256)
        BC[i] = xdbl[(size_t)(g * 256 + (i >> 5)) * 48 + 8 + (i & 31)];
    int cl = tid >> 2, sp = tid & 3;
    int c = ch * 64 + cl;
    float ae[4];
#pragma unroll
    for (int j = 0; j < 4; j++) ae[j] = -__expf(Alog[c * 16 + sp * 4 + j]);
    float dpc = Dp[c];
    float h0 = 0, h1 = 0, h2 = 0, h3 = 0;
    __syncthreads();
    const float* dtg = dt  + (size_t)g * 256 * 128 + c;
    const float* xg  = xsp + (size_t)g * 256 * 128 + c;
    const float* zg  = xz  + (size_t)g * 256 * 256 + 128 + c;
    float* yg = y2 + (size_t)g * 256 * 128 + c;
    for (int t = 0; t < 256; t++) {
        float dtv = dtg[t * 128];
        float xv  = xg[t * 128];
        float zv  = zg[t * 256];
        float u = dtv * xv;
        const float* bc = BC + t * 32 + sp * 4;
        h0 = fmaf(__expf(dtv * ae[0]), h0, u * bc[0]);
        h1 = fmaf(__expf(dtv * ae[1]), h1, u * bc[1]);
        h2 = fmaf(__expf(dtv * ae[2]), h2, u * bc[2]);
        h3 = fmaf(__expf(dtv * ae[3]), h3, u * bc[3]);
        float y = h0 * bc[16] + h1 * bc[17] + h2 * bc[18] + h3 * bc[19];
        y += __shfl_xor(y, 1);
        y += __shfl_xor(y, 2);
        if (sp == 0) {
            float yo = fmaf(dpc, xv, y);
            yg[t * 128] = yo * (zv / (1.f + __expf(-zv)));
        }
    }
}

// ---------------------------------------------------------------- norm (h1,h2) + combine
__global__ __launch_bounds__(256) void norm12_kernel(const float* p1,
    const float* p2, const float* stats,
    const float* g1, const float* be1, const float* g2, const float* be2,
    float* h2out, float* out12)
{
    __shared__ float sc[512];
    int tid = threadIdx.x;
    if (tid < 128) {
        int c = tid;
        const float inv = 1.0f / NN;
        float m1 = stats[c] * inv;
        float v1 = fmaxf(stats[128 + c] * inv - m1 * m1, 0.f);
        float i1 = rsqrtf(v1 + 1e-5f);
        sc[c] = g1[c] * i1; sc[128 + c] = be1[c] - m1 * g1[c] * i1;
        float m2 = stats[256 + c] * inv;
        float v2 = fmaxf(stats[384 + c] * inv - m2 * m2, 0.f);
        float i2 = rsqrtf(v2 + 1e-5f);
        sc[256 + c] = g2[c] * i2; sc[384 + c] = be2[c] - m2 * g2[c] * i2;
    }
    __syncthreads();
    int c = tid & 127;
    float s1 = sc[c], t1 = sc[128 + c], s2 = sc[256 + c], t2 = sc[384 + c];
    for (int i = tid; i < 4096; i += 256) {
        size_t idx = (size_t)blockIdx.x * 4096 + i;
        float a = fmaf(p1[idx], s1, t1);
        float b = fmaf(p2[idx], s2, t2);
        h2out[idx] = b;
        out12[idx] = a + b;
    }
}

// ---------------------------------------------------------------- final norm
__global__ __launch_bounds__(256) void norm3_kernel(const float* p3,
    const float* stats, const float* g3, const float* be3, float* outp)
{
    __shared__ float sc[256];
    int tid = threadIdx.x;
    if (tid < 128) {
        int c = tid;
        const float inv = 1.0f / NN;
        float m = stats[512 + c] * inv;
        float v = fmaxf(stats[640 + c] * inv - m * m, 0.f);
        float iv = rsqrtf(v + 1e-5f);
        sc[c] = g3[c] * iv; sc[128 + c] = be3[c] - m * g3[c] * iv;
    }
    __syncthreads();
    int c = tid & 127;
    float s = sc[c], t = sc[128 + c];
    for (int i = tid; i < 4096; i += 256) {
        size_t idx = (size_t)blockIdx.x * 4096 + i;
        outp[idx] = fmaf(p3[idx], s, t);
    }
}

extern "C" void kernel_launch(void* const* d_in, const int* in_sizes, int n_in,
                              void* d_out, int out_size, void* d_ws, size_t ws_size,
                              hipStream_t stream)
{
    (void)in_sizes; (void)n_in; (void)out_size; (void)ws_size;
    const float* x    = (const float*)d_in[0];
    const int*   ei   = (const int*)d_in[1];
    const float* eps  = (const float*)d_in[3];
    const float* gw1  = (const float*)d_in[4];
    const float* gb1  = (const float*)d_in[5];
    const float* gw2  = (const float*)d_in[6];
    const float* gb2  = (const float*)d_in[7];
    const float* ipw  = (const float*)d_in[8];
    const float* cw   = (const float*)d_in[9];
    const float* cb   = (const float*)d_in[10];
    const float* xpw  = (const float*)d_in[11];
    const float* dtw  = (const float*)d_in[12];
    const float* dtb  = (const float*)d_in[13];
    const float* Alog = (const float*)d_in[14];
    const float* Dp   = (const float*)d_in[15];
    const float* opw  = (const float*)d_in[16];
    const float* mw1  = (const float*)d_in[17];
    const float* mb1  = (const float*)d_in[18];
    const float* mw2  = (const float*)d_in[19];
    const float* mb2  = (const float*)d_in[20];
    const float* g1   = (const float*)d_in[21];
    const float* be1  = (const float*)d_in[22];
    const float* g2   = (const float*)d_in[23];
    const float* be2  = (const float*)d_in[24];
    const float* g3   = (const float*)d_in[25];
    const float* be3  = (const float*)d_in[26];

    float* outp = (float*)d_out;                       // [N*C] final out
    float* h2o  = outp + (size_t)NN * CC;              // [N*C] h2

    float* ws   = (float*)d_ws;
    float* xz   = ws;                                  // N*256 (later t2)
    float* agg  = xz + (size_t)NN * 256;               // N*128 (later p3)
    float* s2b  = agg + (size_t)NN * 128;              // t1 -> xs_post
    float* s3b  = s2b + (size_t)NN * 128;              // dt
    float* s4b  = s3b + (size_t)NN * 128;              // y2 -> out12
    float* xdbl = s4b + (size_t)NN * 128;              // N*48
    float* stats = xdbl + (size_t)NN * 48;             // 768 floats
    int*   cnt   = (int*)(stats + 768);                // N
    int*   baseA = cnt + NN;                           // N+1
    int*   cursor= baseA + NN + 1;                     // N
    int*   perm  = cursor + NN;                        // E
    float* p1 = outp;   // GIN pre-norm lives in d_out (overwritten by norm3)
    float* p2 = h2o;    // mamba pre-norm lives in d_out h2 slot (normed in place)
    float* p3 = agg;
    float* t1 = s2b, *xsp = s2b;
    float* dtb_buf = s3b;
    float* y2 = s4b, *out12 = s4b;
    float* t2 = xz;

    hipMemsetAsync(cnt, 0, NN * sizeof(int), stream);
    hipMemsetAsync(stats, 0, 768 * sizeof(float), stream);

    // CSR build + gather (replaces 67M-fp32-atomic scatter)
    hist_kernel<<<dim3(EE / 256), 256, 0, stream>>>(ei, cnt);
    scan32k_kernel<<<dim3(1), 1024, 0, stream>>>(cnt, baseA, cursor);
    permute_kernel<<<dim3(EE / 256), 256, 0, stream>>>(ei, cursor, perm);
    gather_kernel<<<dim3(NN / 2), 256, 0, stream>>>(perm, baseA, x, agg);

    // GIN MLP: t1 = relu(((1+eps)x+agg) @ gw1^T + gb1); p1 = t1 @ gw2^T + gb2 + x  (stats S1)
    gemm_kernel<128,128,true, true, true, false,false><<<dim3(256,1),256,0,stream>>>(
        x, 128, agg, eps, gw1, gb1, nullptr, t1, 128, nullptr, nullptr);
    gemm_kernel<128,128,false,false,true, true, true ><<<dim3(256,1),256,0,stream>>>(
        t1, 128, nullptr, nullptr, gw2, gb2, x, p1, 128, stats + 0, stats + 128);

    // Mamba: xz = x @ in_proj^T
    gemm_kernel<128,128,false,false,false,false,false><<<dim3(256,2),256,0,stream>>>(
        x, 128, nullptr, nullptr, ipw, nullptr, nullptr, xz, 256, nullptr, nullptr);
    conv_kernel<<<dim3((NN * CC) / 256), 256, 0, stream>>>(xz, cw, cb, xsp);
    gemm_kernel<128,40, false,false,false,false,false><<<dim3(256,1),256,0,stream>>>(
        xsp, 128, nullptr, nullptr, xpw, nullptr, nullptr, xdbl, 48, nullptr, nullptr);
    dt_kernel<<<dim3(NN / 2), 256, 0, stream>>>(xdbl, dtw, dtb, dtb_buf);
    scan_kernel<<<dim3(256), 256, 0, stream>>>(xdbl, dtb_buf, xsp, xz, Alog, Dp, y2);
    gemm_kernel<128,128,false,false,false,true, true ><<<dim3(256,1),256,0,stream>>>(
        y2, 128, nullptr, nullptr, opw, nullptr, x, p2, 128, stats + 256, stats + 384);

    // h1 = bn(p1), h2 = bn(p2) -> h2o ; out12 = h1+h2
    norm12_kernel<<<dim3(1024), 256, 0, stream>>>(p1, p2, stats, g1, be1, g2, be2, h2o, out12);

    // MLP: t2 = relu(out12 @ mw1^T + mb1); p3 = t2 @ mw2^T + mb2 + out12 (stats S3)
    gemm_kernel<128,128,false,true, true, false,false><<<dim3(256,2),256,0,stream>>>(
        out12, 128, nullptr, nullptr, mw1, mb1, nullptr, t2, 256, nullptr, nullptr);
    gemm_kernel<256,128,false,false,true, true, true ><<<dim3(256,1),256,0,stream>>>(
        t2, 256, nullptr, nullptr, mw2, mb2, out12, p3, 128, stats + 512, stats + 640);

    norm3_kernel<<<dim3(1024), 256, 0, stream>>>(p3, stats, g3, be3, outp);
}

// Round 3
// 478.499 us; speedup vs baseline: 1.4374x; 1.2321x over previous
//
#include <hip/hip_runtime.h>
#include <hip/hip_bf16.h>

#define NN 32768
#define GG 128
#define LL 256
#define CC 128
#define EE 524288
#define DSTATE 16
#define NCHUNK 8
#define TCH 32

// ---------------------------------------------------------------- edge histogram
__global__ __launch_bounds__(256) void hist_kernel(const int* __restrict__ ei,
    int* __restrict__ cnt)
{
    int e = blockIdx.x * 256 + threadIdx.x;
    atomicAdd(&cnt[ei[EE + e]], 1);
}

// ---------------------------------------------------------------- exclusive scan of 32768 counts
__global__ __launch_bounds__(1024) void scan32k_kernel(const int* __restrict__ cnt,
    int* __restrict__ base, int* __restrict__ cursor)
{
    __shared__ int part[1024];
    int tid = threadIdx.x;
    int local[32];
    int s = 0;
#pragma unroll
    for (int j = 0; j < 32; j++) { local[j] = cnt[tid * 32 + j]; s += local[j]; }
    part[tid] = s;
    __syncthreads();
    for (int off = 1; off < 1024; off <<= 1) {
        int v = (tid >= off) ? part[tid - off] : 0;
        __syncthreads();
        part[tid] += v;
        __syncthreads();
    }
    int run = part[tid] - s;   // exclusive prefix of this thread's chunk
#pragma unroll
    for (int j = 0; j < 32; j++) {
        base[tid * 32 + j] = run;
        cursor[tid * 32 + j] = run;
        run += local[j];
    }
    if (tid == 0) base[NN] = EE;
}

// ---------------------------------------------------------------- permute srcs into dst-sorted order
__global__ __launch_bounds__(256) void permute_kernel(const int* __restrict__ ei,
    int* __restrict__ cursor, int* __restrict__ perm)
{
    int e = blockIdx.x * 256 + threadIdx.x;
    int dst = ei[EE + e];
    int pos = atomicAdd(&cursor[dst], 1);
    perm[pos] = ei[e];
}

// ---------------------------------------------------------------- gather-sum per node (CSR)
__global__ __launch_bounds__(256) void gather_kernel(const int* __restrict__ perm,
    const int* __restrict__ base, const float* __restrict__ x, float* __restrict__ agg)
{
    int node = blockIdx.x * 2 + (threadIdx.x >> 7);
    int c = threadIdx.x & 127;
    int b0 = base[node], b1 = base[node + 1];
    float s = 0.f, t = 0.f;
    int i = b0;
    for (; i + 1 < b1; i += 2) {
        int s1 = perm[i], s2 = perm[i + 1];
        s += x[(size_t)s1 * CC + c];
        t += x[(size_t)s2 * CC + c];
    }
    if (i < b1) s += x[(size_t)perm[i] * CC + c];
    agg[(size_t)node * CC + c] = s + t;
}

// ---------------------------------------------------------------- generic fp32 GEMM
template<int K, int COLS_VALID, bool APREP, bool RELU, bool HAS_BIAS, bool HAS_RESID, bool STATS>
__global__ __launch_bounds__(256)
void gemm_kernel(const float* __restrict__ A, int lda,
                 const float* __restrict__ A2, const float* __restrict__ epsp,
                 const float* __restrict__ W,
                 const float* __restrict__ bias,
                 const float* __restrict__ resid,
                 float* __restrict__ out, int ldo,
                 float* ssum, float* ssq)
{
    __shared__ alignas(16) float At[16 * 128];
    __shared__ alignas(16) float Wt[16 * 128];
    __shared__ float sred[256];
    const int tid = threadIdx.x;
    const int R0 = blockIdx.x * 128;
    const int by = blockIdx.y;
    const int tr = tid >> 4, tc = tid & 15;
    const int r_s = tid >> 1;
    const int kq = (tid & 1) * 8;
    const float e1 = APREP ? (1.0f + epsp[0]) : 0.0f;

    float acc[8][8];
#pragma unroll
    for (int i = 0; i < 8; i++)
#pragma unroll
        for (int j = 0; j < 8; j++) acc[i][j] = 0.f;

    const int o_g = by * 128 + r_s;
    const float* wrow = W + (size_t)o_g * K;
    const float* arow = A + (size_t)(R0 + r_s) * lda;
    const float* a2row = APREP ? (A2 + (size_t)(R0 + r_s) * (size_t)CC) : nullptr;

    for (int kc = 0; kc < K; kc += 16) {
        float av[8], wv[8];
        {
            float4 t0 = *(const float4*)(arow + kc + kq);
            float4 t1 = *(const float4*)(arow + kc + kq + 4);
            av[0]=t0.x; av[1]=t0.y; av[2]=t0.z; av[3]=t0.w;
            av[4]=t1.x; av[5]=t1.y; av[6]=t1.z; av[7]=t1.w;
        }
        if (APREP) {
            float4 u0 = *(const float4*)(a2row + kc + kq);
            float4 u1 = *(const float4*)(a2row + kc + kq + 4);
            av[0]=fmaf(e1,av[0],u0.x); av[1]=fmaf(e1,av[1],u0.y);
            av[2]=fmaf(e1,av[2],u0.z); av[3]=fmaf(e1,av[3],u0.w);
            av[4]=fmaf(e1,av[4],u1.x); av[5]=fmaf(e1,av[5],u1.y);
            av[6]=fmaf(e1,av[6],u1.z); av[7]=fmaf(e1,av[7],u1.w);
        }
        if (COLS_VALID == 128 || o_g < COLS_VALID) {
            float4 w0 = *(const float4*)(wrow + kc + kq);
            float4 w1 = *(const float4*)(wrow + kc + kq + 4);
            wv[0]=w0.x; wv[1]=w0.y; wv[2]=w0.z; wv[3]=w0.w;
            wv[4]=w1.x; wv[5]=w1.y; wv[6]=w1.z; wv[7]=w1.w;
        } else {
#pragma unroll
            for (int j = 0; j < 8; j++) wv[j] = 0.f;
        }
        __syncthreads();
#pragma unroll
        for (int j = 0; j < 8; j++) {
            At[(kq + j) * 128 + r_s] = av[j];
            Wt[(kq + j) * 128 + r_s] = wv[j];
        }
        __syncthreads();
#pragma unroll
        for (int kk = 0; kk < 16; kk++) {
            const float4* At4 = (const float4*)(At + kk * 128);
            const float4* Wt4 = (const float4*)(Wt + kk * 128);
            float4 a0 = At4[tr * 2], a1 = At4[tr * 2 + 1];
            float4 b0 = Wt4[tc],     b1 = Wt4[tc + 16];
            float a[8] = {a0.x,a0.y,a0.z,a0.w,a1.x,a1.y,a1.z,a1.w};
            float b[8] = {b0.x,b0.y,b0.z,b0.w,b1.x,b1.y,b1.z,b1.w};
#pragma unroll
            for (int i = 0; i < 8; i++)
#pragma unroll
                for (int j = 0; j < 8; j++)
                    acc[i][j] = fmaf(a[i], b[j], acc[i][j]);
        }
    }

    const int c0 = by * 128 + tc * 4;
    const int c1 = c0 + 64;
    float bias0[4] = {0,0,0,0}, bias1[4] = {0,0,0,0};
    if (HAS_BIAS) {
        float4 bb0 = *(const float4*)(bias + c0);
        float4 bb1 = *(const float4*)(bias + c1);
        bias0[0]=bb0.x; bias0[1]=bb0.y; bias0[2]=bb0.z; bias0[3]=bb0.w;
        bias1[0]=bb1.x; bias1[1]=bb1.y; bias1[2]=bb1.z; bias1[3]=bb1.w;
    }
    const bool st0 = (COLS_VALID == 128) || (tc * 4 < COLS_VALID);
    const bool st1 = (COLS_VALID == 128) || (64 + tc * 4 < COLS_VALID);

#pragma unroll
    for (int i = 0; i < 8; i++) {
        int r = R0 + tr * 8 + i;
        float v[8];
#pragma unroll
        for (int j = 0; j < 8; j++) {
            v[j] = acc[i][j] + ((j < 4) ? bias0[j] : bias1[j - 4]);
            if (RELU) v[j] = fmaxf(v[j], 0.f);
        }
        if (HAS_RESID) {
            float4 rv0 = *(const float4*)(resid + (size_t)r * CC + tc * 4);
            float4 rv1 = *(const float4*)(resid + (size_t)r * CC + 64 + tc * 4);
            v[0]+=rv0.x; v[1]+=rv0.y; v[2]+=rv0.z; v[3]+=rv0.w;
            v[4]+=rv1.x; v[5]+=rv1.y; v[6]+=rv1.z; v[7]+=rv1.w;
        }
        if (st0) *(float4*)(out + (size_t)r * ldo + c0) = make_float4(v[0],v[1],v[2],v[3]);
        if (st1) *(float4*)(out + (size_t)r * ldo + c1) = make_float4(v[4],v[5],v[6],v[7]);
        if (STATS) {
#pragma unroll
            for (int j = 0; j < 8; j++) acc[i][j] = v[j];
        }
    }

    if (STATS) {
        __syncthreads();
        if (tid < 128) { sred[tid] = 0.f; sred[tid + 128] = 0.f; }
        __syncthreads();
#pragma unroll
        for (int j = 0; j < 8; j++) {
            int cl = (j < 4) ? (tc * 4 + j) : (64 + tc * 4 + (j - 4));
            float s = 0.f, q = 0.f;
#pragma unroll
            for (int i = 0; i < 8; i++) { float v = acc[i][j]; s += v; q += v * v; }
            atomicAdd(&sred[cl], s);
            atomicAdd(&sred[128 + cl], q);
        }
        __syncthreads();
        if (tid < 128) {
            atomicAdd(&ssum[tid], sred[tid]);
            atomicAdd(&ssq[tid], sred[128 + tid]);
        }
    }
}

// ---------------------------------------------------------------- depthwise causal conv + silu
__global__ __launch_bounds__(256) void conv_kernel(const float* __restrict__ xz,
    const float* __restrict__ cw, const float* __restrict__ cb, float* __restrict__ xsp)
{
    int t = blockIdx.x * 256 + threadIdx.x;   // N*128
    int n = t >> 7, c = t & 127;
    int l = n & (LL - 1);
    float4 w = *(const float4*)(cw + c * 4);
    float v = cb[c];
    v = fmaf(xz[(size_t)n * 256 + c], w.w, v);
    if (l >= 1) v = fmaf(xz[(size_t)(n - 1) * 256 + c], w.z, v);
    if (l >= 2) v = fmaf(xz[(size_t)(n - 2) * 256 + c], w.y, v);
    if (l >= 3) v = fmaf(xz[(size_t)(n - 3) * 256 + c], w.x, v);
    xsp[t] = v / (1.f + __expf(-v));
}

// ---------------------------------------------------------------- dt = softplus(dtr @ dtw^T + b)
__global__ __launch_bounds__(256) void dt_kernel(const float* __restrict__ xdbl,
    const float* __restrict__ dtw, const float* __restrict__ dtb, float* __restrict__ dt)
{
    __shared__ float wT[8 * 128];
    __shared__ float rbuf[16];
    int tid = threadIdx.x;
    for (int i = tid; i < 1024; i += 256) {
        int d = i >> 3, r = i & 7;
        wT[r * 128 + d] = dtw[i];
    }
    int n0 = blockIdx.x * 2;
    if (tid < 16) rbuf[tid] = xdbl[(size_t)(n0 + (tid >> 3)) * 48 + (tid & 7)];
    __syncthreads();
    int rr = tid >> 7, d = tid & 127;
    float acc = dtb[d];
#pragma unroll
    for (int r = 0; r < 8; r++) acc = fmaf(rbuf[rr * 8 + r], wT[r * 128 + d], acc);
    float sp = (acc > 20.f) ? acc : log1pf(__expf(acc));
    dt[(size_t)(n0 + rr) * 128 + d] = sp;
}

// ---------------------------------------------------------------- scan phase A: per-chunk (sum_dt, q)
// grid: g*16 + ch*8 + chunk (2048 blocks); block 256: cl=tid>>2 (64 ch), sp=tid&3
__global__ __launch_bounds__(256) void scan_part_kernel(const float* __restrict__ xdbl,
    const float* __restrict__ dt, const float* __restrict__ xsp,
    const float* __restrict__ Alog, float* __restrict__ Q, float* __restrict__ SDT)
{
    __shared__ float Bs[TCH * 16];
    __shared__ float dts[TCH * 64];
    __shared__ float xss[TCH * 64];
    int b = blockIdx.x;
    int g = b >> 4, ch = (b >> 3) & 1, chunk = b & 7;
    int t0 = chunk * TCH;
    int tid = threadIdx.x;
    for (int i = tid; i < TCH * 16; i += 256)
        Bs[i] = xdbl[(size_t)(g * LL + t0 + (i >> 4)) * 48 + 8 + (i & 15)];
    for (int i = tid; i < TCH * 64; i += 256) {
        int t = i >> 6, cl_ = i & 63;
        size_t row = (size_t)(g * LL + t0 + t) * CC + ch * 64 + cl_;
        dts[i] = dt[row];
        xss[i] = xsp[row];
    }
    int cl = tid >> 2, sp = tid & 3;
    int c = ch * 64 + cl;
    float ae[4];
#pragma unroll
    for (int j = 0; j < 4; j++) ae[j] = -__expf(Alog[c * 16 + sp * 4 + j]);
    __syncthreads();
    float q0 = 0, q1 = 0, q2 = 0, q3 = 0, sdt = 0;
    for (int t = TCH - 1; t >= 0; --t) {
        float dtv = dts[t * 64 + cl];
        float xv  = xss[t * 64 + cl];
        float u = dtv * xv;
        const float* bs = Bs + t * 16 + sp * 4;
        q0 = fmaf(__expf(ae[0] * sdt) * u, bs[0], q0);
        q1 = fmaf(__expf(ae[1] * sdt) * u, bs[1], q1);
        q2 = fmaf(__expf(ae[2] * sdt) * u, bs[2], q2);
        q3 = fmaf(__expf(ae[3] * sdt) * u, bs[3], q3);
        sdt += dtv;
    }
    float4* qp = (float4*)(Q + (((size_t)g * NCHUNK + chunk) * CC + c) * 16 + sp * 4);
    *qp = make_float4(q0, q1, q2, q3);
    if (sp == 0) SDT[((size_t)g * NCHUNK + chunk) * CC + c] = sdt;
}

// ---------------------------------------------------------------- scan phase B: combine chunk states
__global__ __launch_bounds__(256) void scan_combine_kernel(const float* __restrict__ Q,
    const float* __restrict__ SDT, const float* __restrict__ Alog, float* __restrict__ Hin)
{
    int idx = blockIdx.x * 256 + threadIdx.x;   // g*2048 + c*16 + s
    int g = idx >> 11;
    int cs = idx & 2047;
    float ae = -__expf(Alog[cs]);
    float h = 0.f;
#pragma unroll
    for (int k = 0; k < NCHUNK; k++) {
        size_t o = ((size_t)g * NCHUNK + k);
        Hin[o * 2048 + cs] = h;
        float sdt = SDT[o * CC + (cs >> 4)];
        h = fmaf(__expf(ae * sdt), h, Q[o * 2048 + cs]);
    }
}

// ---------------------------------------------------------------- scan phase C: forward with init + y
__global__ __launch_bounds__(256) void scan_final_kernel(const float* __restrict__ xdbl,
    const float* __restrict__ dt, const float* __restrict__ xsp,
    const float* __restrict__ xz, const float* __restrict__ Alog,
    const float* __restrict__ Dp, const float* __restrict__ Hin, float* __restrict__ y2)
{
    __shared__ float BC[TCH * 32];
    __shared__ float dts[TCH * 64];
    __shared__ float xss[TCH * 64];
    int b = blockIdx.x;
    int g = b >> 4, ch = (b >> 3) & 1, chunk = b & 7;
    int t0 = chunk * TCH;
    int tid = threadIdx.x;
    for (int i = tid; i < TCH * 32; i += 256)
        BC[i] = xdbl[(size_t)(g * LL + t0 + (i >> 5)) * 48 + 8 + (i & 31)];
    for (int i = tid; i < TCH * 64; i += 256) {
        int t = i >> 6, cl_ = i & 63;
        size_t row = (size_t)(g * LL + t0 + t) * CC + ch * 64 + cl_;
        dts[i] = dt[row];
        xss[i] = xsp[row];
    }
    int cl = tid >> 2, sp = tid & 3;
    int c = ch * 64 + cl;
    float ae[4];
#pragma unroll
    for (int j = 0; j < 4; j++) ae[j] = -__expf(Alog[c * 16 + sp * 4 + j]);
    float dpc = Dp[c];
    float4 hv = *(const float4*)(Hin + ((size_t)g * NCHUNK + chunk) * 2048 + c * 16 + sp * 4);
    float h0 = hv.x, h1 = hv.y, h2 = hv.z, h3 = hv.w;
    __syncthreads();
    const float* zg = xz + ((size_t)g * LL + t0) * 256 + 128 + c;
    float* yg = y2 + ((size_t)g * LL + t0) * CC + c;
    for (int t = 0; t < TCH; t++) {
        float dtv = dts[t * 64 + cl];
        float xv  = xss[t * 64 + cl];
        float u = dtv * xv;
        const float* bc = BC + t * 32 + sp * 4;
        h0 = fmaf(__expf(dtv * ae[0]), h0, u * bc[0]);
        h1 = fmaf(__expf(dtv * ae[1]), h1, u * bc[1]);
        h2 = fmaf(__expf(dtv * ae[2]), h2, u * bc[2]);
        h3 = fmaf(__expf(dtv * ae[3]), h3, u * bc[3]);
        float y = h0 * bc[16] + h1 * bc[17] + h2 * bc[18] + h3 * bc[19];
        y += __shfl_xor(y, 1);
        y += __shfl_xor(y, 2);
        if (sp == 0) {
            float zv = zg[t * 256];
            float yo = fmaf(dpc, xv, y);
            yg[t * 128] = yo * (zv / (1.f + __expf(-zv)));
        }
    }
}

// ---------------------------------------------------------------- norm (h1,h2) + combine
__global__ __launch_bounds__(256) void norm12_kernel(const float* p1,
    const float* p2, const float* stats,
    const float* g1, const float* be1, const float* g2, const float* be2,
    float* h2out, float* out12)
{
    __shared__ float sc[512];
    int tid = threadIdx.x;
    if (tid < 128) {
        int c = tid;
        const float inv = 1.0f / NN;
        float m1 = stats[c] * inv;
        float v1 = fmaxf(stats[128 + c] * inv - m1 * m1, 0.f);
        float i1 = rsqrtf(v1 + 1e-5f);
        sc[c] = g1[c] * i1; sc[128 + c] = be1[c] - m1 * g1[c] * i1;
        float m2 = stats[256 + c] * inv;
        float v2 = fmaxf(stats[384 + c] * inv - m2 * m2, 0.f);
        float i2 = rsqrtf(v2 + 1e-5f);
        sc[256 + c] = g2[c] * i2; sc[384 + c] = be2[c] - m2 * g2[c] * i2;
    }
    __syncthreads();
    int c = tid & 127;
    float s1 = sc[c], t1 = sc[128 + c], s2 = sc[256 + c], t2 = sc[384 + c];
    for (int i = tid; i < 4096; i += 256) {
        size_t idx = (size_t)blockIdx.x * 4096 + i;
        float a = fmaf(p1[idx], s1, t1);
        float b = fmaf(p2[idx], s2, t2);
        h2out[idx] = b;
        out12[idx] = a + b;
    }
}

// ---------------------------------------------------------------- final norm
__global__ __launch_bounds__(256) void norm3_kernel(const float* p3,
    const float* stats, const float* g3, const float* be3, float* outp)
{
    __shared__ float sc[256];
    int tid = threadIdx.x;
    if (tid < 128) {
        int c = tid;
        const float inv = 1.0f / NN;
        float m = stats[512 + c] * inv;
        float v = fmaxf(stats[640 + c] * inv - m * m, 0.f);
        float iv = rsqrtf(v + 1e-5f);
        sc[c] = g3[c] * iv; sc[128 + c] = be3[c] - m * g3[c] * iv;
    }
    __syncthreads();
    int c = tid & 127;
    float s = sc[c], t = sc[128 + c];
    for (int i = tid; i < 4096; i += 256) {
        size_t idx = (size_t)blockIdx.x * 4096 + i;
        outp[idx] = fmaf(p3[idx], s, t);
    }
}

extern "C" void kernel_launch(void* const* d_in, const int* in_sizes, int n_in,
                              void* d_out, int out_size, void* d_ws, size_t ws_size,
                              hipStream_t stream)
{
    (void)in_sizes; (void)n_in; (void)out_size; (void)ws_size;
    const float* x    = (const float*)d_in[0];
    const int*   ei   = (const int*)d_in[1];
    const float* eps  = (const float*)d_in[3];
    const float* gw1  = (const float*)d_in[4];
    const float* gb1  = (const float*)d_in[5];
    const float* gw2  = (const float*)d_in[6];
    const float* gb2  = (const float*)d_in[7];
    const float* ipw  = (const float*)d_in[8];
    const float* cw   = (const float*)d_in[9];
    const float* cb   = (const float*)d_in[10];
    const float* xpw  = (const float*)d_in[11];
    const float* dtw  = (const float*)d_in[12];
    const float* dtb  = (const float*)d_in[13];
    const float* Alog = (const float*)d_in[14];
    const float* Dp   = (const float*)d_in[15];
    const float* opw  = (const float*)d_in[16];
    const float* mw1  = (const float*)d_in[17];
    const float* mb1  = (const float*)d_in[18];
    const float* mw2  = (const float*)d_in[19];
    const float* mb2  = (const float*)d_in[20];
    const float* g1   = (const float*)d_in[21];
    const float* be1  = (const float*)d_in[22];
    const float* g2   = (const float*)d_in[23];
    const float* be2  = (const float*)d_in[24];
    const float* g3   = (const float*)d_in[25];
    const float* be3  = (const float*)d_in[26];

    float* outp = (float*)d_out;                       // [N*C] final out
    float* h2o  = outp + (size_t)NN * CC;              // [N*C] h2

    float* ws   = (float*)d_ws;
    float* xz   = ws;                                  // N*256 (later t2)
    float* agg  = xz + (size_t)NN * 256;               // N*128 (later Q/Hin, then p3)
    float* s2b  = agg + (size_t)NN * 128;              // t1 -> xs_post
    float* s3b  = s2b + (size_t)NN * 128;              // dt
    float* s4b  = s3b + (size_t)NN * 128;              // y2 -> out12
    float* xdbl = s4b + (size_t)NN * 128;              // N*48
    float* stats = xdbl + (size_t)NN * 48;             // 768 floats
    int*   cnt   = (int*)(stats + 768);                // N
    int*   baseA = cnt + NN;                           // N+1
    int*   cursor= baseA + NN + 1;                     // N
    int*   perm  = cursor + NN;                        // E
    float* SDT   = (float*)(perm + EE);                // G*NCHUNK*C = 131072
    float* p1 = outp;
    float* p2 = h2o;
    float* p3 = agg;
    float* t1 = s2b, *xsp = s2b;
    float* dtb_buf = s3b;
    float* y2 = s4b, *out12 = s4b;
    float* t2 = xz;
    float* Qbuf = agg;                                  // G*8*C*16 = 2M floats
    float* Hin  = agg + (size_t)GG * NCHUNK * CC * 16;  // G*8*C*16 = 2M floats

    hipMemsetAsync(cnt, 0, NN * sizeof(int), stream);
    hipMemsetAsync(stats, 0, 768 * sizeof(float), stream);

    // CSR build + gather
    hist_kernel<<<dim3(EE / 256), 256, 0, stream>>>(ei, cnt);
    scan32k_kernel<<<dim3(1), 1024, 0, stream>>>(cnt, baseA, cursor);
    permute_kernel<<<dim3(EE / 256), 256, 0, stream>>>(ei, cursor, perm);
    gather_kernel<<<dim3(NN / 2), 256, 0, stream>>>(perm, baseA, x, agg);

    // GIN MLP (agg consumed here; its buffer is then reused by the scan)
    gemm_kernel<128,128,true, true, true, false,false><<<dim3(256,1),256,0,stream>>>(
        x, 128, agg, eps, gw1, gb1, nullptr, t1, 128, nullptr, nullptr);
    gemm_kernel<128,128,false,false,true, true, true ><<<dim3(256,1),256,0,stream>>>(
        t1, 128, nullptr, nullptr, gw2, gb2, x, p1, 128, stats + 0, stats + 128);

    // Mamba: xz = x @ in_proj^T
    gemm_kernel<128,128,false,false,false,false,false><<<dim3(256,2),256,0,stream>>>(
        x, 128, nullptr, nullptr, ipw, nullptr, nullptr, xz, 256, nullptr, nullptr);
    conv_kernel<<<dim3((NN * CC) / 256), 256, 0, stream>>>(xz, cw, cb, xsp);
    gemm_kernel<128,40, false,false,false,false,false><<<dim3(256,1),256,0,stream>>>(
        xsp, 128, nullptr, nullptr, xpw, nullptr, nullptr, xdbl, 48, nullptr, nullptr);
    dt_kernel<<<dim3(NN / 2), 256, 0, stream>>>(xdbl, dtw, dtb, dtb_buf);

    // chunked selective scan (8 chunks of 32)
    scan_part_kernel<<<dim3(GG * 16), 256, 0, stream>>>(xdbl, dtb_buf, xsp, Alog, Qbuf, SDT);
    scan_combine_kernel<<<dim3(GG * 2048 / 256), 256, 0, stream>>>(Qbuf, SDT, Alog, Hin);
    scan_final_kernel<<<dim3(GG * 16), 256, 0, stream>>>(xdbl, dtb_buf, xsp, xz, Alog, Dp, Hin, y2);

    gemm_kernel<128,128,false,false,false,true, true ><<<dim3(256,1),256,0,stream>>>(
        y2, 128, nullptr, nullptr, opw, nullptr, x, p2, 128, stats + 256, stats + 384);

    // h1 = bn(p1), h2 = bn(p2) -> h2o ; out12 = h1+h2
    norm12_kernel<<<dim3(1024), 256, 0, stream>>>(p1, p2, stats, g1, be1, g2, be2, h2o, out12);

    // MLP
    gemm_kernel<128,128,false,true, true, false,false><<<dim3(256,2),256,0,stream>>>(
        out12, 128, nullptr, nullptr, mw1, mb1, nullptr, t2, 256, nullptr, nullptr);
    gemm_kernel<256,128,false,false,true, true, true ><<<dim3(256,1),256,0,stream>>>(
        t2, 256, nullptr, nullptr, mw2, mb2, out12, p3, 128, stats + 512, stats + 640);

    norm3_kernel<<<dim3(1024), 256, 0, stream>>>(p3, stats, g3, be3, outp);
}

// Round 4
// 431.388 us; speedup vs baseline: 1.5944x; 1.1092x over previous
//
#include <hip/hip_runtime.h>
#include <hip/hip_bf16.h>

#define NN 32768
#define GG 128
#define LL 256
#define CC 128
#define EE 524288
#define DSTATE 16
#define NCHUNK 8
#define TCH 32

typedef __attribute__((ext_vector_type(8))) short short8v;
typedef __attribute__((ext_vector_type(4))) short short4v;
typedef __attribute__((ext_vector_type(4))) float floatx4;

__device__ inline short f2bf(float f) {
    __hip_bfloat16 h = __float2bfloat16(f);
    short s; __builtin_memcpy(&s, &h, 2); return s;
}

// ---------------------------------------------------------------- edge histogram
__global__ __launch_bounds__(256) void hist_kernel(const int* __restrict__ ei,
    int* __restrict__ cnt)
{
    int e = blockIdx.x * 256 + threadIdx.x;
    atomicAdd(&cnt[ei[EE + e]], 1);
}

// ---------------------------------------------------------------- exclusive scan of 32768 counts
__global__ __launch_bounds__(1024) void scan32k_kernel(const int* __restrict__ cnt,
    int* __restrict__ base, int* __restrict__ cursor)
{
    __shared__ int part[1024];
    int tid = threadIdx.x;
    int local[32];
    int s = 0;
#pragma unroll
    for (int j = 0; j < 32; j++) { local[j] = cnt[tid * 32 + j]; s += local[j]; }
    part[tid] = s;
    __syncthreads();
    for (int off = 1; off < 1024; off <<= 1) {
        int v = (tid >= off) ? part[tid - off] : 0;
        __syncthreads();
        part[tid] += v;
        __syncthreads();
    }
    int run = part[tid] - s;
#pragma unroll
    for (int j = 0; j < 32; j++) {
        base[tid * 32 + j] = run;
        cursor[tid * 32 + j] = run;
        run += local[j];
    }
    if (tid == 0) base[NN] = EE;
}

// ---------------------------------------------------------------- permute srcs into dst-sorted order
__global__ __launch_bounds__(256) void permute_kernel(const int* __restrict__ ei,
    int* __restrict__ cursor, int* __restrict__ perm)
{
    int e = blockIdx.x * 256 + threadIdx.x;
    int dst = ei[EE + e];
    int pos = atomicAdd(&cursor[dst], 1);
    perm[pos] = ei[e];
}

// ---------------------------------------------------------------- gather-sum per node (CSR)
__global__ __launch_bounds__(256) void gather_kernel(const int* __restrict__ perm,
    const int* __restrict__ base, const float* __restrict__ x, float* __restrict__ agg)
{
    int node = blockIdx.x * 2 + (threadIdx.x >> 7);
    int c = threadIdx.x & 127;
    int b0 = base[node], b1 = base[node + 1];
    float s = 0.f, t = 0.f;
    int i = b0;
    for (; i + 1 < b1; i += 2) {
        int s1 = perm[i], s2 = perm[i + 1];
        s += x[(size_t)s1 * CC + c];
        t += x[(size_t)s2 * CC + c];
    }
    if (i < b1) s += x[(size_t)perm[i] * CC + c];
    agg[(size_t)node * CC + c] = s + t;
}

// ---------------------------------------------------------------- bf16 MFMA GEMM
// out[r][o] = sum_k A'[r][k]*W[o][k] (+bias)(relu)(+resid); optional BN stats.
// A' = APREP ? (1+eps)*A + A2 : A. 128x128 tile, 4 waves (2x2), 64x64/wave,
// 16x16x32 bf16 MFMA, fp32 accum. COLS_VALID = total valid out cols.
template<int K, int COLS_VALID, bool APREP, bool RELU, bool HAS_BIAS, bool HAS_RESID, bool STATS>
__global__ __launch_bounds__(256)
void mfma_gemm(const float* __restrict__ A, int lda,
               const float* __restrict__ A2, const float* __restrict__ epsp,
               const float* __restrict__ W,
               const float* __restrict__ bias,
               const float* __restrict__ resid,
               float* __restrict__ out, int ldo,
               float* ssum, float* ssq)
{
    __shared__ short Asb[128 * 72];   // [row][72] bf16, 144B row stride
    __shared__ short Wsb[128 * 72];   // [outcol][72]
    __shared__ float sred[256];
    const int tid = threadIdx.x;
    const int R0 = blockIdx.x * 128;
    const int by = blockIdx.y;
    const int lane = tid & 63;
    const int wv = tid >> 6;
    const int wr = wv >> 1, wc = wv & 1;
    const float e1 = APREP ? (1.0f + epsp[0]) : 0.0f;

    if (STATS) sred[tid] = 0.f;

    floatx4 acc[4][4];
#pragma unroll
    for (int m = 0; m < 4; m++)
#pragma unroll
        for (int n = 0; n < 4; n++)
#pragma unroll
            for (int r = 0; r < 4; r++) acc[m][n][r] = 0.f;

    for (int kc = 0; kc < K; kc += 64) {
        // stage A tile: 128 rows x 64 k (fp32 -> bf16)
#pragma unroll
        for (int t = 0; t < 8; t++) {
            int flat = tid + t * 256;          // 2048 float4s
            int row = flat >> 4, c4 = flat & 15;
            float4 v = *(const float4*)(A + (size_t)(R0 + row) * lda + kc + c4 * 4);
            if (APREP) {
                float4 u = *(const float4*)(A2 + (size_t)(R0 + row) * CC + kc + c4 * 4);
                v.x = fmaf(e1, v.x, u.x); v.y = fmaf(e1, v.y, u.y);
                v.z = fmaf(e1, v.z, u.z); v.w = fmaf(e1, v.w, u.w);
            }
            short4v s = { f2bf(v.x), f2bf(v.y), f2bf(v.z), f2bf(v.w) };
            *(short4v*)&Asb[row * 72 + c4 * 4] = s;
        }
        // stage W tile: 128 outcols x 64 k
#pragma unroll
        for (int t = 0; t < 8; t++) {
            int flat = tid + t * 256;
            int o_l = flat >> 4, c4 = flat & 15;
            int o_g = by * 128 + o_l;
            float4 v = make_float4(0.f, 0.f, 0.f, 0.f);
            if (o_g < COLS_VALID)
                v = *(const float4*)(W + (size_t)o_g * K + kc + c4 * 4);
            short4v s = { f2bf(v.x), f2bf(v.y), f2bf(v.z), f2bf(v.w) };
            *(short4v*)&Wsb[o_l * 72 + c4 * 4] = s;
        }
        __syncthreads();
#pragma unroll
        for (int kk = 0; kk < 2; kk++) {
            int ko = kk * 32 + (lane >> 4) * 8;
            short8v a[4], b[4];
#pragma unroll
            for (int m = 0; m < 4; m++)
                a[m] = *(const short8v*)&Asb[(wr * 64 + m * 16 + (lane & 15)) * 72 + ko];
#pragma unroll
            for (int n = 0; n < 4; n++)
                b[n] = *(const short8v*)&Wsb[(wc * 64 + n * 16 + (lane & 15)) * 72 + ko];
#pragma unroll
            for (int m = 0; m < 4; m++)
#pragma unroll
                for (int n = 0; n < 4; n++)
                    acc[m][n] = __builtin_amdgcn_mfma_f32_16x16x32_bf16(
                        a[m], b[n], acc[m][n], 0, 0, 0);
        }
        __syncthreads();
    }

    // epilogue: D[row][col]: col = wc*64+n*16+(lane&15), row = wr*64+m*16+(lane>>4)*4+r
    float sumn[4] = {0,0,0,0}, sqn[4] = {0,0,0,0};
    int   coll[4];
    float bcol[4];
#pragma unroll
    for (int n = 0; n < 4; n++) {
        coll[n] = by * 128 + wc * 64 + n * 16 + (lane & 15);
        bcol[n] = (HAS_BIAS && coll[n] < COLS_VALID) ? bias[coll[n]] : 0.f;
    }
#pragma unroll
    for (int m = 0; m < 4; m++) {
#pragma unroll
        for (int r = 0; r < 4; r++) {
            int row_g = R0 + wr * 64 + m * 16 + ((lane >> 4) << 2) + r;
#pragma unroll
            for (int n = 0; n < 4; n++) {
                float v = acc[m][n][r] + bcol[n];
                if (RELU) v = fmaxf(v, 0.f);
                if (HAS_RESID) v += resid[(size_t)row_g * CC + coll[n]];
                if (coll[n] < COLS_VALID)
                    out[(size_t)row_g * ldo + coll[n]] = v;
                if (STATS) { sumn[n] += v; sqn[n] += v * v; }
            }
        }
    }
    if (STATS) {
        __syncthreads();   // sred zero-init + compute done
#pragma unroll
        for (int n = 0; n < 4; n++) {
            int cl = wc * 64 + n * 16 + (lane & 15);   // by==0 for STATS GEMMs
            atomicAdd(&sred[cl], sumn[n]);
            atomicAdd(&sred[128 + cl], sqn[n]);
        }
        __syncthreads();
        if (tid < 128) {
            atomicAdd(&ssum[tid], sred[tid]);
            atomicAdd(&ssq[tid], sred[128 + tid]);
        }
    }
}

// ---------------------------------------------------------------- depthwise causal conv + silu
__global__ __launch_bounds__(256) void conv_kernel(const float* __restrict__ xz,
    const float* __restrict__ cw, const float* __restrict__ cb, float* __restrict__ xsp)
{
    int t = blockIdx.x * 256 + threadIdx.x;   // N*128
    int n = t >> 7, c = t & 127;
    int l = n & (LL - 1);
    float4 w = *(const float4*)(cw + c * 4);
    float v = cb[c];
    v = fmaf(xz[(size_t)n * 256 + c], w.w, v);
    if (l >= 1) v = fmaf(xz[(size_t)(n - 1) * 256 + c], w.z, v);
    if (l >= 2) v = fmaf(xz[(size_t)(n - 2) * 256 + c], w.y, v);
    if (l >= 3) v = fmaf(xz[(size_t)(n - 3) * 256 + c], w.x, v);
    xsp[t] = v / (1.f + __expf(-v));
}

// ---------------------------------------------------------------- dt = softplus(dtr @ dtw^T + b)
__global__ __launch_bounds__(256) void dt_kernel(const float* __restrict__ xdbl,
    const float* __restrict__ dtw, const float* __restrict__ dtb, float* __restrict__ dt)
{
    __shared__ float wT[8 * 128];
    __shared__ float rbuf[16];
    int tid = threadIdx.x;
    for (int i = tid; i < 1024; i += 256) {
        int d = i >> 3, r = i & 7;
        wT[r * 128 + d] = dtw[i];
    }
    int n0 = blockIdx.x * 2;
    if (tid < 16) rbuf[tid] = xdbl[(size_t)(n0 + (tid >> 3)) * 48 + (tid & 7)];
    __syncthreads();
    int rr = tid >> 7, d = tid & 127;
    float acc = dtb[d];
#pragma unroll
    for (int r = 0; r < 8; r++) acc = fmaf(rbuf[rr * 8 + r], wT[r * 128 + d], acc);
    float sp = (acc > 20.f) ? acc : log1pf(__expf(acc));
    dt[(size_t)(n0 + rr) * 128 + d] = sp;
}

// ---------------------------------------------------------------- scan phase A: per-chunk (sum_dt, q)
__global__ __launch_bounds__(256) void scan_part_kernel(const float* __restrict__ xdbl,
    const float* __restrict__ dt, const float* __restrict__ xsp,
    const float* __restrict__ Alog, float* __restrict__ Q, float* __restrict__ SDT)
{
    __shared__ float Bs[TCH * 16];
    __shared__ float dts[TCH * 64];
    __shared__ float xss[TCH * 64];
    int b = blockIdx.x;
    int g = b >> 4, ch = (b >> 3) & 1, chunk = b & 7;
    int t0 = chunk * TCH;
    int tid = threadIdx.x;
    for (int i = tid; i < TCH * 16; i += 256)
        Bs[i] = xdbl[(size_t)(g * LL + t0 + (i >> 4)) * 48 + 8 + (i & 15)];
    for (int i = tid; i < TCH * 64; i += 256) {
        int t = i >> 6, cl_ = i & 63;
        size_t row = (size_t)(g * LL + t0 + t) * CC + ch * 64 + cl_;
        dts[i] = dt[row];
        xss[i] = xsp[row];
    }
    int cl = tid >> 2, sp = tid & 3;
    int c = ch * 64 + cl;
    float ae[4];
#pragma unroll
    for (int j = 0; j < 4; j++) ae[j] = -__expf(Alog[c * 16 + sp * 4 + j]);
    __syncthreads();
    float q0 = 0, q1 = 0, q2 = 0, q3 = 0, sdt = 0;
    for (int t = TCH - 1; t >= 0; --t) {
        float dtv = dts[t * 64 + cl];
        float xv  = xss[t * 64 + cl];
        float u = dtv * xv;
        const float* bs = Bs + t * 16 + sp * 4;
        q0 = fmaf(__expf(ae[0] * sdt) * u, bs[0], q0);
        q1 = fmaf(__expf(ae[1] * sdt) * u, bs[1], q1);
        q2 = fmaf(__expf(ae[2] * sdt) * u, bs[2], q2);
        q3 = fmaf(__expf(ae[3] * sdt) * u, bs[3], q3);
        sdt += dtv;
    }
    float4* qp = (float4*)(Q + (((size_t)g * NCHUNK + chunk) * CC + c) * 16 + sp * 4);
    *qp = make_float4(q0, q1, q2, q3);
    if (sp == 0) SDT[((size_t)g * NCHUNK + chunk) * CC + c] = sdt;
}

// ---------------------------------------------------------------- scan phase B: combine chunk states
__global__ __launch_bounds__(256) void scan_combine_kernel(const float* __restrict__ Q,
    const float* __restrict__ SDT, const float* __restrict__ Alog, float* __restrict__ Hin)
{
    int idx = blockIdx.x * 256 + threadIdx.x;   // g*2048 + c*16 + s
    int g = idx >> 11;
    int cs = idx & 2047;
    float ae = -__expf(Alog[cs]);
    float h = 0.f;
#pragma unroll
    for (int k = 0; k < NCHUNK; k++) {
        size_t o = ((size_t)g * NCHUNK + k);
        Hin[o * 2048 + cs] = h;
        float sdt = SDT[o * CC + (cs >> 4)];
        h = fmaf(__expf(ae * sdt), h, Q[o * 2048 + cs]);
    }
}

// ---------------------------------------------------------------- scan phase C: forward with init + y
__global__ __launch_bounds__(256) void scan_final_kernel(const float* __restrict__ xdbl,
    const float* __restrict__ dt, const float* __restrict__ xsp,
    const float* __restrict__ xz, const float* __restrict__ Alog,
    const float* __restrict__ Dp, const float* __restrict__ Hin, float* __restrict__ y2)
{
    __shared__ float BC[TCH * 32];
    __shared__ float dts[TCH * 64];
    __shared__ float xss[TCH * 64];
    int b = blockIdx.x;
    int g = b >> 4, ch = (b >> 3) & 1, chunk = b & 7;
    int t0 = chunk * TCH;
    int tid = threadIdx.x;
    for (int i = tid; i < TCH * 32; i += 256)
        BC[i] = xdbl[(size_t)(g * LL + t0 + (i >> 5)) * 48 + 8 + (i & 31)];
    for (int i = tid; i < TCH * 64; i += 256) {
        int t = i >> 6, cl_ = i & 63;
        size_t row = (size_t)(g * LL + t0 + t) * CC + ch * 64 + cl_;
        dts[i] = dt[row];
        xss[i] = xsp[row];
    }
    int cl = tid >> 2, sp = tid & 3;
    int c = ch * 64 + cl;
    float ae[4];
#pragma unroll
    for (int j = 0; j < 4; j++) ae[j] = -__expf(Alog[c * 16 + sp * 4 + j]);
    float dpc = Dp[c];
    float4 hv = *(const float4*)(Hin + ((size_t)g * NCHUNK + chunk) * 2048 + c * 16 + sp * 4);
    float h0 = hv.x, h1 = hv.y, h2 = hv.z, h3 = hv.w;
    __syncthreads();
    const float* zg = xz + ((size_t)g * LL + t0) * 256 + 128 + c;
    float* yg = y2 + ((size_t)g * LL + t0) * CC + c;
    for (int t = 0; t < TCH; t++) {
        float dtv = dts[t * 64 + cl];
        float xv  = xss[t * 64 + cl];
        float u = dtv * xv;
        const float* bc = BC + t * 32 + sp * 4;
        h0 = fmaf(__expf(dtv * ae[0]), h0, u * bc[0]);
        h1 = fmaf(__expf(dtv * ae[1]), h1, u * bc[1]);
        h2 = fmaf(__expf(dtv * ae[2]), h2, u * bc[2]);
        h3 = fmaf(__expf(dtv * ae[3]), h3, u * bc[3]);
        float y = h0 * bc[16] + h1 * bc[17] + h2 * bc[18] + h3 * bc[19];
        y += __shfl_xor(y, 1);
        y += __shfl_xor(y, 2);
        if (sp == 0) {
            float zv = zg[t * 256];
            float yo = fmaf(dpc, xv, y);
            yg[t * 128] = yo * (zv / (1.f + __expf(-zv)));
        }
    }
}

// ---------------------------------------------------------------- norm (h1,h2) + combine
__global__ __launch_bounds__(256) void norm12_kernel(const float* p1,
    const float* p2, const float* stats,
    const float* g1, const float* be1, const float* g2, const float* be2,
    float* h2out, float* out12)
{
    __shared__ float sc[512];
    int tid = threadIdx.x;
    if (tid < 128) {
        int c = tid;
        const float inv = 1.0f / NN;
        float m1 = stats[c] * inv;
        float v1 = fmaxf(stats[128 + c] * inv - m1 * m1, 0.f);
        float i1 = rsqrtf(v1 + 1e-5f);
        sc[c] = g1[c] * i1; sc[128 + c] = be1[c] - m1 * g1[c] * i1;
        float m2 = stats[256 + c] * inv;
        float v2 = fmaxf(stats[384 + c] * inv - m2 * m2, 0.f);
        float i2 = rsqrtf(v2 + 1e-5f);
        sc[256 + c] = g2[c] * i2; sc[384 + c] = be2[c] - m2 * g2[c] * i2;
    }
    __syncthreads();
    int c = tid & 127;
    float s1 = sc[c], t1 = sc[128 + c], s2 = sc[256 + c], t2 = sc[384 + c];
    for (int i = tid; i < 4096; i += 256) {
        size_t idx = (size_t)blockIdx.x * 4096 + i;
        float a = fmaf(p1[idx], s1, t1);
        float b = fmaf(p2[idx], s2, t2);
        h2out[idx] = b;
        out12[idx] = a + b;
    }
}

// ---------------------------------------------------------------- final norm
__global__ __launch_bounds__(256) void norm3_kernel(const float* p3,
    const float* stats, const float* g3, const float* be3, float* outp)
{
    __shared__ float sc[256];
    int tid = threadIdx.x;
    if (tid < 128) {
        int c = tid;
        const float inv = 1.0f / NN;
        float m = stats[512 + c] * inv;
        float v = fmaxf(stats[640 + c] * inv - m * m, 0.f);
        float iv = rsqrtf(v + 1e-5f);
        sc[c] = g3[c] * iv; sc[128 + c] = be3[c] - m * g3[c] * iv;
    }
    __syncthreads();
    int c = tid & 127;
    float s = sc[c], t = sc[128 + c];
    for (int i = tid; i < 4096; i += 256) {
        size_t idx = (size_t)blockIdx.x * 4096 + i;
        outp[idx] = fmaf(p3[idx], s, t);
    }
}

extern "C" void kernel_launch(void* const* d_in, const int* in_sizes, int n_in,
                              void* d_out, int out_size, void* d_ws, size_t ws_size,
                              hipStream_t stream)
{
    (void)in_sizes; (void)n_in; (void)out_size; (void)ws_size;
    const float* x    = (const float*)d_in[0];
    const int*   ei   = (const int*)d_in[1];
    const float* eps  = (const float*)d_in[3];
    const float* gw1  = (const float*)d_in[4];
    const float* gb1  = (const float*)d_in[5];
    const float* gw2  = (const float*)d_in[6];
    const float* gb2  = (const float*)d_in[7];
    const float* ipw  = (const float*)d_in[8];
    const float* cw   = (const float*)d_in[9];
    const float* cb   = (const float*)d_in[10];
    const float* xpw  = (const float*)d_in[11];
    const float* dtw  = (const float*)d_in[12];
    const float* dtb  = (const float*)d_in[13];
    const float* Alog = (const float*)d_in[14];
    const float* Dp   = (const float*)d_in[15];
    const float* opw  = (const float*)d_in[16];
    const float* mw1  = (const float*)d_in[17];
    const float* mb1  = (const float*)d_in[18];
    const float* mw2  = (const float*)d_in[19];
    const float* mb2  = (const float*)d_in[20];
    const float* g1   = (const float*)d_in[21];
    const float* be1  = (const float*)d_in[22];
    const float* g2   = (const float*)d_in[23];
    const float* be2  = (const float*)d_in[24];
    const float* g3   = (const float*)d_in[25];
    const float* be3  = (const float*)d_in[26];

    float* outp = (float*)d_out;                       // [N*C] final out
    float* h2o  = outp + (size_t)NN * CC;              // [N*C] h2

    float* ws   = (float*)d_ws;
    float* xz   = ws;                                  // N*256 (later t2)
    float* agg  = xz + (size_t)NN * 256;               // N*128 (later Q/Hin, then p3)
    float* s2b  = agg + (size_t)NN * 128;              // t1 -> xs_post
    float* s3b  = s2b + (size_t)NN * 128;              // dt
    float* s4b  = s3b + (size_t)NN * 128;              // y2 -> out12
    float* xdbl = s4b + (size_t)NN * 128;              // N*48
    float* stats = xdbl + (size_t)NN * 48;             // 768 floats
    int*   cnt   = (int*)(stats + 768);                // N
    int*   baseA = cnt + NN;                           // N+1
    int*   cursor= baseA + NN + 1;                     // N
    int*   perm  = cursor + NN;                        // E
    float* SDT   = (float*)(perm + EE);                // G*NCHUNK*C
    float* p1 = outp;
    float* p2 = h2o;
    float* p3 = agg;
    float* t1 = s2b, *xsp = s2b;
    float* dtb_buf = s3b;
    float* y2 = s4b, *out12 = s4b;
    float* t2 = xz;
    float* Qbuf = agg;                                  // G*8*C*16
    float* Hin  = agg + (size_t)GG * NCHUNK * CC * 16;  // G*8*C*16

    hipMemsetAsync(cnt, 0, NN * sizeof(int), stream);
    hipMemsetAsync(stats, 0, 768 * sizeof(float), stream);

    // CSR build + gather
    hist_kernel<<<dim3(EE / 256), 256, 0, stream>>>(ei, cnt);
    scan32k_kernel<<<dim3(1), 1024, 0, stream>>>(cnt, baseA, cursor);
    permute_kernel<<<dim3(EE / 256), 256, 0, stream>>>(ei, cursor, perm);
    gather_kernel<<<dim3(NN / 2), 256, 0, stream>>>(perm, baseA, x, agg);

    // GIN MLP
    mfma_gemm<128,128,true, true, true, false,false><<<dim3(256,1),256,0,stream>>>(
        x, 128, agg, eps, gw1, gb1, nullptr, t1, 128, nullptr, nullptr);
    mfma_gemm<128,128,false,false,true, true, true ><<<dim3(256,1),256,0,stream>>>(
        t1, 128, nullptr, nullptr, gw2, gb2, x, p1, 128, stats + 0, stats + 128);

    // Mamba: xz = x @ in_proj^T
    mfma_gemm<128,256,false,false,false,false,false><<<dim3(256,2),256,0,stream>>>(
        x, 128, nullptr, nullptr, ipw, nullptr, nullptr, xz, 256, nullptr, nullptr);
    conv_kernel<<<dim3((NN * CC) / 256), 256, 0, stream>>>(xz, cw, cb, xsp);
    mfma_gemm<128,40, false,false,false,false,false><<<dim3(256,1),256,0,stream>>>(
        xsp, 128, nullptr, nullptr, xpw, nullptr, nullptr, xdbl, 48, nullptr, nullptr);
    dt_kernel<<<dim3(NN / 2), 256, 0, stream>>>(xdbl, dtw, dtb, dtb_buf);

    // chunked selective scan (8 chunks of 32)
    scan_part_kernel<<<dim3(GG * 16), 256, 0, stream>>>(xdbl, dtb_buf, xsp, Alog, Qbuf, SDT);
    scan_combine_kernel<<<dim3(GG * 2048 / 256), 256, 0, stream>>>(Qbuf, SDT, Alog, Hin);
    scan_final_kernel<<<dim3(GG * 16), 256, 0, stream>>>(xdbl, dtb_buf, xsp, xz, Alog, Dp, Hin, y2);

    mfma_gemm<128,128,false,false,false,true, true ><<<dim3(256,1),256,0,stream>>>(
        y2, 128, nullptr, nullptr, opw, nullptr, x, p2, 128, stats + 256, stats + 384);

    // h1 = bn(p1), h2 = bn(p2) -> h2o ; out12 = h1+h2
    norm12_kernel<<<dim3(1024), 256, 0, stream>>>(p1, p2, stats, g1, be1, g2, be2, h2o, out12);

    // MLP
    mfma_gemm<128,256,false,true, true, false,false><<<dim3(256,2),256,0,stream>>>(
        out12, 128, nullptr, nullptr, mw1, mb1, nullptr, t2, 256, nullptr, nullptr);
    mfma_gemm<256,128,false,false,true, true, true ><<<dim3(256,1),256,0,stream>>>(
        t2, 256, nullptr, nullptr, mw2, mb2, out12, p3, 128, stats + 512, stats + 640);

    norm3_kernel<<<dim3(1024), 256, 0, stream>>>(p3, stats, g3, be3, outp);
}

// Round 5
// 403.297 us; speedup vs baseline: 1.7054x; 1.0697x over previous
//
#include <hip/hip_runtime.h>
#include <hip/hip_bf16.h>

#define NN 32768
#define GG 128
#define LL 256
#define CC 128
#define EE 524288
#define NCHUNK 8
#define TCH 32

typedef __attribute__((ext_vector_type(8))) short short8v;
typedef __attribute__((ext_vector_type(4))) short short4v;
typedef __attribute__((ext_vector_type(4))) float floatx4;

__device__ inline short f2bf(float f) {
    __hip_bfloat16 h = __float2bfloat16(f);
    short s; __builtin_memcpy(&s, &h, 2); return s;
}
__device__ inline float b2f(unsigned short u) {
    unsigned v = ((unsigned)u) << 16; float f; __builtin_memcpy(&f, &v, 4); return f;
}

// ---------------------------------------------------------------- x -> bf16 copy
__global__ __launch_bounds__(256) void xb_kernel(const float* __restrict__ x,
    unsigned short* __restrict__ xb)
{
    size_t i = (size_t)blockIdx.x * 256 + threadIdx.x;   // NN*CC/8
    float4 a = *(const float4*)(x + i * 8);
    float4 b = *(const float4*)(x + i * 8 + 4);
    short8v s = { f2bf(a.x), f2bf(a.y), f2bf(a.z), f2bf(a.w),
                  f2bf(b.x), f2bf(b.y), f2bf(b.z), f2bf(b.w) };
    *(short8v*)(xb + i * 8) = s;
}

// ---------------------------------------------------------------- Wdt = dtw @ xpw[:8]
__global__ __launch_bounds__(256) void wdt_kernel(const float* __restrict__ dtw,
    const float* __restrict__ xpw, float* __restrict__ Wdt)
{
    int i = blockIdx.x * 256 + threadIdx.x;   // 16384
    int d = i >> 7, c = i & 127;
    float s = 0.f;
#pragma unroll
    for (int r = 0; r < 8; r++) s = fmaf(dtw[d * 8 + r], xpw[r * 128 + c], s);
    Wdt[i] = s;
}

// ---------------------------------------------------------------- edge histogram
__global__ __launch_bounds__(256) void hist_kernel(const int* __restrict__ ei,
    int* __restrict__ cnt)
{
    int e = blockIdx.x * 256 + threadIdx.x;
    atomicAdd(&cnt[ei[EE + e]], 1);
}

// ---------------------------------------------------------------- exclusive scan of 32768 counts
__global__ __launch_bounds__(1024) void scan32k_kernel(const int* __restrict__ cnt,
    int* __restrict__ base, int* __restrict__ cursor)
{
    __shared__ int part[1024];
    int tid = threadIdx.x;
    int local[32];
    int s = 0;
#pragma unroll
    for (int j = 0; j < 32; j++) { local[j] = cnt[tid * 32 + j]; s += local[j]; }
    part[tid] = s;
    __syncthreads();
    for (int off = 1; off < 1024; off <<= 1) {
        int v = (tid >= off) ? part[tid - off] : 0;
        __syncthreads();
        part[tid] += v;
        __syncthreads();
    }
    int run = part[tid] - s;
#pragma unroll
    for (int j = 0; j < 32; j++) {
        base[tid * 32 + j] = run;
        cursor[tid * 32 + j] = run;
        run += local[j];
    }
    if (tid == 0) base[NN] = EE;
}

// ---------------------------------------------------------------- permute srcs into dst-sorted order
__global__ __launch_bounds__(256) void permute_kernel(const int* __restrict__ ei,
    int* __restrict__ cursor, int* __restrict__ perm)
{
    int e = blockIdx.x * 256 + threadIdx.x;
    int dst = ei[EE + e];
    int pos = atomicAdd(&cursor[dst], 1);
    perm[pos] = ei[e];
}

// ---------------------------------------------------------------- gather-sum + (1+eps)x, bf16 in/out
__global__ __launch_bounds__(256) void gather_kernel(const int* __restrict__ perm,
    const int* __restrict__ base, const unsigned short* __restrict__ xb,
    const float* __restrict__ epsp, unsigned short* __restrict__ hgin)
{
    int node = blockIdx.x * 8 + (threadIdx.x >> 5);
    int c4 = threadIdx.x & 31;
    int b0 = base[node], b1 = base[node + 1];
    float s0 = 0, s1 = 0, s2 = 0, s3 = 0;
    float t0 = 0, t1 = 0, t2 = 0, t3 = 0;
    int i = b0;
    for (; i + 1 < b1; i += 2) {
        short4v v0 = *(const short4v*)(xb + (size_t)perm[i] * CC + c4 * 4);
        short4v v1 = *(const short4v*)(xb + (size_t)perm[i + 1] * CC + c4 * 4);
        s0 += b2f((unsigned short)v0[0]); s1 += b2f((unsigned short)v0[1]);
        s2 += b2f((unsigned short)v0[2]); s3 += b2f((unsigned short)v0[3]);
        t0 += b2f((unsigned short)v1[0]); t1 += b2f((unsigned short)v1[1]);
        t2 += b2f((unsigned short)v1[2]); t3 += b2f((unsigned short)v1[3]);
    }
    if (i < b1) {
        short4v v0 = *(const short4v*)(xb + (size_t)perm[i] * CC + c4 * 4);
        s0 += b2f((unsigned short)v0[0]); s1 += b2f((unsigned short)v0[1]);
        s2 += b2f((unsigned short)v0[2]); s3 += b2f((unsigned short)v0[3]);
    }
    float e1 = 1.f + epsp[0];
    short4v xv = *(const short4v*)(xb + (size_t)node * CC + c4 * 4);
    float r0 = fmaf(e1, b2f((unsigned short)xv[0]), s0 + t0);
    float r1 = fmaf(e1, b2f((unsigned short)xv[1]), s1 + t1);
    float r2 = fmaf(e1, b2f((unsigned short)xv[2]), s2 + t2);
    float r3 = fmaf(e1, b2f((unsigned short)xv[3]), s3 + t3);
    short4v o = { f2bf(r0), f2bf(r1), f2bf(r2), f2bf(r3) };
    *(short4v*)(hgin + (size_t)node * CC + c4 * 4) = o;
}

// ---------------------------------------------------------------- bf16-A MFMA GEMM
// out[r][o] = sum_k A[r][k]*W[o][k] (+bias)(act)(+resid); optional BN stats.
// A bf16 in memory. 64x128 tile, 4 waves (2x2), wave 32x64, 16x16x32 MFMA.
// ACT: 0 none, 1 relu, 2 softplus. RESID: 0 none, 1 bf16, 2 fp32.
// OUTM bit0: fp32 store, bit1: bf16 store. by selects (out,outb) vs (out_b1,outb_b1).
template<int K, int COLS_VALID, int ACT, bool HAS_BIAS, int RESID, bool STATS, int OUTM>
__global__ __launch_bounds__(256)
void mfma_gemm(const unsigned short* __restrict__ A, int lda,
               const float* __restrict__ W,
               const float* __restrict__ bias,
               const void* __restrict__ resid,
               float* out, float* out_b1,
               unsigned short* outb, unsigned short* outb_b1, int ldo,
               float* ssum, float* ssq)
{
    __shared__ short Asb[64 * 72];
    __shared__ short Wsb[128 * 72];
    __shared__ float sred[256];
    const int tid = threadIdx.x;
    const int R0 = blockIdx.x * 64;
    const int by = blockIdx.y;
    const int lane = tid & 63;
    const int wv = tid >> 6;
    const int wr = wv >> 1, wc = wv & 1;

    if (STATS) sred[tid] = 0.f;

    floatx4 acc[2][4];
#pragma unroll
    for (int m = 0; m < 2; m++)
#pragma unroll
        for (int n = 0; n < 4; n++)
#pragma unroll
            for (int r = 0; r < 4; r++) acc[m][n][r] = 0.f;

    for (int kc = 0; kc < K; kc += 64) {
        // stage A: 64 rows x 64 k bf16 (512 x 16B)
#pragma unroll
        for (int t = 0; t < 2; t++) {
            int flat = tid + t * 256;
            int row = flat >> 3, seg = flat & 7;
            *(short8v*)&Asb[row * 72 + seg * 8] =
                *(const short8v*)(A + (size_t)(R0 + row) * lda + kc + seg * 8);
        }
        // stage W: 128 outcols x 64 k fp32 -> bf16
#pragma unroll
        for (int t = 0; t < 8; t++) {
            int flat = tid + t * 256;
            int o_l = flat >> 4, c4 = flat & 15;
            int o_g = by * 128 + o_l;
            float4 v = make_float4(0.f, 0.f, 0.f, 0.f);
            if (o_g < COLS_VALID)
                v = *(const float4*)(W + (size_t)o_g * K + kc + c4 * 4);
            short4v s = { f2bf(v.x), f2bf(v.y), f2bf(v.z), f2bf(v.w) };
            *(short4v*)&Wsb[o_l * 72 + c4 * 4] = s;
        }
        __syncthreads();
#pragma unroll
        for (int kk = 0; kk < 2; kk++) {
            int ko = kk * 32 + (lane >> 4) * 8;
            short8v a[2], b[4];
#pragma unroll
            for (int m = 0; m < 2; m++)
                a[m] = *(const short8v*)&Asb[(wr * 32 + m * 16 + (lane & 15)) * 72 + ko];
#pragma unroll
            for (int n = 0; n < 4; n++)
                b[n] = *(const short8v*)&Wsb[(wc * 64 + n * 16 + (lane & 15)) * 72 + ko];
#pragma unroll
            for (int m = 0; m < 2; m++)
#pragma unroll
                for (int n = 0; n < 4; n++)
                    acc[m][n] = __builtin_amdgcn_mfma_f32_16x16x32_bf16(
                        a[m], b[n], acc[m][n], 0, 0, 0);
        }
        __syncthreads();
    }

    float sumn[4] = {0, 0, 0, 0}, sqn[4] = {0, 0, 0, 0};
    int coll[4];
    float bcol[4];
#pragma unroll
    for (int n = 0; n < 4; n++) {
        coll[n] = by * 128 + wc * 64 + n * 16 + (lane & 15);
        bcol[n] = (HAS_BIAS && coll[n] < COLS_VALID) ? bias[coll[n]] : 0.f;
    }
    float* op = by ? out_b1 : out;
    unsigned short* opb = by ? outb_b1 : outb;
#pragma unroll
    for (int m = 0; m < 2; m++) {
#pragma unroll
        for (int r = 0; r < 4; r++) {
            int row_g = R0 + wr * 32 + m * 16 + ((lane >> 4) << 2) + r;
#pragma unroll
            for (int n = 0; n < 4; n++) {
                float v = acc[m][n][r] + bcol[n];
                if (ACT == 1) v = fmaxf(v, 0.f);
                if (ACT == 2) v = (v > 20.f) ? v : log1pf(__expf(v));
                if (RESID == 1)
                    v += b2f(((const unsigned short*)resid)[(size_t)row_g * CC + coll[n]]);
                if (RESID == 2)
                    v += ((const float*)resid)[(size_t)row_g * CC + coll[n]];
                if (coll[n] < COLS_VALID) {
                    int cl_ = coll[n] - (by ? 128 : 0);
                    if (OUTM & 1) op[(size_t)row_g * ldo + cl_] = v;
                    if (OUTM & 2) opb[(size_t)row_g * ldo + cl_] = (unsigned short)f2bf(v);
                }
                if (STATS) { sumn[n] += v; sqn[n] += v * v; }
            }
        }
    }
    if (STATS) {
#pragma unroll
        for (int n = 0; n < 4; n++) {
            int cl = wc * 64 + n * 16 + (lane & 15);
            atomicAdd(&sred[cl], sumn[n]);
            atomicAdd(&sred[128 + cl], sqn[n]);
        }
        __syncthreads();
        if (tid < 128) {
            atomicAdd(&ssum[tid], sred[tid]);
            atomicAdd(&ssq[tid], sred[128 + tid]);
        }
    }
}

// ---------------------------------------------------------------- depthwise causal conv + silu
__global__ __launch_bounds__(256) void conv_kernel(const float* __restrict__ xs_pre,
    const float* __restrict__ cw, const float* __restrict__ cb,
    unsigned short* __restrict__ xsb)
{
    int t = blockIdx.x * 256 + threadIdx.x;   // NN*32
    int n = t >> 5, c4 = t & 31;
    int l = n & (LL - 1);
    const float* bp = xs_pre + (size_t)n * CC + c4 * 4;
    float4 x0 = *(const float4*)bp;
    float4 x1 = (l >= 1) ? *(const float4*)(bp - CC) : make_float4(0, 0, 0, 0);
    float4 x2 = (l >= 2) ? *(const float4*)(bp - 2 * CC) : make_float4(0, 0, 0, 0);
    float4 x3 = (l >= 3) ? *(const float4*)(bp - 3 * CC) : make_float4(0, 0, 0, 0);
    float4 cbv = *(const float4*)(cb + c4 * 4);
    unsigned short o[4];
#pragma unroll
    for (int j = 0; j < 4; j++) {
        float4 w = *(const float4*)(cw + (c4 * 4 + j) * 4);
        float v = (&cbv.x)[j];
        v = fmaf((&x0.x)[j], w.w, v);
        v = fmaf((&x1.x)[j], w.z, v);
        v = fmaf((&x2.x)[j], w.y, v);
        v = fmaf((&x3.x)[j], w.x, v);
        v = v / (1.f + __expf(-v));
        o[j] = (unsigned short)f2bf(v);
    }
    short4v s = { (short)o[0], (short)o[1], (short)o[2], (short)o[3] };
    *(short4v*)(xsb + (size_t)t * 4) = s;
}

// ---------------------------------------------------------------- scan phase A: per-chunk (sum_dt, q)
__global__ __launch_bounds__(256) void scan_part_kernel(const float* __restrict__ BCp,
    const unsigned short* __restrict__ dtp, const unsigned short* __restrict__ xsp_,
    const float* __restrict__ Alog, float* __restrict__ Q, float* __restrict__ SDT)
{
    __shared__ float Bs[TCH * 16];
    __shared__ float dts[TCH * 64];
    __shared__ float xss[TCH * 64];
    int b = blockIdx.x;
    int g = b >> 4, ch = (b >> 3) & 1, chunk = b & 7;
    int t0 = chunk * TCH;
    int tid = threadIdx.x;
    for (int i4 = tid; i4 < TCH * 4; i4 += 256) {
        int t = i4 >> 2, j4 = i4 & 3;
        *(float4*)&Bs[t * 16 + j4 * 4] =
            *(const float4*)(BCp + (size_t)(g * LL + t0 + t) * 32 + j4 * 4);
    }
    for (int i4 = tid; i4 < TCH * 16; i4 += 256) {
        int t = i4 >> 4, c4 = i4 & 15;
        size_t off = (size_t)(g * LL + t0 + t) * CC + ch * 64 + c4 * 4;
        short4v dv = *(const short4v*)(dtp + off);
        short4v xv = *(const short4v*)(xsp_ + off);
        *(float4*)&dts[t * 64 + c4 * 4] = make_float4(
            b2f((unsigned short)dv[0]), b2f((unsigned short)dv[1]),
            b2f((unsigned short)dv[2]), b2f((unsigned short)dv[3]));
        *(float4*)&xss[t * 64 + c4 * 4] = make_float4(
            b2f((unsigned short)xv[0]), b2f((unsigned short)xv[1]),
            b2f((unsigned short)xv[2]), b2f((unsigned short)xv[3]));
    }
    int cl = tid >> 2, sp = tid & 3;
    int c = ch * 64 + cl;
    float ae[4];
#pragma unroll
    for (int j = 0; j < 4; j++) ae[j] = -__expf(Alog[c * 16 + sp * 4 + j]);
    __syncthreads();
    float q0 = 0, q1 = 0, q2 = 0, q3 = 0, sdt = 0;
    for (int t = TCH - 1; t >= 0; --t) {
        float dtv = dts[t * 64 + cl];
        float xv  = xss[t * 64 + cl];
        float u = dtv * xv;
        const float* bs = Bs + t * 16 + sp * 4;
        q0 = fmaf(__expf(ae[0] * sdt) * u, bs[0], q0);
        q1 = fmaf(__expf(ae[1] * sdt) * u, bs[1], q1);
        q2 = fmaf(__expf(ae[2] * sdt) * u, bs[2], q2);
        q3 = fmaf(__expf(ae[3] * sdt) * u, bs[3], q3);
        sdt += dtv;
    }
    float4* qp = (float4*)(Q + (((size_t)g * NCHUNK + chunk) * CC + c) * 16 + sp * 4);
    *qp = make_float4(q0, q1, q2, q3);
    if (sp == 0) SDT[((size_t)g * NCHUNK + chunk) * CC + c] = sdt;
}

// ---------------------------------------------------------------- scan phase B: combine chunk states
__global__ __launch_bounds__(256) void scan_combine_kernel(const float* __restrict__ Q,
    const float* __restrict__ SDT, const float* __restrict__ Alog, float* __restrict__ Hin)
{
    int idx = blockIdx.x * 256 + threadIdx.x;   // g*2048 + c*16 + s
    int g = idx >> 11;
    int cs = idx & 2047;
    float ae = -__expf(Alog[cs]);
    float h = 0.f;
#pragma unroll
    for (int k = 0; k < NCHUNK; k++) {
        size_t o = ((size_t)g * NCHUNK + k);
        Hin[o * 2048 + cs] = h;
        float sdt = SDT[o * CC + (cs >> 4)];
        h = fmaf(__expf(ae * sdt), h, Q[o * 2048 + cs]);
    }
}

// ---------------------------------------------------------------- scan phase C: forward with init + y
__global__ __launch_bounds__(256) void scan_final_kernel(const float* __restrict__ BCp,
    const unsigned short* __restrict__ dtp, const unsigned short* __restrict__ xsp_,
    const float* __restrict__ zbuf, const float* __restrict__ Alog,
    const float* __restrict__ Dp, const float* __restrict__ Hin,
    unsigned short* __restrict__ y2b)
{
    __shared__ float BCs[TCH * 32];
    __shared__ float dts[TCH * 64];
    __shared__ float xss[TCH * 64];
    int b = blockIdx.x;
    int g = b >> 4, ch = (b >> 3) & 1, chunk = b & 7;
    int t0 = chunk * TCH;
    int tid = threadIdx.x;
    for (int i4 = tid; i4 < TCH * 8; i4 += 256) {
        int t = i4 >> 3, j4 = i4 & 7;
        *(float4*)&BCs[t * 32 + j4 * 4] =
            *(const float4*)(BCp + (size_t)(g * LL + t0 + t) * 32 + j4 * 4);
    }
    for (int i4 = tid; i4 < TCH * 16; i4 += 256) {
        int t = i4 >> 4, c4 = i4 & 15;
        size_t off = (size_t)(g * LL + t0 + t) * CC + ch * 64 + c4 * 4;
        short4v dv = *(const short4v*)(dtp + off);
        short4v xv = *(const short4v*)(xsp_ + off);
        *(float4*)&dts[t * 64 + c4 * 4] = make_float4(
            b2f((unsigned short)dv[0]), b2f((unsigned short)dv[1]),
            b2f((unsigned short)dv[2]), b2f((unsigned short)dv[3]));
        *(float4*)&xss[t * 64 + c4 * 4] = make_float4(
            b2f((unsigned short)xv[0]), b2f((unsigned short)xv[1]),
            b2f((unsigned short)xv[2]), b2f((unsigned short)xv[3]));
    }
    int cl = tid >> 2, sp = tid & 3;
    int c = ch * 64 + cl;
    float ae[4];
#pragma unroll
    for (int j = 0; j < 4; j++) ae[j] = -__expf(Alog[c * 16 + sp * 4 + j]);
    float dpc = Dp[c];
    float4 hv = *(const float4*)(Hin + ((size_t)g * NCHUNK + chunk) * 2048 + c * 16 + sp * 4);
    float h0 = hv.x, h1 = hv.y, h2 = hv.z, h3 = hv.w;
    __syncthreads();
    const float* zg = zbuf + (size_t)(g * LL + t0) * CC + c;
    unsigned short* yg = y2b + (size_t)(g * LL + t0) * CC + c;
    for (int t = 0; t < TCH; t++) {
        float dtv = dts[t * 64 + cl];
        float xv  = xss[t * 64 + cl];
        float u = dtv * xv;
        const float* bc = BCs + t * 32 + sp * 4;
        h0 = fmaf(__expf(dtv * ae[0]), h0, u * bc[0]);
        h1 = fmaf(__expf(dtv * ae[1]), h1, u * bc[1]);
        h2 = fmaf(__expf(dtv * ae[2]), h2, u * bc[2]);
        h3 = fmaf(__expf(dtv * ae[3]), h3, u * bc[3]);
        float y = h0 * bc[16] + h1 * bc[17] + h2 * bc[18] + h3 * bc[19];
        y += __shfl_xor(y, 1);
        y += __shfl_xor(y, 2);
        if (sp == 0) {
            float zv = zg[t * CC];
            float yo = fmaf(dpc, xv, y);
            yg[t * CC] = (unsigned short)f2bf(yo * (zv / (1.f + __expf(-zv))));
        }
    }
}

// ---------------------------------------------------------------- norm (h1,h2) + combine
__global__ __launch_bounds__(256) void norm12_kernel(const float* __restrict__ p1,
    const float* __restrict__ p2, const float* __restrict__ stats,
    const float* g1, const float* be1, const float* g2, const float* be2,
    float* __restrict__ h2out, float* __restrict__ out12,
    unsigned short* __restrict__ out12b)
{
    __shared__ float sc[512];
    int tid = threadIdx.x;
    if (tid < 128) {
        int c = tid;
        const float inv = 1.0f / NN;
        float m1 = stats[c] * inv;
        float v1 = fmaxf(stats[128 + c] * inv - m1 * m1, 0.f);
        float i1 = rsqrtf(v1 + 1e-5f);
        sc[c] = g1[c] * i1; sc[128 + c] = be1[c] - m1 * g1[c] * i1;
        float m2 = stats[256 + c] * inv;
        float v2 = fmaxf(stats[384 + c] * inv - m2 * m2, 0.f);
        float i2 = rsqrtf(v2 + 1e-5f);
        sc[256 + c] = g2[c] * i2; sc[384 + c] = be2[c] - m2 * g2[c] * i2;
    }
    __syncthreads();
    size_t idx = (size_t)blockIdx.x * 256 + tid;   // NN*CC/4
    int c4 = (int)(idx & 31);
    float4 s1 = *(float4*)&sc[c4 * 4];
    float4 t1 = *(float4*)&sc[128 + c4 * 4];
    float4 s2 = *(float4*)&sc[256 + c4 * 4];
    float4 t2 = *(float4*)&sc[384 + c4 * 4];
    float4 a = *(const float4*)(p1 + idx * 4);
    float4 b = *(const float4*)(p2 + idx * 4);
    float4 h, o;
    h.x = fmaf(b.x, s2.x, t2.x); o.x = fmaf(a.x, s1.x, t1.x) + h.x;
    h.y = fmaf(b.y, s2.y, t2.y); o.y = fmaf(a.y, s1.y, t1.y) + h.y;
    h.z = fmaf(b.z, s2.z, t2.z); o.z = fmaf(a.z, s1.z, t1.z) + h.z;
    h.w = fmaf(b.w, s2.w, t2.w); o.w = fmaf(a.w, s1.w, t1.w) + h.w;
    *(float4*)(h2out + idx * 4) = h;
    *(float4*)(out12 + idx * 4) = o;
    short4v ob = { f2bf(o.x), f2bf(o.y), f2bf(o.z), f2bf(o.w) };
    *(short4v*)(out12b + idx * 4) = ob;
}

// ---------------------------------------------------------------- final norm
__global__ __launch_bounds__(256) void norm3_kernel(const float* __restrict__ p3,
    const float* __restrict__ stats, const float* g3, const float* be3,
    float* __restrict__ outp)
{
    __shared__ float sc[256];
    int tid = threadIdx.x;
    if (tid < 128) {
        int c = tid;
        const float inv = 1.0f / NN;
        float m = stats[512 + c] * inv;
        float v = fmaxf(stats[640 + c] * inv - m * m, 0.f);
        float iv = rsqrtf(v + 1e-5f);
        sc[c] = g3[c] * iv; sc[128 + c] = be3[c] - m * g3[c] * iv;
    }
    __syncthreads();
    size_t idx = (size_t)blockIdx.x * 256 + tid;   // NN*CC/4
    int c4 = (int)(idx & 31);
    float4 s = *(float4*)&sc[c4 * 4];
    float4 t = *(float4*)&sc[128 + c4 * 4];
    float4 a = *(const float4*)(p3 + idx * 4);
    float4 o;
    o.x = fmaf(a.x, s.x, t.x); o.y = fmaf(a.y, s.y, t.y);
    o.z = fmaf(a.z, s.z, t.z); o.w = fmaf(a.w, s.w, t.w);
    *(float4*)(outp + idx * 4) = o;
}

extern "C" void kernel_launch(void* const* d_in, const int* in_sizes, int n_in,
                              void* d_out, int out_size, void* d_ws, size_t ws_size,
                              hipStream_t stream)
{
    (void)in_sizes; (void)n_in; (void)out_size; (void)ws_size;
    const float* x    = (const float*)d_in[0];
    const int*   ei   = (const int*)d_in[1];
    const float* eps  = (const float*)d_in[3];
    const float* gw1  = (const float*)d_in[4];
    const float* gb1  = (const float*)d_in[5];
    const float* gw2  = (const float*)d_in[6];
    const float* gb2  = (const float*)d_in[7];
    const float* ipw  = (const float*)d_in[8];
    const float* cw   = (const float*)d_in[9];
    const float* cb   = (const float*)d_in[10];
    const float* xpw  = (const float*)d_in[11];
    const float* dtw  = (const float*)d_in[12];
    const float* dtb  = (const float*)d_in[13];
    const float* Alog = (const float*)d_in[14];
    const float* Dp   = (const float*)d_in[15];
    const float* opw  = (const float*)d_in[16];
    const float* mw1  = (const float*)d_in[17];
    const float* mb1  = (const float*)d_in[18];
    const float* mw2  = (const float*)d_in[19];
    const float* mb2  = (const float*)d_in[20];
    const float* g1   = (const float*)d_in[21];
    const float* be1  = (const float*)d_in[22];
    const float* g2   = (const float*)d_in[23];
    const float* be2  = (const float*)d_in[24];
    const float* g3   = (const float*)d_in[25];
    const float* be3  = (const float*)d_in[26];

    float* outp = (float*)d_out;                       // final out [N*C]
    float* h2o  = outp + (size_t)NN * CC;              // h2 [N*C]
    float* p1 = outp;
    float* p2 = h2o;

    const size_t M1 = 1u << 20;
    float* ws = (float*)d_ws;
    float*  xs_pre = ws;                                  // 4M fl (later Q+Hin, p3)
    float*  zbuf   = ws + 4 * M1;                         // 4M fl (later out12)
    unsigned short* dtb_buf = (unsigned short*)(ws + 8 * M1);   // 4M bf16 (later out12b)
    unsigned short* xb      = (unsigned short*)(ws + 10 * M1);  // 4M bf16
    unsigned short* hgin    = (unsigned short*)(ws + 12 * M1);  // 4M bf16 (later y2b)
    unsigned short* t1b     = (unsigned short*)(ws + 14 * M1);  // 4M bf16 (later xsb)
    unsigned short* t2b     = (unsigned short*)(ws + 16 * M1);  // 8M bf16
    float*  BC     = ws + 20 * M1;                        // 1M fl
    float*  Wdt    = ws + 21 * M1;                        // 16384
    float*  stats  = Wdt + 16384;                         // 768
    int*    cnt    = (int*)(stats + 768);
    int*    baseA  = cnt + NN;
    int*    cursor = baseA + NN + 1;
    int*    perm   = cursor + NN;
    float*  SDT    = (float*)(perm + EE);                 // 131072

    float* Qbuf = xs_pre;                  // 2M fl
    float* Hin  = xs_pre + 2 * M1;         // 2M fl
    float* p3   = xs_pre;
    float* out12 = zbuf;
    unsigned short* out12b = dtb_buf;
    unsigned short* y2b = hgin;
    unsigned short* xsb = t1b;

    hipMemsetAsync(cnt, 0, NN * sizeof(int), stream);
    hipMemsetAsync(stats, 0, 768 * sizeof(float), stream);

    xb_kernel<<<dim3(NN * CC / 8 / 256), 256, 0, stream>>>(x, xb);
    wdt_kernel<<<dim3(64), 256, 0, stream>>>(dtw, xpw, Wdt);

    // CSR build + gather (emits hgin = (1+eps)x + agg in bf16)
    hist_kernel<<<dim3(EE / 256), 256, 0, stream>>>(ei, cnt);
    scan32k_kernel<<<dim3(1), 1024, 0, stream>>>(cnt, baseA, cursor);
    permute_kernel<<<dim3(EE / 256), 256, 0, stream>>>(ei, cursor, perm);
    gather_kernel<<<dim3(NN / 8), 256, 0, stream>>>(perm, baseA, xb, eps, hgin);

    // GIN MLP: t1b = relu(hgin@gw1^T+gb1) ; p1 = t1b@gw2^T+gb2 + x (stats S1)
    mfma_gemm<128, 128, 1, true, 0, false, 2><<<dim3(512, 1), 256, 0, stream>>>(
        hgin, 128, gw1, gb1, nullptr, nullptr, nullptr, t1b, nullptr, 128, nullptr, nullptr);
    mfma_gemm<128, 128, 0, true, 1, true, 1><<<dim3(512, 1), 256, 0, stream>>>(
        t1b, 128, gw2, gb2, xb, p1, nullptr, nullptr, nullptr, 128, stats + 0, stats + 128);

    // in_proj: xs_pre (cols 0-127) and zbuf (cols 128-255)
    mfma_gemm<128, 256, 0, false, 0, false, 1><<<dim3(512, 2), 256, 0, stream>>>(
        xb, 128, ipw, nullptr, nullptr, xs_pre, zbuf, nullptr, nullptr, 128, nullptr, nullptr);
    conv_kernel<<<dim3(NN * 32 / 256), 256, 0, stream>>>(xs_pre, cw, cb, xsb);

    // x_proj folded with dt_proj: dt = softplus(xs@Wdt^T + dtb) (bf16 out); BC = xs@xpw[8:40]^T
    mfma_gemm<128, 128, 2, true, 0, false, 2><<<dim3(512, 1), 256, 0, stream>>>(
        xsb, 128, Wdt, dtb, nullptr, nullptr, nullptr, dtb_buf, nullptr, 128, nullptr, nullptr);
    mfma_gemm<128, 32, 0, false, 0, false, 1><<<dim3(512, 1), 256, 0, stream>>>(
        xsb, 128, xpw + 8 * 128, nullptr, nullptr, BC, nullptr, nullptr, nullptr, 32, nullptr, nullptr);

    // chunked selective scan
    scan_part_kernel<<<dim3(GG * 16), 256, 0, stream>>>(BC, dtb_buf, xsb, Alog, Qbuf, SDT);
    scan_combine_kernel<<<dim3(GG * 2048 / 256), 256, 0, stream>>>(Qbuf, SDT, Alog, Hin);
    scan_final_kernel<<<dim3(GG * 16), 256, 0, stream>>>(BC, dtb_buf, xsb, zbuf, Alog, Dp, Hin, y2b);

    // out_proj: p2 = y2b@opw^T + x (stats S2)
    mfma_gemm<128, 128, 0, false, 1, true, 1><<<dim3(512, 1), 256, 0, stream>>>(
        y2b, 128, opw, nullptr, xb, p2, nullptr, nullptr, nullptr, 128, stats + 256, stats + 384);

    // norms 1,2 + combine
    norm12_kernel<<<dim3(NN * CC / 4 / 256), 256, 0, stream>>>(
        p1, p2, stats, g1, be1, g2, be2, h2o, out12, out12b);

    // MLP: t2b = relu(out12b@mw1^T+mb1) ; p3 = t2b@mw2^T+mb2 + out12 (stats S3)
    mfma_gemm<128, 256, 1, true, 0, false, 2><<<dim3(512, 2), 256, 0, stream>>>(
        out12b, 128, mw1, mb1, nullptr, nullptr, nullptr, t2b, t2b + 128, 256, nullptr, nullptr);
    mfma_gemm<256, 128, 0, true, 2, true, 1><<<dim3(512, 1), 256, 0, stream>>>(
        t2b, 256, mw2, mb2, out12, p3, nullptr, nullptr, nullptr, 128, stats + 512, stats + 640);

    norm3_kernel<<<dim3(NN * CC / 4 / 256), 256, 0, stream>>>(p3, stats, g3, be3, outp);
}

// Round 6
// 402.623 us; speedup vs baseline: 1.7083x; 1.0017x over previous
//
#include <hip/hip_runtime.h>
#include <hip/hip_bf16.h>

#define NN 32768
#define GG 128
#define LL 256
#define CC 128
#define EE 524288
#define NCHUNK 8
#define TCH 32

typedef __attribute__((ext_vector_type(8))) short short8v;
typedef __attribute__((ext_vector_type(4))) short short4v;
typedef __attribute__((ext_vector_type(4))) float floatx4;

__device__ inline short f2bf(float f) {
    __hip_bfloat16 h = __float2bfloat16(f);
    short s; __builtin_memcpy(&s, &h, 2); return s;
}
__device__ inline float b2f(unsigned short u) {
    unsigned v = ((unsigned)u) << 16; float f; __builtin_memcpy(&f, &v, 4); return f;
}

// ---------------------------------------------------------------- fp32 -> bf16 bulk convert
__global__ __launch_bounds__(256) void wcvt_kernel(const float* __restrict__ src,
    unsigned short* __restrict__ dst)
{
    size_t i = (size_t)blockIdx.x * 256 + threadIdx.x;
    float4 a = *(const float4*)(src + i * 8);
    float4 b = *(const float4*)(src + i * 8 + 4);
    short8v s = { f2bf(a.x), f2bf(a.y), f2bf(a.z), f2bf(a.w),
                  f2bf(b.x), f2bf(b.y), f2bf(b.z), f2bf(b.w) };
    *(short8v*)(dst + i * 8) = s;
}

// ---------------------------------------------------------------- Wdt = dtw @ xpw[:8] (bf16 out)
__global__ __launch_bounds__(256) void wdt_kernel(const float* __restrict__ dtw,
    const float* __restrict__ xpw, unsigned short* __restrict__ Wdtb)
{
    int i = blockIdx.x * 256 + threadIdx.x;   // 16384
    int d = i >> 7, c = i & 127;
    float s = 0.f;
#pragma unroll
    for (int r = 0; r < 8; r++) s = fmaf(dtw[d * 8 + r], xpw[r * 128 + c], s);
    Wdtb[i] = (unsigned short)f2bf(s);
}

// ---------------------------------------------------------------- edge histogram
__global__ __launch_bounds__(256) void hist_kernel(const int* __restrict__ ei,
    int* __restrict__ cnt)
{
    int e = blockIdx.x * 256 + threadIdx.x;
    atomicAdd(&cnt[ei[EE + e]], 1);
}

// ---------------------------------------------------------------- exclusive scan of 32768 counts
__global__ __launch_bounds__(1024) void scan32k_kernel(const int* __restrict__ cnt,
    int* __restrict__ base, int* __restrict__ cursor)
{
    __shared__ int part[1024];
    int tid = threadIdx.x;
    int local[32];
    int s = 0;
#pragma unroll
    for (int j = 0; j < 32; j++) { local[j] = cnt[tid * 32 + j]; s += local[j]; }
    part[tid] = s;
    __syncthreads();
    for (int off = 1; off < 1024; off <<= 1) {
        int v = (tid >= off) ? part[tid - off] : 0;
        __syncthreads();
        part[tid] += v;
        __syncthreads();
    }
    int run = part[tid] - s;
#pragma unroll
    for (int j = 0; j < 32; j++) {
        base[tid * 32 + j] = run;
        cursor[tid * 32 + j] = run;
        run += local[j];
    }
    if (tid == 0) base[NN] = EE;
}

// ---------------------------------------------------------------- permute srcs into dst-sorted order
__global__ __launch_bounds__(256) void permute_kernel(const int* __restrict__ ei,
    int* __restrict__ cursor, int* __restrict__ perm)
{
    int e = blockIdx.x * 256 + threadIdx.x;
    int dst = ei[EE + e];
    int pos = atomicAdd(&cursor[dst], 1);
    perm[pos] = ei[e];
}

// ---------------------------------------------------------------- gather-sum + (1+eps)x, bf16 in/out
__global__ __launch_bounds__(256) void gather_kernel(const int* __restrict__ perm,
    const int* __restrict__ base, const unsigned short* __restrict__ xb,
    const float* __restrict__ epsp, unsigned short* __restrict__ hgin)
{
    int node = blockIdx.x * 8 + (threadIdx.x >> 5);
    int c4 = threadIdx.x & 31;
    int b0 = base[node], b1 = base[node + 1];
    float s0 = 0, s1 = 0, s2 = 0, s3 = 0;
    float t0 = 0, t1 = 0, t2 = 0, t3 = 0;
    int i = b0;
    for (; i + 1 < b1; i += 2) {
        short4v v0 = *(const short4v*)(xb + (size_t)perm[i] * CC + c4 * 4);
        short4v v1 = *(const short4v*)(xb + (size_t)perm[i + 1] * CC + c4 * 4);
        s0 += b2f((unsigned short)v0[0]); s1 += b2f((unsigned short)v0[1]);
        s2 += b2f((unsigned short)v0[2]); s3 += b2f((unsigned short)v0[3]);
        t0 += b2f((unsigned short)v1[0]); t1 += b2f((unsigned short)v1[1]);
        t2 += b2f((unsigned short)v1[2]); t3 += b2f((unsigned short)v1[3]);
    }
    if (i < b1) {
        short4v v0 = *(const short4v*)(xb + (size_t)perm[i] * CC + c4 * 4);
        s0 += b2f((unsigned short)v0[0]); s1 += b2f((unsigned short)v0[1]);
        s2 += b2f((unsigned short)v0[2]); s3 += b2f((unsigned short)v0[3]);
    }
    float e1 = 1.f + epsp[0];
    short4v xv = *(const short4v*)(xb + (size_t)node * CC + c4 * 4);
    float r0 = fmaf(e1, b2f((unsigned short)xv[0]), s0 + t0);
    float r1 = fmaf(e1, b2f((unsigned short)xv[1]), s1 + t1);
    float r2 = fmaf(e1, b2f((unsigned short)xv[2]), s2 + t2);
    float r3 = fmaf(e1, b2f((unsigned short)xv[3]), s3 + t3);
    short4v o = { f2bf(r0), f2bf(r1), f2bf(r2), f2bf(r3) };
    *(short4v*)(hgin + (size_t)node * CC + c4 * 4) = o;
}

// ---------------------------------------------------------------- register MFMA GEMM (no LDS staging, no barriers)
// out[r][o] = sum_k A[r][k]*W[o][k] (+bias)(act)(+resid). A,W bf16 in memory.
// 32x128 tile, 4 waves col-split (wave 32x32). grid (NN/32, NCOL/128).
// ACT: 0 none,1 relu,2 softplus. RESID: 0 none,1 bf16,2 fp32.
// OUTM bit0 fp32 store, bit1 bf16 store. by selects (out,outb)/(out_b1,outb_b1).
template<int K, int COLS_VALID, int ACT, bool HAS_BIAS, int RESID, bool STATS, int OUTM>
__global__ __launch_bounds__(256)
void rgemm(const unsigned short* __restrict__ A, int lda,
           const unsigned short* __restrict__ Wb,
           const float* __restrict__ bias,
           const void* __restrict__ resid,
           float* out, float* out_b1,
           unsigned short* outb, unsigned short* outb_b1, int ldo,
           float* ssum, float* ssq)
{
    __shared__ float sred[256];
    const int tid = threadIdx.x;
    const int R0 = blockIdx.x * 32;
    const int by = blockIdx.y;
    const int lane = tid & 63;
    const int wc = tid >> 6;
    const int rql = lane & 15;
    const int kseg = (lane >> 4) * 8;
    constexpr bool FULL = (COLS_VALID % 128) == 0;

    if (STATS) { sred[tid] = 0.f; __syncthreads(); }

    floatx4 acc[2][2];
#pragma unroll
    for (int m = 0; m < 2; m++)
#pragma unroll
        for (int n = 0; n < 2; n++)
#pragma unroll
            for (int r = 0; r < 4; r++) acc[m][n][r] = 0.f;

    int colg[2];
    colg[0] = by * 128 + wc * 32 + rql;
    colg[1] = colg[0] + 16;
    const bool v0 = FULL || (colg[0] < COLS_VALID);
    const bool v1 = FULL || (colg[1] < COLS_VALID);
    const unsigned short* ap = A + (size_t)(R0 + rql) * lda + kseg;
    const unsigned short* wp0 = Wb + (size_t)colg[0] * K + kseg;
    const unsigned short* wp1 = Wb + (size_t)colg[1] * K + kseg;
    const short8v z8 = { 0, 0, 0, 0, 0, 0, 0, 0 };

#pragma unroll
    for (int kk = 0; kk < K / 32; kk++) {
        short8v a0 = *(const short8v*)(ap + kk * 32);
        short8v a1 = *(const short8v*)(ap + (size_t)16 * lda + kk * 32);
        short8v b0 = v0 ? *(const short8v*)(wp0 + kk * 32) : z8;
        short8v b1 = v1 ? *(const short8v*)(wp1 + kk * 32) : z8;
        acc[0][0] = __builtin_amdgcn_mfma_f32_16x16x32_bf16(a0, b0, acc[0][0], 0, 0, 0);
        acc[0][1] = __builtin_amdgcn_mfma_f32_16x16x32_bf16(a0, b1, acc[0][1], 0, 0, 0);
        acc[1][0] = __builtin_amdgcn_mfma_f32_16x16x32_bf16(a1, b0, acc[1][0], 0, 0, 0);
        acc[1][1] = __builtin_amdgcn_mfma_f32_16x16x32_bf16(a1, b1, acc[1][1], 0, 0, 0);
    }

    float sumn[2] = {0, 0}, sqn[2] = {0, 0};
    float bcol[2];
#pragma unroll
    for (int n = 0; n < 2; n++)
        bcol[n] = (HAS_BIAS && (FULL || colg[n] < COLS_VALID)) ? bias[colg[n]] : 0.f;
    float* op = by ? out_b1 : out;
    unsigned short* opb = by ? outb_b1 : outb;
#pragma unroll
    for (int m = 0; m < 2; m++) {
#pragma unroll
        for (int r = 0; r < 4; r++) {
            int row_g = R0 + m * 16 + ((lane >> 4) << 2) + r;
#pragma unroll
            for (int n = 0; n < 2; n++) {
                float v = acc[m][n][r] + bcol[n];
                if (ACT == 1) v = fmaxf(v, 0.f);
                if (ACT == 2) v = (v > 20.f) ? v : log1pf(__expf(v));
                if (RESID == 1)
                    v += b2f(((const unsigned short*)resid)[(size_t)row_g * CC + colg[n]]);
                if (RESID == 2)
                    v += ((const float*)resid)[(size_t)row_g * CC + colg[n]];
                if (FULL || colg[n] < COLS_VALID) {
                    int cl_ = colg[n] - by * 128;
                    if (OUTM & 1) op[(size_t)row_g * ldo + cl_] = v;
                    if (OUTM & 2) opb[(size_t)row_g * ldo + cl_] = (unsigned short)f2bf(v);
                }
                if (STATS) { sumn[n] += v; sqn[n] += v * v; }
            }
        }
    }
    if (STATS) {
#pragma unroll
        for (int n = 0; n < 2; n++) {
            int cl = wc * 32 + n * 16 + rql;
            atomicAdd(&sred[cl], sumn[n]);
            atomicAdd(&sred[128 + cl], sqn[n]);
        }
        __syncthreads();
        if (tid < 128) {
            atomicAdd(&ssum[tid], sred[tid]);
            atomicAdd(&ssq[tid], sred[128 + tid]);
        }
    }
}

// ---------------------------------------------------------------- depthwise causal conv + silu
__global__ __launch_bounds__(256) void conv_kernel(const float* __restrict__ xs_pre,
    const float* __restrict__ cw, const float* __restrict__ cb,
    unsigned short* __restrict__ xsb)
{
    int t = blockIdx.x * 256 + threadIdx.x;   // NN*32
    int n = t >> 5, c4 = t & 31;
    int l = n & (LL - 1);
    const float* bp = xs_pre + (size_t)n * CC + c4 * 4;
    float4 x0 = *(const float4*)bp;
    float4 x1 = (l >= 1) ? *(const float4*)(bp - CC) : make_float4(0, 0, 0, 0);
    float4 x2 = (l >= 2) ? *(const float4*)(bp - 2 * CC) : make_float4(0, 0, 0, 0);
    float4 x3 = (l >= 3) ? *(const float4*)(bp - 3 * CC) : make_float4(0, 0, 0, 0);
    float4 cbv = *(const float4*)(cb + c4 * 4);
    unsigned short o[4];
#pragma unroll
    for (int j = 0; j < 4; j++) {
        float4 w = *(const float4*)(cw + (c4 * 4 + j) * 4);
        float v = (&cbv.x)[j];
        v = fmaf((&x0.x)[j], w.w, v);
        v = fmaf((&x1.x)[j], w.z, v);
        v = fmaf((&x2.x)[j], w.y, v);
        v = fmaf((&x3.x)[j], w.x, v);
        v = v / (1.f + __expf(-v));
        o[j] = (unsigned short)f2bf(v);
    }
    short4v s = { (short)o[0], (short)o[1], (short)o[2], (short)o[3] };
    *(short4v*)(xsb + (size_t)t * 4) = s;
}

// ---------------------------------------------------------------- scan phase A: per-chunk (sum_dt, q)
__global__ __launch_bounds__(256) void scan_part_kernel(const float* __restrict__ BCp,
    const unsigned short* __restrict__ dtp, const unsigned short* __restrict__ xsp_,
    const float* __restrict__ Alog, float* __restrict__ Q, float* __restrict__ SDT)
{
    __shared__ float Bs[TCH * 16];
    __shared__ float dts[TCH * 64];
    __shared__ float xss[TCH * 64];
    int b = blockIdx.x;
    int g = b >> 4, ch = (b >> 3) & 1, chunk = b & 7;
    int t0 = chunk * TCH;
    int tid = threadIdx.x;
    for (int i4 = tid; i4 < TCH * 4; i4 += 256) {
        int t = i4 >> 2, j4 = i4 & 3;
        *(float4*)&Bs[t * 16 + j4 * 4] =
            *(const float4*)(BCp + (size_t)(g * LL + t0 + t) * 32 + j4 * 4);
    }
    for (int i4 = tid; i4 < TCH * 16; i4 += 256) {
        int t = i4 >> 4, c4 = i4 & 15;
        size_t off = (size_t)(g * LL + t0 + t) * CC + ch * 64 + c4 * 4;
        short4v dv = *(const short4v*)(dtp + off);
        short4v xv = *(const short4v*)(xsp_ + off);
        *(float4*)&dts[t * 64 + c4 * 4] = make_float4(
            b2f((unsigned short)dv[0]), b2f((unsigned short)dv[1]),
            b2f((unsigned short)dv[2]), b2f((unsigned short)dv[3]));
        *(float4*)&xss[t * 64 + c4 * 4] = make_float4(
            b2f((unsigned short)xv[0]), b2f((unsigned short)xv[1]),
            b2f((unsigned short)xv[2]), b2f((unsigned short)xv[3]));
    }
    int cl = tid >> 2, sp = tid & 3;
    int c = ch * 64 + cl;
    float ae[4];
#pragma unroll
    for (int j = 0; j < 4; j++) ae[j] = -__expf(Alog[c * 16 + sp * 4 + j]);
    __syncthreads();
    float q0 = 0, q1 = 0, q2 = 0, q3 = 0, sdt = 0;
    for (int t = TCH - 1; t >= 0; --t) {
        float dtv = dts[t * 64 + cl];
        float xv  = xss[t * 64 + cl];
        float u = dtv * xv;
        const float* bs = Bs + t * 16 + sp * 4;
        q0 = fmaf(__expf(ae[0] * sdt) * u, bs[0], q0);
        q1 = fmaf(__expf(ae[1] * sdt) * u, bs[1], q1);
        q2 = fmaf(__expf(ae[2] * sdt) * u, bs[2], q2);
        q3 = fmaf(__expf(ae[3] * sdt) * u, bs[3], q3);
        sdt += dtv;
    }
    float4* qp = (float4*)(Q + (((size_t)g * NCHUNK + chunk) * CC + c) * 16 + sp * 4);
    *qp = make_float4(q0, q1, q2, q3);
    if (sp == 0) SDT[((size_t)g * NCHUNK + chunk) * CC + c] = sdt;
}

// ---------------------------------------------------------------- scan phase B: combine chunk states
__global__ __launch_bounds__(256) void scan_combine_kernel(const float* __restrict__ Q,
    const float* __restrict__ SDT, const float* __restrict__ Alog, float* __restrict__ Hin)
{
    int idx = blockIdx.x * 256 + threadIdx.x;   // g*2048 + c*16 + s
    int g = idx >> 11;
    int cs = idx & 2047;
    float ae = -__expf(Alog[cs]);
    float h = 0.f;
#pragma unroll
    for (int k = 0; k < NCHUNK; k++) {
        size_t o = ((size_t)g * NCHUNK + k);
        Hin[o * 2048 + cs] = h;
        float sdt = SDT[o * CC + (cs >> 4)];
        h = fmaf(__expf(ae * sdt), h, Q[o * 2048 + cs]);
    }
}

// ---------------------------------------------------------------- scan phase C: forward with init + y
__global__ __launch_bounds__(256) void scan_final_kernel(const float* __restrict__ BCp,
    const unsigned short* __restrict__ dtp, const unsigned short* __restrict__ xsp_,
    const float* __restrict__ zbuf, const float* __restrict__ Alog,
    const float* __restrict__ Dp, const float* __restrict__ Hin,
    unsigned short* __restrict__ y2b)
{
    __shared__ float BCs[TCH * 32];
    __shared__ float dts[TCH * 64];
    __shared__ float xss[TCH * 64];
    int b = blockIdx.x;
    int g = b >> 4, ch = (b >> 3) & 1, chunk = b & 7;
    int t0 = chunk * TCH;
    int tid = threadIdx.x;
    for (int i4 = tid; i4 < TCH * 8; i4 += 256) {
        int t = i4 >> 3, j4 = i4 & 7;
        *(float4*)&BCs[t * 32 + j4 * 4] =
            *(const float4*)(BCp + (size_t)(g * LL + t0 + t) * 32 + j4 * 4);
    }
    for (int i4 = tid; i4 < TCH * 16; i4 += 256) {
        int t = i4 >> 4, c4 = i4 & 15;
        size_t off = (size_t)(g * LL + t0 + t) * CC + ch * 64 + c4 * 4;
        short4v dv = *(const short4v*)(dtp + off);
        short4v xv = *(const short4v*)(xsp_ + off);
        *(float4*)&dts[t * 64 + c4 * 4] = make_float4(
            b2f((unsigned short)dv[0]), b2f((unsigned short)dv[1]),
            b2f((unsigned short)dv[2]), b2f((unsigned short)dv[3]));
        *(float4*)&xss[t * 64 + c4 * 4] = make_float4(
            b2f((unsigned short)xv[0]), b2f((unsigned short)xv[1]),
            b2f((unsigned short)xv[2]), b2f((unsigned short)xv[3]));
    }
    int cl = tid >> 2, sp = tid & 3;
    int c = ch * 64 + cl;
    float ae[4];
#pragma unroll
    for (int j = 0; j < 4; j++) ae[j] = -__expf(Alog[c * 16 + sp * 4 + j]);
    float dpc = Dp[c];
    float4 hv = *(const float4*)(Hin + ((size_t)g * NCHUNK + chunk) * 2048 + c * 16 + sp * 4);
    float h0 = hv.x, h1 = hv.y, h2 = hv.z, h3 = hv.w;
    __syncthreads();
    const float* zg = zbuf + (size_t)(g * LL + t0) * CC + c;
    unsigned short* yg = y2b + (size_t)(g * LL + t0) * CC + c;
    for (int t = 0; t < TCH; t++) {
        float dtv = dts[t * 64 + cl];
        float xv  = xss[t * 64 + cl];
        float u = dtv * xv;
        const float* bc = BCs + t * 32 + sp * 4;
        h0 = fmaf(__expf(dtv * ae[0]), h0, u * bc[0]);
        h1 = fmaf(__expf(dtv * ae[1]), h1, u * bc[1]);
        h2 = fmaf(__expf(dtv * ae[2]), h2, u * bc[2]);
        h3 = fmaf(__expf(dtv * ae[3]), h3, u * bc[3]);
        float y = h0 * bc[16] + h1 * bc[17] + h2 * bc[18] + h3 * bc[19];
        y += __shfl_xor(y, 1);
        y += __shfl_xor(y, 2);
        if (sp == 0) {
            float zv = zg[t * CC];
            float yo = fmaf(dpc, xv, y);
            yg[t * CC] = (unsigned short)f2bf(yo * (zv / (1.f + __expf(-zv))));
        }
    }
}

// ---------------------------------------------------------------- norm (h1,h2) + combine
__global__ __launch_bounds__(256) void norm12_kernel(const float* __restrict__ p1,
    const float* __restrict__ p2, const float* __restrict__ stats,
    const float* g1, const float* be1, const float* g2, const float* be2,
    float* __restrict__ h2out, float* __restrict__ out12,
    unsigned short* __restrict__ out12b)
{
    __shared__ float sc[512];
    int tid = threadIdx.x;
    if (tid < 128) {
        int c = tid;
        const float inv = 1.0f / NN;
        float m1 = stats[c] * inv;
        float v1 = fmaxf(stats[128 + c] * inv - m1 * m1, 0.f);
        float i1 = rsqrtf(v1 + 1e-5f);
        sc[c] = g1[c] * i1; sc[128 + c] = be1[c] - m1 * g1[c] * i1;
        float m2 = stats[256 + c] * inv;
        float v2 = fmaxf(stats[384 + c] * inv - m2 * m2, 0.f);
        float i2 = rsqrtf(v2 + 1e-5f);
        sc[256 + c] = g2[c] * i2; sc[384 + c] = be2[c] - m2 * g2[c] * i2;
    }
    __syncthreads();
    size_t idx = (size_t)blockIdx.x * 256 + tid;   // NN*CC/4
    int c4 = (int)(idx & 31);
    float4 s1 = *(float4*)&sc[c4 * 4];
    float4 t1 = *(float4*)&sc[128 + c4 * 4];
    float4 s2 = *(float4*)&sc[256 + c4 * 4];
    float4 t2 = *(float4*)&sc[384 + c4 * 4];
    float4 a = *(const float4*)(p1 + idx * 4);
    float4 b = *(const float4*)(p2 + idx * 4);
    float4 h, o;
    h.x = fmaf(b.x, s2.x, t2.x); o.x = fmaf(a.x, s1.x, t1.x) + h.x;
    h.y = fmaf(b.y, s2.y, t2.y); o.y = fmaf(a.y, s1.y, t1.y) + h.y;
    h.z = fmaf(b.z, s2.z, t2.z); o.z = fmaf(a.z, s1.z, t1.z) + h.z;
    h.w = fmaf(b.w, s2.w, t2.w); o.w = fmaf(a.w, s1.w, t1.w) + h.w;
    *(float4*)(h2out + idx * 4) = h;
    *(float4*)(out12 + idx * 4) = o;
    short4v ob = { f2bf(o.x), f2bf(o.y), f2bf(o.z), f2bf(o.w) };
    *(short4v*)(out12b + idx * 4) = ob;
}

// ---------------------------------------------------------------- final norm
__global__ __launch_bounds__(256) void norm3_kernel(const float* __restrict__ p3,
    const float* __restrict__ stats, const float* g3, const float* be3,
    float* __restrict__ outp)
{
    __shared__ float sc[256];
    int tid = threadIdx.x;
    if (tid < 128) {
        int c = tid;
        const float inv = 1.0f / NN;
        float m = stats[512 + c] * inv;
        float v = fmaxf(stats[640 + c] * inv - m * m, 0.f);
        float iv = rsqrtf(v + 1e-5f);
        sc[c] = g3[c] * iv; sc[128 + c] = be3[c] - m * g3[c] * iv;
    }
    __syncthreads();
    size_t idx = (size_t)blockIdx.x * 256 + tid;   // NN*CC/4
    int c4 = (int)(idx & 31);
    float4 s = *(float4*)&sc[c4 * 4];
    float4 t = *(float4*)&sc[128 + c4 * 4];
    float4 a = *(const float4*)(p3 + idx * 4);
    float4 o;
    o.x = fmaf(a.x, s.x, t.x); o.y = fmaf(a.y, s.y, t.y);
    o.z = fmaf(a.z, s.z, t.z); o.w = fmaf(a.w, s.w, t.w);
    *(float4*)(outp + idx * 4) = o;
}

extern "C" void kernel_launch(void* const* d_in, const int* in_sizes, int n_in,
                              void* d_out, int out_size, void* d_ws, size_t ws_size,
                              hipStream_t stream)
{
    (void)in_sizes; (void)n_in; (void)out_size; (void)ws_size;
    const float* x    = (const float*)d_in[0];
    const int*   ei   = (const int*)d_in[1];
    const float* eps  = (const float*)d_in[3];
    const float* gw1  = (const float*)d_in[4];
    const float* gb1  = (const float*)d_in[5];
    const float* gw2  = (const float*)d_in[6];
    const float* gb2  = (const float*)d_in[7];
    const float* ipw  = (const float*)d_in[8];
    const float* cw   = (const float*)d_in[9];
    const float* cb   = (const float*)d_in[10];
    const float* xpw  = (const float*)d_in[11];
    const float* dtw  = (const float*)d_in[12];
    const float* dtb  = (const float*)d_in[13];
    const float* Alog = (const float*)d_in[14];
    const float* Dp   = (const float*)d_in[15];
    const float* opw  = (const float*)d_in[16];
    const float* mw1  = (const float*)d_in[17];
    const float* mb1  = (const float*)d_in[18];
    const float* mw2  = (const float*)d_in[19];
    const float* mb2  = (const float*)d_in[20];
    const float* g1   = (const float*)d_in[21];
    const float* be1  = (const float*)d_in[22];
    const float* g2   = (const float*)d_in[23];
    const float* be2  = (const float*)d_in[24];
    const float* g3   = (const float*)d_in[25];
    const float* be3  = (const float*)d_in[26];

    float* outp = (float*)d_out;                       // final out [N*C]
    float* h2o  = outp + (size_t)NN * CC;              // h2 [N*C]
    float* p1 = outp;
    float* p2 = h2o;

    const size_t M1 = 1u << 20;
    float* ws = (float*)d_ws;
    float*  xs_pre = ws;                                  // 4M fl (later Q+Hin, p3)
    float*  zbuf   = ws + 4 * M1;                         // 4M fl (later out12)
    unsigned short* dtb_buf = (unsigned short*)(ws + 8 * M1);   // 4M bf16 (later out12b)
    unsigned short* xb      = (unsigned short*)(ws + 10 * M1);  // 4M bf16
    unsigned short* hgin    = (unsigned short*)(ws + 12 * M1);  // 4M bf16 (later y2b)
    unsigned short* t1b     = (unsigned short*)(ws + 14 * M1);  // 4M bf16 (later xsb)
    unsigned short* t2b     = (unsigned short*)(ws + 16 * M1);  // 8M bf16
    float*  BC     = ws + 20 * M1;                        // 1M fl
    float*  stats  = ws + 21 * M1;                        // 768
    int*    cnt    = (int*)(stats + 768);
    int*    baseA  = cnt + NN;
    int*    cursor = baseA + NN + 1;
    int*    perm   = cursor + NN;
    float*  SDT    = (float*)(perm + EE);                 // 131072
    unsigned short* wbase = (unsigned short*)(SDT + 131072);
    unsigned short* gw1b = wbase;                // 16384
    unsigned short* gw2b = wbase + 16384;
    unsigned short* ipwb = wbase + 32768;        // 32768
    unsigned short* wdtb = wbase + 65536;        // 16384
    unsigned short* xpwb = wbase + 81920;        // 4096
    unsigned short* opwb = wbase + 86016;        // 16384
    unsigned short* mw1b = wbase + 102400;       // 32768
    unsigned short* mw2b = wbase + 135168;       // 32768

    float* Qbuf = xs_pre;                  // 2M fl
    float* Hin  = xs_pre + 2 * M1;         // 2M fl
    float* p3   = xs_pre;
    float* out12 = zbuf;
    unsigned short* out12b = dtb_buf;
    unsigned short* y2b = hgin;
    unsigned short* xsb = t1b;

    hipMemsetAsync(cnt, 0, NN * sizeof(int), stream);
    hipMemsetAsync(stats, 0, 768 * sizeof(float), stream);

    // input + weight bf16 conversion
    wcvt_kernel<<<dim3(NN * CC / 8 / 256), 256, 0, stream>>>(x, xb);
    wcvt_kernel<<<dim3(8), 256, 0, stream>>>(gw1, gw1b);
    wcvt_kernel<<<dim3(8), 256, 0, stream>>>(gw2, gw2b);
    wcvt_kernel<<<dim3(16), 256, 0, stream>>>(ipw, ipwb);
    wcvt_kernel<<<dim3(2), 256, 0, stream>>>(xpw + 8 * 128, xpwb);
    wcvt_kernel<<<dim3(8), 256, 0, stream>>>(opw, opwb);
    wcvt_kernel<<<dim3(16), 256, 0, stream>>>(mw1, mw1b);
    wcvt_kernel<<<dim3(16), 256, 0, stream>>>(mw2, mw2b);
    wdt_kernel<<<dim3(64), 256, 0, stream>>>(dtw, xpw, wdtb);

    // CSR build + gather (emits hgin = (1+eps)x + agg in bf16)
    hist_kernel<<<dim3(EE / 256), 256, 0, stream>>>(ei, cnt);
    scan32k_kernel<<<dim3(1), 1024, 0, stream>>>(cnt, baseA, cursor);
    permute_kernel<<<dim3(EE / 256), 256, 0, stream>>>(ei, cursor, perm);
    gather_kernel<<<dim3(NN / 8), 256, 0, stream>>>(perm, baseA, xb, eps, hgin);

    // GIN MLP: t1b = relu(hgin@gw1^T+gb1) ; p1 = t1b@gw2^T+gb2 + x (stats S1)
    rgemm<128, 128, 1, true, 0, false, 2><<<dim3(1024, 1), 256, 0, stream>>>(
        hgin, 128, gw1b, gb1, nullptr, nullptr, nullptr, t1b, nullptr, 128, nullptr, nullptr);
    rgemm<128, 128, 0, true, 1, true, 1><<<dim3(1024, 1), 256, 0, stream>>>(
        t1b, 128, gw2b, gb2, xb, p1, nullptr, nullptr, nullptr, 128, stats + 0, stats + 128);

    // in_proj -> xs_pre (cols 0-127) / zbuf (cols 128-255)
    rgemm<128, 256, 0, false, 0, false, 1><<<dim3(1024, 2), 256, 0, stream>>>(
        xb, 128, ipwb, nullptr, nullptr, xs_pre, zbuf, nullptr, nullptr, 128, nullptr, nullptr);
    conv_kernel<<<dim3(NN * 32 / 256), 256, 0, stream>>>(xs_pre, cw, cb, xsb);

    // dt = softplus(xs@Wdt^T + dtb) (bf16); BC = xs@xpw[8:40]^T
    rgemm<128, 128, 2, true, 0, false, 2><<<dim3(1024, 1), 256, 0, stream>>>(
        xsb, 128, wdtb, dtb, nullptr, nullptr, nullptr, dtb_buf, nullptr, 128, nullptr, nullptr);
    rgemm<128, 32, 0, false, 0, false, 1><<<dim3(1024, 1), 256, 0, stream>>>(
        xsb, 128, xpwb, nullptr, nullptr, BC, nullptr, nullptr, nullptr, 32, nullptr, nullptr);

    // chunked selective scan
    scan_part_kernel<<<dim3(GG * 16), 256, 0, stream>>>(BC, dtb_buf, xsb, Alog, Qbuf, SDT);
    scan_combine_kernel<<<dim3(GG * 2048 / 256), 256, 0, stream>>>(Qbuf, SDT, Alog, Hin);
    scan_final_kernel<<<dim3(GG * 16), 256, 0, stream>>>(BC, dtb_buf, xsb, zbuf, Alog, Dp, Hin, y2b);

    // out_proj: p2 = y2b@opw^T + x (stats S2)
    rgemm<128, 128, 0, false, 1, true, 1><<<dim3(1024, 1), 256, 0, stream>>>(
        y2b, 128, opwb, nullptr, xb, p2, nullptr, nullptr, nullptr, 128, stats + 256, stats + 384);

    // norms 1,2 + combine
    norm12_kernel<<<dim3(NN * CC / 4 / 256), 256, 0, stream>>>(
        p1, p2, stats, g1, be1, g2, be2, h2o, out12, out12b);

    // MLP: t2b = relu(out12b@mw1^T+mb1) ; p3 = t2b@mw2^T+mb2 + out12 (stats S3)
    rgemm<128, 256, 1, true, 0, false, 2><<<dim3(1024, 2), 256, 0, stream>>>(
        out12b, 128, mw1b, mb1, nullptr, nullptr, nullptr, t2b, t2b + 128, 256, nullptr, nullptr);
    rgemm<256, 128, 0, true, 2, true, 1><<<dim3(1024, 1), 256, 0, stream>>>(
        t2b, 256, mw2b, mb2, out12, p3, nullptr, nullptr, nullptr, 128, stats + 512, stats + 640);

    norm3_kernel<<<dim3(NN * CC / 4 / 256), 256, 0, stream>>>(p3, stats, g3, be3, outp);
}

// Round 7
// 378.940 us; speedup vs baseline: 1.8151x; 1.0625x over previous
//
#include <hip/hip_runtime.h>
#include <hip/hip_bf16.h>

#define NN 32768
#define GG 128
#define LL 256
#define CC 128
#define EE 524288
#define NCHUNK 8
#define TCH 32

typedef __attribute__((ext_vector_type(8))) short short8v;
typedef __attribute__((ext_vector_type(4))) short short4v;
typedef __attribute__((ext_vector_type(4))) float floatx4;

__device__ inline short f2bf(float f) {
    __hip_bfloat16 h = __float2bfloat16(f);
    short s; __builtin_memcpy(&s, &h, 2); return s;
}
__device__ inline float b2f(unsigned short u) {
    unsigned v = ((unsigned)u) << 16; float f; __builtin_memcpy(&f, &v, 4); return f;
}

// ---------------------------------------------------------------- fp32 -> bf16 bulk convert
__global__ __launch_bounds__(256) void wcvt_kernel(const float* __restrict__ src,
    unsigned short* __restrict__ dst)
{
    size_t i = (size_t)blockIdx.x * 256 + threadIdx.x;
    float4 a = *(const float4*)(src + i * 8);
    float4 b = *(const float4*)(src + i * 8 + 4);
    short8v s = { f2bf(a.x), f2bf(a.y), f2bf(a.z), f2bf(a.w),
                  f2bf(b.x), f2bf(b.y), f2bf(b.z), f2bf(b.w) };
    *(short8v*)(dst + i * 8) = s;
}

// ---------------------------------------------------------------- Wdt = dtw @ xpw[:8] (bf16 out)
__global__ __launch_bounds__(256) void wdt_kernel(const float* __restrict__ dtw,
    const float* __restrict__ xpw, unsigned short* __restrict__ Wdtb)
{
    int i = blockIdx.x * 256 + threadIdx.x;   // 16384
    int d = i >> 7, c = i & 127;
    float s = 0.f;
#pragma unroll
    for (int r = 0; r < 8; r++) s = fmaf(dtw[d * 8 + r], xpw[r * 128 + c], s);
    Wdtb[i] = (unsigned short)f2bf(s);
}

// ---------------------------------------------------------------- edge histogram
__global__ __launch_bounds__(256) void hist_kernel(const int* __restrict__ ei,
    int* __restrict__ cnt)
{
    int e = blockIdx.x * 256 + threadIdx.x;
    atomicAdd(&cnt[ei[EE + e]], 1);
}

// ---------------------------------------------------------------- exclusive scan of 32768 counts
__global__ __launch_bounds__(1024) void scan32k_kernel(const int* __restrict__ cnt,
    int* __restrict__ base, int* __restrict__ cursor)
{
    __shared__ int part[1024];
    int tid = threadIdx.x;
    int local[32];
    int s = 0;
#pragma unroll
    for (int j = 0; j < 32; j++) { local[j] = cnt[tid * 32 + j]; s += local[j]; }
    part[tid] = s;
    __syncthreads();
    for (int off = 1; off < 1024; off <<= 1) {
        int v = (tid >= off) ? part[tid - off] : 0;
        __syncthreads();
        part[tid] += v;
        __syncthreads();
    }
    int run = part[tid] - s;
#pragma unroll
    for (int j = 0; j < 32; j++) {
        base[tid * 32 + j] = run;
        cursor[tid * 32 + j] = run;
        run += local[j];
    }
    if (tid == 0) base[NN] = EE;
}

// ---------------------------------------------------------------- permute srcs into dst-sorted order
__global__ __launch_bounds__(256) void permute_kernel(const int* __restrict__ ei,
    int* __restrict__ cursor, int* __restrict__ perm)
{
    int e = blockIdx.x * 256 + threadIdx.x;
    int dst = ei[EE + e];
    int pos = atomicAdd(&cursor[dst], 1);
    perm[pos] = ei[e];
}

// ---------------------------------------------------------------- gather-sum + (1+eps)x, bf16 in/out
__global__ __launch_bounds__(256) void gather_kernel(const int* __restrict__ perm,
    const int* __restrict__ base, const unsigned short* __restrict__ xb,
    const float* __restrict__ epsp, unsigned short* __restrict__ hgin)
{
    int node = blockIdx.x * 8 + (threadIdx.x >> 5);
    int c4 = threadIdx.x & 31;
    int b0 = base[node], b1 = base[node + 1];
    float s0 = 0, s1 = 0, s2 = 0, s3 = 0;
    float t0 = 0, t1 = 0, t2 = 0, t3 = 0;
    int i = b0;
    for (; i + 1 < b1; i += 2) {
        short4v v0 = *(const short4v*)(xb + (size_t)perm[i] * CC + c4 * 4);
        short4v v1 = *(const short4v*)(xb + (size_t)perm[i + 1] * CC + c4 * 4);
        s0 += b2f((unsigned short)v0[0]); s1 += b2f((unsigned short)v0[1]);
        s2 += b2f((unsigned short)v0[2]); s3 += b2f((unsigned short)v0[3]);
        t0 += b2f((unsigned short)v1[0]); t1 += b2f((unsigned short)v1[1]);
        t2 += b2f((unsigned short)v1[2]); t3 += b2f((unsigned short)v1[3]);
    }
    if (i < b1) {
        short4v v0 = *(const short4v*)(xb + (size_t)perm[i] * CC + c4 * 4);
        s0 += b2f((unsigned short)v0[0]); s1 += b2f((unsigned short)v0[1]);
        s2 += b2f((unsigned short)v0[2]); s3 += b2f((unsigned short)v0[3]);
    }
    float e1 = 1.f + epsp[0];
    short4v xv = *(const short4v*)(xb + (size_t)node * CC + c4 * 4);
    float r0 = fmaf(e1, b2f((unsigned short)xv[0]), s0 + t0);
    float r1 = fmaf(e1, b2f((unsigned short)xv[1]), s1 + t1);
    float r2 = fmaf(e1, b2f((unsigned short)xv[2]), s2 + t2);
    float r3 = fmaf(e1, b2f((unsigned short)xv[3]), s3 + t3);
    short4v o = { f2bf(r0), f2bf(r1), f2bf(r2), f2bf(r3) };
    *(short4v*)(hgin + (size_t)node * CC + c4 * 4) = o;
}

// ---------------------------------------------------------------- register MFMA GEMM, batched loads
// out[r][o] = sum_k A[r][k]*W[o][k] (+bias)(act)(+resid). A,W bf16 in memory.
// 32x128 tile, 4 waves col-split (wave 32x32). grid (NN/32, NCOL/128).
// K-loop: batches of 4 k-slices -> 16 loads issued back-to-back (sched_barrier
// pins them before the MFMAs) so each wave keeps ~256B in flight; 1 latency
// wait per batch instead of 16 (fixes round-6's VGPR=28 serialized chain).
// ACT: 0 none,1 relu,2 softplus. RESID: 0 none,1 bf16,2 fp32.
// OUTM bit0 fp32 store, bit1 bf16 store. by selects (out,outb)/(out_b1,outb_b1).
template<int K, int COLS_VALID, int ACT, bool HAS_BIAS, int RESID, bool STATS, int OUTM>
__global__ __launch_bounds__(256, 4)
void rgemm(const unsigned short* __restrict__ A, int lda,
           const unsigned short* __restrict__ Wb,
           const float* __restrict__ bias,
           const void* __restrict__ resid,
           float* out, float* out_b1,
           unsigned short* outb, unsigned short* outb_b1, int ldo,
           float* ssum, float* ssq)
{
    __shared__ float sred[256];
    const int tid = threadIdx.x;
    const int R0 = blockIdx.x * 32;
    const int by = blockIdx.y;
    const int lane = tid & 63;
    const int wc = tid >> 6;
    const int rql = lane & 15;
    const int kseg = (lane >> 4) * 8;
    constexpr bool FULL = (COLS_VALID % 128) == 0;
    constexpr int NK = K / 32;
    constexpr int NB = (NK > 4) ? 4 : NK;

    if (STATS) { sred[tid] = 0.f; __syncthreads(); }

    floatx4 acc[2][2];
#pragma unroll
    for (int m = 0; m < 2; m++)
#pragma unroll
        for (int n = 0; n < 2; n++)
#pragma unroll
            for (int r = 0; r < 4; r++) acc[m][n][r] = 0.f;

    int colg[2];
    colg[0] = by * 128 + wc * 32 + rql;
    colg[1] = colg[0] + 16;
    const bool v0 = FULL || (colg[0] < COLS_VALID);
    const bool v1 = FULL || (colg[1] < COLS_VALID);
    const unsigned short* ap  = A + (size_t)(R0 + rql) * lda + kseg;
    const unsigned short* ap2 = ap + (size_t)16 * lda;
    const unsigned short* wp0 = Wb + (size_t)colg[0] * K + kseg;
    const unsigned short* wp1 = Wb + (size_t)colg[1] * K + kseg;
    const short8v z8 = { 0, 0, 0, 0, 0, 0, 0, 0 };

#pragma unroll
    for (int kb = 0; kb < NK; kb += NB) {
        short8v a0[NB], a1[NB], b0[NB], b1[NB];
#pragma unroll
        for (int j = 0; j < NB; j++) {
            int kk = kb + j;
            a0[j] = *(const short8v*)(ap  + kk * 32);
            a1[j] = *(const short8v*)(ap2 + kk * 32);
            b0[j] = v0 ? *(const short8v*)(wp0 + kk * 32) : z8;
            b1[j] = v1 ? *(const short8v*)(wp1 + kk * 32) : z8;
        }
        __builtin_amdgcn_sched_barrier(0);   // issue the whole batch before any MFMA
#pragma unroll
        for (int j = 0; j < NB; j++) {
            acc[0][0] = __builtin_amdgcn_mfma_f32_16x16x32_bf16(a0[j], b0[j], acc[0][0], 0, 0, 0);
            acc[0][1] = __builtin_amdgcn_mfma_f32_16x16x32_bf16(a0[j], b1[j], acc[0][1], 0, 0, 0);
            acc[1][0] = __builtin_amdgcn_mfma_f32_16x16x32_bf16(a1[j], b0[j], acc[1][0], 0, 0, 0);
            acc[1][1] = __builtin_amdgcn_mfma_f32_16x16x32_bf16(a1[j], b1[j], acc[1][1], 0, 0, 0);
        }
    }

    float sumn[2] = {0, 0}, sqn[2] = {0, 0};
    float bcol[2];
#pragma unroll
    for (int n = 0; n < 2; n++)
        bcol[n] = (HAS_BIAS && (FULL || colg[n] < COLS_VALID)) ? bias[colg[n]] : 0.f;
    float* op = by ? out_b1 : out;
    unsigned short* opb = by ? outb_b1 : outb;
#pragma unroll
    for (int m = 0; m < 2; m++) {
#pragma unroll
        for (int r = 0; r < 4; r++) {
            int row_g = R0 + m * 16 + ((lane >> 4) << 2) + r;
#pragma unroll
            for (int n = 0; n < 2; n++) {
                float v = acc[m][n][r] + bcol[n];
                if (ACT == 1) v = fmaxf(v, 0.f);
                if (ACT == 2) v = (v > 20.f) ? v : log1pf(__expf(v));
                if (RESID == 1)
                    v += b2f(((const unsigned short*)resid)[(size_t)row_g * CC + colg[n]]);
                if (RESID == 2)
                    v += ((const float*)resid)[(size_t)row_g * CC + colg[n]];
                if (FULL || colg[n] < COLS_VALID) {
                    int cl_ = colg[n] - by * 128;
                    if (OUTM & 1) op[(size_t)row_g * ldo + cl_] = v;
                    if (OUTM & 2) opb[(size_t)row_g * ldo + cl_] = (unsigned short)f2bf(v);
                }
                if (STATS) { sumn[n] += v; sqn[n] += v * v; }
            }
        }
    }
    if (STATS) {
#pragma unroll
        for (int n = 0; n < 2; n++) {
            int cl = wc * 32 + n * 16 + rql;
            atomicAdd(&sred[cl], sumn[n]);
            atomicAdd(&sred[128 + cl], sqn[n]);
        }
        __syncthreads();
        if (tid < 128) {
            atomicAdd(&ssum[tid], sred[tid]);
            atomicAdd(&ssq[tid], sred[128 + tid]);
        }
    }
}

// ---------------------------------------------------------------- depthwise causal conv + silu
__global__ __launch_bounds__(256) void conv_kernel(const float* __restrict__ xs_pre,
    const float* __restrict__ cw, const float* __restrict__ cb,
    unsigned short* __restrict__ xsb)
{
    int t = blockIdx.x * 256 + threadIdx.x;   // NN*32
    int n = t >> 5, c4 = t & 31;
    int l = n & (LL - 1);
    const float* bp = xs_pre + (size_t)n * CC + c4 * 4;
    float4 x0 = *(const float4*)bp;
    float4 x1 = (l >= 1) ? *(const float4*)(bp - CC) : make_float4(0, 0, 0, 0);
    float4 x2 = (l >= 2) ? *(const float4*)(bp - 2 * CC) : make_float4(0, 0, 0, 0);
    float4 x3 = (l >= 3) ? *(const float4*)(bp - 3 * CC) : make_float4(0, 0, 0, 0);
    float4 cbv = *(const float4*)(cb + c4 * 4);
    unsigned short o[4];
#pragma unroll
    for (int j = 0; j < 4; j++) {
        float4 w = *(const float4*)(cw + (c4 * 4 + j) * 4);
        float v = (&cbv.x)[j];
        v = fmaf((&x0.x)[j], w.w, v);
        v = fmaf((&x1.x)[j], w.z, v);
        v = fmaf((&x2.x)[j], w.y, v);
        v = fmaf((&x3.x)[j], w.x, v);
        v = v / (1.f + __expf(-v));
        o[j] = (unsigned short)f2bf(v);
    }
    short4v s = { (short)o[0], (short)o[1], (short)o[2], (short)o[3] };
    *(short4v*)(xsb + (size_t)t * 4) = s;
}

// ---------------------------------------------------------------- scan phase A: per-chunk (sum_dt, q)
__global__ __launch_bounds__(256) void scan_part_kernel(const float* __restrict__ BCp,
    const unsigned short* __restrict__ dtp, const unsigned short* __restrict__ xsp_,
    const float* __restrict__ Alog, float* __restrict__ Q, float* __restrict__ SDT)
{
    __shared__ float Bs[TCH * 16];
    __shared__ float dts[TCH * 64];
    __shared__ float xss[TCH * 64];
    int b = blockIdx.x;
    int g = b >> 4, ch = (b >> 3) & 1, chunk = b & 7;
    int t0 = chunk * TCH;
    int tid = threadIdx.x;
    for (int i4 = tid; i4 < TCH * 4; i4 += 256) {
        int t = i4 >> 2, j4 = i4 & 3;
        *(float4*)&Bs[t * 16 + j4 * 4] =
            *(const float4*)(BCp + (size_t)(g * LL + t0 + t) * 32 + j4 * 4);
    }
    for (int i4 = tid; i4 < TCH * 16; i4 += 256) {
        int t = i4 >> 4, c4 = i4 & 15;
        size_t off = (size_t)(g * LL + t0 + t) * CC + ch * 64 + c4 * 4;
        short4v dv = *(const short4v*)(dtp + off);
        short4v xv = *(const short4v*)(xsp_ + off);
        *(float4*)&dts[t * 64 + c4 * 4] = make_float4(
            b2f((unsigned short)dv[0]), b2f((unsigned short)dv[1]),
            b2f((unsigned short)dv[2]), b2f((unsigned short)dv[3]));
        *(float4*)&xss[t * 64 + c4 * 4] = make_float4(
            b2f((unsigned short)xv[0]), b2f((unsigned short)xv[1]),
            b2f((unsigned short)xv[2]), b2f((unsigned short)xv[3]));
    }
    int cl = tid >> 2, sp = tid & 3;
    int c = ch * 64 + cl;
    float ae[4];
#pragma unroll
    for (int j = 0; j < 4; j++) ae[j] = -__expf(Alog[c * 16 + sp * 4 + j]);
    __syncthreads();
    float q0 = 0, q1 = 0, q2 = 0, q3 = 0, sdt = 0;
    for (int t = TCH - 1; t >= 0; --t) {
        float dtv = dts[t * 64 + cl];
        float xv  = xss[t * 64 + cl];
        float u = dtv * xv;
        const float* bs = Bs + t * 16 + sp * 4;
        q0 = fmaf(__expf(ae[0] * sdt) * u, bs[0], q0);
        q1 = fmaf(__expf(ae[1] * sdt) * u, bs[1], q1);
        q2 = fmaf(__expf(ae[2] * sdt) * u, bs[2], q2);
        q3 = fmaf(__expf(ae[3] * sdt) * u, bs[3], q3);
        sdt += dtv;
    }
    float4* qp = (float4*)(Q + (((size_t)g * NCHUNK + chunk) * CC + c) * 16 + sp * 4);
    *qp = make_float4(q0, q1, q2, q3);
    if (sp == 0) SDT[((size_t)g * NCHUNK + chunk) * CC + c] = sdt;
}

// ---------------------------------------------------------------- scan phase B: combine chunk states
__global__ __launch_bounds__(256) void scan_combine_kernel(const float* __restrict__ Q,
    const float* __restrict__ SDT, const float* __restrict__ Alog, float* __restrict__ Hin)
{
    int idx = blockIdx.x * 256 + threadIdx.x;   // g*2048 + c*16 + s
    int g = idx >> 11;
    int cs = idx & 2047;
    float ae = -__expf(Alog[cs]);
    float h = 0.f;
#pragma unroll
    for (int k = 0; k < NCHUNK; k++) {
        size_t o = ((size_t)g * NCHUNK + k);
        Hin[o * 2048 + cs] = h;
        float sdt = SDT[o * CC + (cs >> 4)];
        h = fmaf(__expf(ae * sdt), h, Q[o * 2048 + cs]);
    }
}

// ---------------------------------------------------------------- scan phase C: forward with init + y
__global__ __launch_bounds__(256) void scan_final_kernel(const float* __restrict__ BCp,
    const unsigned short* __restrict__ dtp, const unsigned short* __restrict__ xsp_,
    const float* __restrict__ zbuf, const float* __restrict__ Alog,
    const float* __restrict__ Dp, const float* __restrict__ Hin,
    unsigned short* __restrict__ y2b)
{
    __shared__ float BCs[TCH * 32];
    __shared__ float dts[TCH * 64];
    __shared__ float xss[TCH * 64];
    int b = blockIdx.x;
    int g = b >> 4, ch = (b >> 3) & 1, chunk = b & 7;
    int t0 = chunk * TCH;
    int tid = threadIdx.x;
    for (int i4 = tid; i4 < TCH * 8; i4 += 256) {
        int t = i4 >> 3, j4 = i4 & 7;
        *(float4*)&BCs[t * 32 + j4 * 4] =
            *(const float4*)(BCp + (size_t)(g * LL + t0 + t) * 32 + j4 * 4);
    }
    for (int i4 = tid; i4 < TCH * 16; i4 += 256) {
        int t = i4 >> 4, c4 = i4 & 15;
        size_t off = (size_t)(g * LL + t0 + t) * CC + ch * 64 + c4 * 4;
        short4v dv = *(const short4v*)(dtp + off);
        short4v xv = *(const short4v*)(xsp_ + off);
        *(float4*)&dts[t * 64 + c4 * 4] = make_float4(
            b2f((unsigned short)dv[0]), b2f((unsigned short)dv[1]),
            b2f((unsigned short)dv[2]), b2f((unsigned short)dv[3]));
        *(float4*)&xss[t * 64 + c4 * 4] = make_float4(
            b2f((unsigned short)xv[0]), b2f((unsigned short)xv[1]),
            b2f((unsigned short)xv[2]), b2f((unsigned short)xv[3]));
    }
    int cl = tid >> 2, sp = tid & 3;
    int c = ch * 64 + cl;
    float ae[4];
#pragma unroll
    for (int j = 0; j < 4; j++) ae[j] = -__expf(Alog[c * 16 + sp * 4 + j]);
    float dpc = Dp[c];
    float4 hv = *(const float4*)(Hin + ((size_t)g * NCHUNK + chunk) * 2048 + c * 16 + sp * 4);
    float h0 = hv.x, h1 = hv.y, h2 = hv.z, h3 = hv.w;
    __syncthreads();
    const float* zg = zbuf + (size_t)(g * LL + t0) * CC + c;
    unsigned short* yg = y2b + (size_t)(g * LL + t0) * CC + c;
    for (int t = 0; t < TCH; t++) {
        float dtv = dts[t * 64 + cl];
        float xv  = xss[t * 64 + cl];
        float u = dtv * xv;
        const float* bc = BCs + t * 32 + sp * 4;
        h0 = fmaf(__expf(dtv * ae[0]), h0, u * bc[0]);
        h1 = fmaf(__expf(dtv * ae[1]), h1, u * bc[1]);
        h2 = fmaf(__expf(dtv * ae[2]), h2, u * bc[2]);
        h3 = fmaf(__expf(dtv * ae[3]), h3, u * bc[3]);
        float y = h0 * bc[16] + h1 * bc[17] + h2 * bc[18] + h3 * bc[19];
        y += __shfl_xor(y, 1);
        y += __shfl_xor(y, 2);
        if (sp == 0) {
            float zv = zg[t * CC];
            float yo = fmaf(dpc, xv, y);
            yg[t * CC] = (unsigned short)f2bf(yo * (zv / (1.f + __expf(-zv))));
        }
    }
}

// ---------------------------------------------------------------- norm (h1,h2) + combine
__global__ __launch_bounds__(256) void norm12_kernel(const float* __restrict__ p1,
    const float* __restrict__ p2, const float* __restrict__ stats,
    const float* g1, const float* be1, const float* g2, const float* be2,
    float* __restrict__ h2out, float* __restrict__ out12,
    unsigned short* __restrict__ out12b)
{
    __shared__ float sc[512];
    int tid = threadIdx.x;
    if (tid < 128) {
        int c = tid;
        const float inv = 1.0f / NN;
        float m1 = stats[c] * inv;
        float v1 = fmaxf(stats[128 + c] * inv - m1 * m1, 0.f);
        float i1 = rsqrtf(v1 + 1e-5f);
        sc[c] = g1[c] * i1; sc[128 + c] = be1[c] - m1 * g1[c] * i1;
        float m2 = stats[256 + c] * inv;
        float v2 = fmaxf(stats[384 + c] * inv - m2 * m2, 0.f);
        float i2 = rsqrtf(v2 + 1e-5f);
        sc[256 + c] = g2[c] * i2; sc[384 + c] = be2[c] - m2 * g2[c] * i2;
    }
    __syncthreads();
    size_t idx = (size_t)blockIdx.x * 256 + tid;   // NN*CC/4
    int c4 = (int)(idx & 31);
    float4 s1 = *(float4*)&sc[c4 * 4];
    float4 t1 = *(float4*)&sc[128 + c4 * 4];
    float4 s2 = *(float4*)&sc[256 + c4 * 4];
    float4 t2 = *(float4*)&sc[384 + c4 * 4];
    float4 a = *(const float4*)(p1 + idx * 4);
    float4 b = *(const float4*)(p2 + idx * 4);
    float4 h, o;
    h.x = fmaf(b.x, s2.x, t2.x); o.x = fmaf(a.x, s1.x, t1.x) + h.x;
    h.y = fmaf(b.y, s2.y, t2.y); o.y = fmaf(a.y, s1.y, t1.y) + h.y;
    h.z = fmaf(b.z, s2.z, t2.z); o.z = fmaf(a.z, s1.z, t1.z) + h.z;
    h.w = fmaf(b.w, s2.w, t2.w); o.w = fmaf(a.w, s1.w, t1.w) + h.w;
    *(float4*)(h2out + idx * 4) = h;
    *(float4*)(out12 + idx * 4) = o;
    short4v ob = { f2bf(o.x), f2bf(o.y), f2bf(o.z), f2bf(o.w) };
    *(short4v*)(out12b + idx * 4) = ob;
}

// ---------------------------------------------------------------- final norm
__global__ __launch_bounds__(256) void norm3_kernel(const float* __restrict__ p3,
    const float* __restrict__ stats, const float* g3, const float* be3,
    float* __restrict__ outp)
{
    __shared__ float sc[256];
    int tid = threadIdx.x;
    if (tid < 128) {
        int c = tid;
        const float inv = 1.0f / NN;
        float m = stats[512 + c] * inv;
        float v = fmaxf(stats[640 + c] * inv - m * m, 0.f);
        float iv = rsqrtf(v + 1e-5f);
        sc[c] = g3[c] * iv; sc[128 + c] = be3[c] - m * g3[c] * iv;
    }
    __syncthreads();
    size_t idx = (size_t)blockIdx.x * 256 + tid;   // NN*CC/4
    int c4 = (int)(idx & 31);
    float4 s = *(float4*)&sc[c4 * 4];
    float4 t = *(float4*)&sc[128 + c4 * 4];
    float4 a = *(const float4*)(p3 + idx * 4);
    float4 o;
    o.x = fmaf(a.x, s.x, t.x); o.y = fmaf(a.y, s.y, t.y);
    o.z = fmaf(a.z, s.z, t.z); o.w = fmaf(a.w, s.w, t.w);
    *(float4*)(outp + idx * 4) = o;
}

extern "C" void kernel_launch(void* const* d_in, const int* in_sizes, int n_in,
                              void* d_out, int out_size, void* d_ws, size_t ws_size,
                              hipStream_t stream)
{
    (void)in_sizes; (void)n_in; (void)out_size; (void)ws_size;
    const float* x    = (const float*)d_in[0];
    const int*   ei   = (const int*)d_in[1];
    const float* eps  = (const float*)d_in[3];
    const float* gw1  = (const float*)d_in[4];
    const float* gb1  = (const float*)d_in[5];
    const float* gw2  = (const float*)d_in[6];
    const float* gb2  = (const float*)d_in[7];
    const float* ipw  = (const float*)d_in[8];
    const float* cw   = (const float*)d_in[9];
    const float* cb   = (const float*)d_in[10];
    const float* xpw  = (const float*)d_in[11];
    const float* dtw  = (const float*)d_in[12];
    const float* dtb  = (const float*)d_in[13];
    const float* Alog = (const float*)d_in[14];
    const float* Dp   = (const float*)d_in[15];
    const float* opw  = (const float*)d_in[16];
    const float* mw1  = (const float*)d_in[17];
    const float* mb1  = (const float*)d_in[18];
    const float* mw2  = (const float*)d_in[19];
    const float* mb2  = (const float*)d_in[20];
    const float* g1   = (const float*)d_in[21];
    const float* be1  = (const float*)d_in[22];
    const float* g2   = (const float*)d_in[23];
    const float* be2  = (const float*)d_in[24];
    const float* g3   = (const float*)d_in[25];
    const float* be3  = (const float*)d_in[26];

    float* outp = (float*)d_out;                       // final out [N*C]
    float* h2o  = outp + (size_t)NN * CC;              // h2 [N*C]
    float* p1 = outp;
    float* p2 = h2o;

    const size_t M1 = 1u << 20;
    float* ws = (float*)d_ws;
    float*  xs_pre = ws;                                  // 4M fl (later Q+Hin, p3)
    float*  zbuf   = ws + 4 * M1;                         // 4M fl (later out12)
    unsigned short* dtb_buf = (unsigned short*)(ws + 8 * M1);   // 4M bf16 (later out12b)
    unsigned short* xb      = (unsigned short*)(ws + 10 * M1);  // 4M bf16
    unsigned short* hgin    = (unsigned short*)(ws + 12 * M1);  // 4M bf16 (later y2b)
    unsigned short* t1b     = (unsigned short*)(ws + 14 * M1);  // 4M bf16 (later xsb)
    unsigned short* t2b     = (unsigned short*)(ws + 16 * M1);  // 8M bf16
    float*  BC     = ws + 20 * M1;                        // 1M fl
    float*  stats  = ws + 21 * M1;                        // 768
    int*    cnt    = (int*)(stats + 768);
    int*    baseA  = cnt + NN;
    int*    cursor = baseA + NN + 1;
    int*    perm   = cursor + NN;
    float*  SDT    = (float*)(perm + EE);                 // 131072
    unsigned short* wbase = (unsigned short*)(SDT + 131072);
    unsigned short* gw1b = wbase;                // 16384
    unsigned short* gw2b = wbase + 16384;
    unsigned short* ipwb = wbase + 32768;        // 32768
    unsigned short* wdtb = wbase + 65536;        // 16384
    unsigned short* xpwb = wbase + 81920;        // 4096
    unsigned short* opwb = wbase + 86016;        // 16384
    unsigned short* mw1b = wbase + 102400;       // 32768
    unsigned short* mw2b = wbase + 135168;       // 32768

    float* Qbuf = xs_pre;                  // 2M fl
    float* Hin  = xs_pre + 2 * M1;         // 2M fl
    float* p3   = xs_pre;
    float* out12 = zbuf;
    unsigned short* out12b = dtb_buf;
    unsigned short* y2b = hgin;
    unsigned short* xsb = t1b;

    hipMemsetAsync(cnt, 0, NN * sizeof(int), stream);
    hipMemsetAsync(stats, 0, 768 * sizeof(float), stream);

    // input + weight bf16 conversion
    wcvt_kernel<<<dim3(NN * CC / 8 / 256), 256, 0, stream>>>(x, xb);
    wcvt_kernel<<<dim3(8), 256, 0, stream>>>(gw1, gw1b);
    wcvt_kernel<<<dim3(8), 256, 0, stream>>>(gw2, gw2b);
    wcvt_kernel<<<dim3(16), 256, 0, stream>>>(ipw, ipwb);
    wcvt_kernel<<<dim3(2), 256, 0, stream>>>(xpw + 8 * 128, xpwb);
    wcvt_kernel<<<dim3(8), 256, 0, stream>>>(opw, opwb);
    wcvt_kernel<<<dim3(16), 256, 0, stream>>>(mw1, mw1b);
    wcvt_kernel<<<dim3(16), 256, 0, stream>>>(mw2, mw2b);
    wdt_kernel<<<dim3(64), 256, 0, stream>>>(dtw, xpw, wdtb);

    // CSR build + gather (emits hgin = (1+eps)x + agg in bf16)
    hist_kernel<<<dim3(EE / 256), 256, 0, stream>>>(ei, cnt);
    scan32k_kernel<<<dim3(1), 1024, 0, stream>>>(cnt, baseA, cursor);
    permute_kernel<<<dim3(EE / 256), 256, 0, stream>>>(ei, cursor, perm);
    gather_kernel<<<dim3(NN / 8), 256, 0, stream>>>(perm, baseA, xb, eps, hgin);

    // GIN MLP: t1b = relu(hgin@gw1^T+gb1) ; p1 = t1b@gw2^T+gb2 + x (stats S1)
    rgemm<128, 128, 1, true, 0, false, 2><<<dim3(1024, 1), 256, 0, stream>>>(
        hgin, 128, gw1b, gb1, nullptr, nullptr, nullptr, t1b, nullptr, 128, nullptr, nullptr);
    rgemm<128, 128, 0, true, 1, true, 1><<<dim3(1024, 1), 256, 0, stream>>>(
        t1b, 128, gw2b, gb2, xb, p1, nullptr, nullptr, nullptr, 128, stats + 0, stats + 128);

    // in_proj -> xs_pre (cols 0-127) / zbuf (cols 128-255)
    rgemm<128, 256, 0, false, 0, false, 1><<<dim3(1024, 2), 256, 0, stream>>>(
        xb, 128, ipwb, nullptr, nullptr, xs_pre, zbuf, nullptr, nullptr, 128, nullptr, nullptr);
    conv_kernel<<<dim3(NN * 32 / 256), 256, 0, stream>>>(xs_pre, cw, cb, xsb);

    // dt = softplus(xs@Wdt^T + dtb) (bf16); BC = xs@xpw[8:40]^T
    rgemm<128, 128, 2, true, 0, false, 2><<<dim3(1024, 1), 256, 0, stream>>>(
        xsb, 128, wdtb, dtb, nullptr, nullptr, nullptr, dtb_buf, nullptr, 128, nullptr, nullptr);
    rgemm<128, 32, 0, false, 0, false, 1><<<dim3(1024, 1), 256, 0, stream>>>(
        xsb, 128, xpwb, nullptr, nullptr, BC, nullptr, nullptr, nullptr, 32, nullptr, nullptr);

    // chunked selective scan
    scan_part_kernel<<<dim3(GG * 16), 256, 0, stream>>>(BC, dtb_buf, xsb, Alog, Qbuf, SDT);
    scan_combine_kernel<<<dim3(GG * 2048 / 256), 256, 0, stream>>>(Qbuf, SDT, Alog, Hin);
    scan_final_kernel<<<dim3(GG * 16), 256, 0, stream>>>(BC, dtb_buf, xsb, zbuf, Alog, Dp, Hin, y2b);

    // out_proj: p2 = y2b@opw^T + x (stats S2)
    rgemm<128, 128, 0, false, 1, true, 1><<<dim3(1024, 1), 256, 0, stream>>>(
        y2b, 128, opwb, nullptr, xb, p2, nullptr, nullptr, nullptr, 128, stats + 256, stats + 384);

    // norms 1,2 + combine
    norm12_kernel<<<dim3(NN * CC / 4 / 256), 256, 0, stream>>>(
        p1, p2, stats, g1, be1, g2, be2, h2o, out12, out12b);

    // MLP: t2b = relu(out12b@mw1^T+mb1) ; p3 = t2b@mw2^T+mb2 + out12 (stats S3)
    rgemm<128, 256, 1, true, 0, false, 2><<<dim3(1024, 2), 256, 0, stream>>>(
        out12b, 128, mw1b, mb1, nullptr, nullptr, nullptr, t2b, t2b + 128, 256, nullptr, nullptr);
    rgemm<256, 128, 0, true, 2, true, 1><<<dim3(1024, 1), 256, 0, stream>>>(
        t2b, 256, mw2b, mb2, out12, p3, nullptr, nullptr, nullptr, 128, stats + 512, stats + 640);

    norm3_kernel<<<dim3(NN * CC / 4 / 256), 256, 0, stream>>>(p3, stats, g3, be3, outp);
}

// Round 8
// 321.865 us; speedup vs baseline: 2.1369x; 1.1773x over previous
//
#include <hip/hip_runtime.h>
#include <hip/hip_bf16.h>

#define NN 32768
#define GG 128
#define LL 256
#define CC 128
#define EE 524288
#define NCHUNK 8
#define TCH 32

typedef __attribute__((ext_vector_type(8))) short short8v;
typedef __attribute__((ext_vector_type(4))) short short4v;
typedef __attribute__((ext_vector_type(4))) float floatx4;

__device__ inline short f2bf(float f) {
    __hip_bfloat16 h = __float2bfloat16(f);
    short s; __builtin_memcpy(&s, &h, 2); return s;
}
__device__ inline float b2f(unsigned short u) {
    unsigned v = ((unsigned)u) << 16; float f; __builtin_memcpy(&f, &v, 4); return f;
}
__device__ inline floatx4 mfma16(short8v a, short8v b, floatx4 c) {
    return __builtin_amdgcn_mfma_f32_16x16x32_bf16(a, b, c, 0, 0, 0);
}

// ---------------------------------------------------------------- fp32 -> bf16 bulk convert
__global__ __launch_bounds__(256) void wcvt_kernel(const float* __restrict__ src,
    unsigned short* __restrict__ dst)
{
    size_t i = (size_t)blockIdx.x * 256 + threadIdx.x;
    float4 a = *(const float4*)(src + i * 8);
    float4 b = *(const float4*)(src + i * 8 + 4);
    short8v s = { f2bf(a.x), f2bf(a.y), f2bf(a.z), f2bf(a.w),
                  f2bf(b.x), f2bf(b.y), f2bf(b.z), f2bf(b.w) };
    *(short8v*)(dst + i * 8) = s;
}

// ---------------------------------------------------------------- Wdt = dtw @ xpw[:8] (bf16 out)
__global__ __launch_bounds__(256) void wdt_kernel(const float* __restrict__ dtw,
    const float* __restrict__ xpw, unsigned short* __restrict__ Wdtb)
{
    int i = blockIdx.x * 256 + threadIdx.x;   // 16384
    int d = i >> 7, c = i & 127;
    float s = 0.f;
#pragma unroll
    for (int r = 0; r < 8; r++) s = fmaf(dtw[d * 8 + r], xpw[r * 128 + c], s);
    Wdtb[i] = (unsigned short)f2bf(s);
}

// ---------------------------------------------------------------- edge histogram
__global__ __launch_bounds__(256) void hist_kernel(const int* __restrict__ ei,
    int* __restrict__ cnt)
{
    int e = blockIdx.x * 256 + threadIdx.x;
    atomicAdd(&cnt[ei[EE + e]], 1);
}

// ---------------------------------------------------------------- exclusive scan of 32768 counts
__global__ __launch_bounds__(1024) void scan32k_kernel(const int* __restrict__ cnt,
    int* __restrict__ base, int* __restrict__ cursor)
{
    __shared__ int part[1024];
    int tid = threadIdx.x;
    int local[32];
    int s = 0;
#pragma unroll
    for (int j = 0; j < 32; j++) { local[j] = cnt[tid * 32 + j]; s += local[j]; }
    part[tid] = s;
    __syncthreads();
    for (int off = 1; off < 1024; off <<= 1) {
        int v = (tid >= off) ? part[tid - off] : 0;
        __syncthreads();
        part[tid] += v;
        __syncthreads();
    }
    int run = part[tid] - s;
#pragma unroll
    for (int j = 0; j < 32; j++) {
        base[tid * 32 + j] = run;
        cursor[tid * 32 + j] = run;
        run += local[j];
    }
    if (tid == 0) base[NN] = EE;
}

// ---------------------------------------------------------------- permute srcs into dst-sorted order
__global__ __launch_bounds__(256) void permute_kernel(const int* __restrict__ ei,
    int* __restrict__ cursor, int* __restrict__ perm)
{
    int e = blockIdx.x * 256 + threadIdx.x;
    int dst = ei[EE + e];
    int pos = atomicAdd(&cursor[dst], 1);
    perm[pos] = ei[e];
}

// ---------------------------------------------------------------- gather-sum + (1+eps)x, bf16 in/out
__global__ __launch_bounds__(256) void gather_kernel(const int* __restrict__ perm,
    const int* __restrict__ base, const unsigned short* __restrict__ xb,
    const float* __restrict__ epsp, unsigned short* __restrict__ hgin)
{
    int node = blockIdx.x * 8 + (threadIdx.x >> 5);
    int c4 = threadIdx.x & 31;
    int b0 = base[node], b1 = base[node + 1];
    float s0 = 0, s1 = 0, s2 = 0, s3 = 0;
    float t0 = 0, t1 = 0, t2 = 0, t3 = 0;
    int i = b0;
    for (; i + 1 < b1; i += 2) {
        short4v v0 = *(const short4v*)(xb + (size_t)perm[i] * CC + c4 * 4);
        short4v v1 = *(const short4v*)(xb + (size_t)perm[i + 1] * CC + c4 * 4);
        s0 += b2f((unsigned short)v0[0]); s1 += b2f((unsigned short)v0[1]);
        s2 += b2f((unsigned short)v0[2]); s3 += b2f((unsigned short)v0[3]);
        t0 += b2f((unsigned short)v1[0]); t1 += b2f((unsigned short)v1[1]);
        t2 += b2f((unsigned short)v1[2]); t3 += b2f((unsigned short)v1[3]);
    }
    if (i < b1) {
        short4v v0 = *(const short4v*)(xb + (size_t)perm[i] * CC + c4 * 4);
        s0 += b2f((unsigned short)v0[0]); s1 += b2f((unsigned short)v0[1]);
        s2 += b2f((unsigned short)v0[2]); s3 += b2f((unsigned short)v0[3]);
    }
    float e1 = 1.f + epsp[0];
    short4v xv = *(const short4v*)(xb + (size_t)node * CC + c4 * 4);
    float r0 = fmaf(e1, b2f((unsigned short)xv[0]), s0 + t0);
    float r1 = fmaf(e1, b2f((unsigned short)xv[1]), s1 + t1);
    float r2 = fmaf(e1, b2f((unsigned short)xv[2]), s2 + t2);
    float r3 = fmaf(e1, b2f((unsigned short)xv[3]), s3 + t3);
    short4v o = { f2bf(r0), f2bf(r1), f2bf(r2), f2bf(r3) };
    *(short4v*)(hgin + (size_t)node * CC + c4 * 4) = o;
}

// ---------------------------------------------------------------- single register-GEMM, W hoisted
// out[r][o] = sum_k A[r][k]*W[o][k] (+bias)(act)(+resid). lda == K. All cols valid.
// 32x128 tile (4 waves x 32 cols), 2 tiles/block grid-stride, A double-buffered.
// ACT: 0 none,1 relu,2 softplus. RESID: 0 none,1 bf16. OUTM bit0 fp32, bit1 bf16.
template<int K, int ACT, bool HAS_BIAS, int RESID, bool STATS, int OUTM>
__global__ __launch_bounds__(256)
void rgemm(const unsigned short* __restrict__ A,
           const unsigned short* __restrict__ Wb,
           const float* __restrict__ bias,
           const unsigned short* __restrict__ residb,
           float* out, float* out_b1,
           unsigned short* outb, unsigned short* outb_b1, int ldo,
           float* ssum, float* ssq)
{
    __shared__ float sred[256];
    const int tid = threadIdx.x;
    const int by = blockIdx.y;
    const int lane = tid & 63;
    const int wc = tid >> 6;
    const int rql = lane & 15;
    const int kseg = (lane >> 4) * 8;
    const int rsub = (lane >> 4) * 4;
    constexpr int NK = K / 32;

    if (STATS) sred[tid] = 0.f;

    int colg[2];
    colg[0] = by * 128 + wc * 32 + rql;
    colg[1] = colg[0] + 16;
    short8v w0[NK], w1[NK];
    {
        const unsigned short* wp0 = Wb + (size_t)colg[0] * K + kseg;
        const unsigned short* wp1 = Wb + (size_t)colg[1] * K + kseg;
#pragma unroll
        for (int kk = 0; kk < NK; kk++) {
            w0[kk] = *(const short8v*)(wp0 + kk * 32);
            w1[kk] = *(const short8v*)(wp1 + kk * 32);
        }
    }
    float bcol[2] = {0.f, 0.f};
    if (HAS_BIAS) { bcol[0] = bias[colg[0]]; bcol[1] = bias[colg[1]]; }
    float ssumr[2] = {0.f, 0.f}, ssqr[2] = {0.f, 0.f};

    short8v abuf[2][NK][2];
    {
        const unsigned short* ap = A + (size_t)(blockIdx.x * 32 + rql) * K + kseg;
#pragma unroll
        for (int kk = 0; kk < NK; kk++) {
            abuf[0][kk][0] = *(const short8v*)(ap + kk * 32);
            abuf[0][kk][1] = *(const short8v*)(ap + 16 * K + kk * 32);
        }
    }
    float* op = by ? out_b1 : out;
    unsigned short* opb = by ? outb_b1 : outb;

#pragma unroll
    for (int t = 0; t < 2; t++) {
        const int R0 = (blockIdx.x + t * 512) * 32;
        if (t == 0) {
            const unsigned short* ap = A + (size_t)((blockIdx.x + 512) * 32 + rql) * K + kseg;
#pragma unroll
            for (int kk = 0; kk < NK; kk++) {
                abuf[1][kk][0] = *(const short8v*)(ap + kk * 32);
                abuf[1][kk][1] = *(const short8v*)(ap + 16 * K + kk * 32);
            }
        }
        __builtin_amdgcn_sched_barrier(0);
        floatx4 acc[2][2];
#pragma unroll
        for (int m = 0; m < 2; m++)
#pragma unroll
            for (int n = 0; n < 2; n++)
#pragma unroll
                for (int r = 0; r < 4; r++) acc[m][n][r] = 0.f;
#pragma unroll
        for (int kk = 0; kk < NK; kk++) {
            acc[0][0] = mfma16(abuf[t][kk][0], w0[kk], acc[0][0]);
            acc[0][1] = mfma16(abuf[t][kk][0], w1[kk], acc[0][1]);
            acc[1][0] = mfma16(abuf[t][kk][1], w0[kk], acc[1][0]);
            acc[1][1] = mfma16(abuf[t][kk][1], w1[kk], acc[1][1]);
        }
#pragma unroll
        for (int m = 0; m < 2; m++) {
#pragma unroll
            for (int r = 0; r < 4; r++) {
                int row_g = R0 + m * 16 + rsub + r;
#pragma unroll
                for (int n = 0; n < 2; n++) {
                    float v = acc[m][n][r] + bcol[n];
                    if (ACT == 1) v = fmaxf(v, 0.f);
                    if (ACT == 2) v = (v > 20.f) ? v : log1pf(__expf(v));
                    if (RESID == 1)
                        v += b2f(residb[(size_t)row_g * CC + colg[n]]);
                    int cl_ = colg[n] - by * 128;
                    if (OUTM & 1) op[(size_t)row_g * ldo + cl_] = v;
                    if (OUTM & 2) opb[(size_t)row_g * ldo + cl_] = (unsigned short)f2bf(v);
                    if (STATS) { ssumr[n] += v; ssqr[n] += v * v; }
                }
            }
        }
    }
    if (STATS) {
        __syncthreads();
#pragma unroll
        for (int n = 0; n < 2; n++) {
            int cl = wc * 32 + n * 16 + rql;
            atomicAdd(&sred[cl], ssumr[n]);
            atomicAdd(&sred[128 + cl], ssqr[n]);
        }
        __syncthreads();
        if (tid < 128) {
            atomicAdd(&ssum[tid], sred[tid]);
            atomicAdd(&ssq[tid], sred[128 + tid]);
        }
    }
}

// ---------------------------------------------------------------- fused 2-layer GEMM (LDS handoff)
// layer1: mid = relu(A @ W1^T + b1)  [32 x KMID]  -> LDS (bf16)
// layer2: out = mid @ W2^T + b2 + resid           -> fp32 + BN stats
template<int KMID>
__global__ __launch_bounds__(256)
void fused2(const unsigned short* __restrict__ A,
            const unsigned short* __restrict__ W1b, const float* __restrict__ b1,
            const unsigned short* __restrict__ W2b, const float* __restrict__ b2,
            const unsigned short* __restrict__ residb,
            float* __restrict__ outp,
            float* ssum, float* ssq)
{
    constexpr int NF1 = KMID / 64;    // layer-1 col frags per wave
    constexpr int NK1 = 4;            // K1 = 128
    constexpr int NK2 = KMID / 32;
    constexpr int LDSW = KMID + 8;
    __shared__ unsigned short lds[2][32 * LDSW];
    __shared__ float sred[256];
    const int tid = threadIdx.x;
    const int lane = tid & 63;
    const int wc = tid >> 6;
    const int rql = lane & 15;
    const int kseg = (lane >> 4) * 8;
    const int rsub = (lane >> 4) * 4;

    sred[tid] = 0.f;

    short8v w1r[NF1][NK1];
    int colg1[NF1];
    float b1c[NF1];
#pragma unroll
    for (int f = 0; f < NF1; f++) {
        colg1[f] = wc * (16 * NF1) + f * 16 + rql;
        const unsigned short* wp = W1b + (size_t)colg1[f] * 128 + kseg;
#pragma unroll
        for (int kk = 0; kk < NK1; kk++) w1r[f][kk] = *(const short8v*)(wp + kk * 32);
        b1c[f] = b1[colg1[f]];
    }
    int colg2[2];
    colg2[0] = wc * 32 + rql;
    colg2[1] = colg2[0] + 16;
    float b2c[2] = { b2[colg2[0]], b2[colg2[1]] };
    float ssumr[2] = {0.f, 0.f}, ssqr[2] = {0.f, 0.f};

    short8v abuf[2][NK1][2];
    {
        const unsigned short* ap = A + (size_t)(blockIdx.x * 32 + rql) * 128 + kseg;
#pragma unroll
        for (int kk = 0; kk < NK1; kk++) {
            abuf[0][kk][0] = *(const short8v*)(ap + kk * 32);
            abuf[0][kk][1] = *(const short8v*)(ap + 16 * 128 + kk * 32);
        }
    }
    __syncthreads();   // sred zero visible before any atomics later

#pragma unroll
    for (int t = 0; t < 2; t++) {
        const int R0 = (blockIdx.x + t * 512) * 32;
        // ---- layer 1 ----
        floatx4 acc1[2][NF1];
#pragma unroll
        for (int m = 0; m < 2; m++)
#pragma unroll
            for (int f = 0; f < NF1; f++)
#pragma unroll
                for (int r = 0; r < 4; r++) acc1[m][f][r] = 0.f;
#pragma unroll
        for (int kk = 0; kk < NK1; kk++)
#pragma unroll
            for (int m = 0; m < 2; m++)
#pragma unroll
                for (int f = 0; f < NF1; f++)
                    acc1[m][f] = mfma16(abuf[t][kk][m], w1r[f][kk], acc1[m][f]);
        unsigned short* L = &lds[t][0];
#pragma unroll
        for (int m = 0; m < 2; m++)
#pragma unroll
            for (int f = 0; f < NF1; f++)
#pragma unroll
                for (int r = 0; r < 4; r++) {
                    float v = fmaxf(acc1[m][f][r] + b1c[f], 0.f);
                    L[(m * 16 + rsub + r) * LDSW + colg1[f]] = (unsigned short)f2bf(v);
                }
        __syncthreads();
        // ---- prefetch next A tile (overlaps W2 loads + layer-2 compute) ----
        if (t == 0) {
            const unsigned short* ap = A + (size_t)((blockIdx.x + 512) * 32 + rql) * 128 + kseg;
#pragma unroll
            for (int kk = 0; kk < NK1; kk++) {
                abuf[1][kk][0] = *(const short8v*)(ap + kk * 32);
                abuf[1][kk][1] = *(const short8v*)(ap + 16 * 128 + kk * 32);
            }
        }
        // ---- layer 2 ----
        short8v w2a[NK2], w2b[NK2];
        {
            const unsigned short* wq0 = W2b + (size_t)colg2[0] * KMID + kseg;
            const unsigned short* wq1 = W2b + (size_t)colg2[1] * KMID + kseg;
#pragma unroll
            for (int kk = 0; kk < NK2; kk++) {
                w2a[kk] = *(const short8v*)(wq0 + kk * 32);
                w2b[kk] = *(const short8v*)(wq1 + kk * 32);
            }
        }
        floatx4 acc2[2][2];
#pragma unroll
        for (int m = 0; m < 2; m++)
#pragma unroll
            for (int n = 0; n < 2; n++)
#pragma unroll
                for (int r = 0; r < 4; r++) acc2[m][n][r] = 0.f;
#pragma unroll
        for (int kk = 0; kk < NK2; kk++) {
            short8v a2lo = *(const short8v*)&L[rql * LDSW + kseg + kk * 32];
            short8v a2hi = *(const short8v*)&L[(rql + 16) * LDSW + kseg + kk * 32];
            acc2[0][0] = mfma16(a2lo, w2a[kk], acc2[0][0]);
            acc2[0][1] = mfma16(a2lo, w2b[kk], acc2[0][1]);
            acc2[1][0] = mfma16(a2hi, w2a[kk], acc2[1][0]);
            acc2[1][1] = mfma16(a2hi, w2b[kk], acc2[1][1]);
        }
#pragma unroll
        for (int m = 0; m < 2; m++) {
#pragma unroll
            for (int r = 0; r < 4; r++) {
                int row_g = R0 + m * 16 + rsub + r;
#pragma unroll
                for (int n = 0; n < 2; n++) {
                    float v = acc2[m][n][r] + b2c[n];
                    v += b2f(residb[(size_t)row_g * CC + colg2[n]]);
                    outp[(size_t)row_g * CC + colg2[n]] = v;
                    ssumr[n] += v; ssqr[n] += v * v;
                }
            }
        }
    }
    __syncthreads();
#pragma unroll
    for (int n = 0; n < 2; n++) {
        atomicAdd(&sred[colg2[n]], ssumr[n]);
        atomicAdd(&sred[128 + colg2[n]], ssqr[n]);
    }
    __syncthreads();
    if (tid < 128) {
        atomicAdd(&ssum[tid], sred[tid]);
        atomicAdd(&ssq[tid], sred[128 + tid]);
    }
}

// ---------------------------------------------------------------- fused dt + BC GEMM (5 waves)
// waves 0-3: dt = softplus(xs@Wdt^T + dtb) -> bf16 [NN][128]
// wave 4:    BC = xs@xpw[8:40]^T           -> fp32 [NN][32]
__global__ __launch_bounds__(320)
void dtbc_kernel(const unsigned short* __restrict__ A,
                 const unsigned short* __restrict__ Wdtb, const float* __restrict__ dtb,
                 const unsigned short* __restrict__ xpwb,
                 unsigned short* __restrict__ dtout, float* __restrict__ BCout)
{
    const int tid = threadIdx.x;
    const int lane = tid & 63;
    const int wc = tid >> 6;     // 0..4
    const int rql = lane & 15;
    const int kseg = (lane >> 4) * 8;
    const int rsub = (lane >> 4) * 4;
    const bool isBC = (wc == 4);

    int col0 = isBC ? rql : (wc * 32 + rql);
    int col1 = col0 + 16;
    const unsigned short* Wb = isBC ? xpwb : Wdtb;
    short8v w0[4], w1[4];
    {
        const unsigned short* wp0 = Wb + (size_t)col0 * 128 + kseg;
        const unsigned short* wp1 = Wb + (size_t)col1 * 128 + kseg;
#pragma unroll
        for (int kk = 0; kk < 4; kk++) {
            w0[kk] = *(const short8v*)(wp0 + kk * 32);
            w1[kk] = *(const short8v*)(wp1 + kk * 32);
        }
    }
    float bc0 = isBC ? 0.f : dtb[col0];
    float bc1 = isBC ? 0.f : dtb[col1];

    short8v abuf[2][4][2];
    {
        const unsigned short* ap = A + (size_t)(blockIdx.x * 32 + rql) * 128 + kseg;
#pragma unroll
        for (int kk = 0; kk < 4; kk++) {
            abuf[0][kk][0] = *(const short8v*)(ap + kk * 32);
            abuf[0][kk][1] = *(const short8v*)(ap + 16 * 128 + kk * 32);
        }
    }
#pragma unroll
    for (int t = 0; t < 2; t++) {
        const int R0 = (blockIdx.x + t * 512) * 32;
        if (t == 0) {
            const unsigned short* ap = A + (size_t)((blockIdx.x + 512) * 32 + rql) * 128 + kseg;
#pragma unroll
            for (int kk = 0; kk < 4; kk++) {
                abuf[1][kk][0] = *(const short8v*)(ap + kk * 32);
                abuf[1][kk][1] = *(const short8v*)(ap + 16 * 128 + kk * 32);
            }
        }
        __builtin_amdgcn_sched_barrier(0);
        floatx4 acc[2][2];
#pragma unroll
        for (int m = 0; m < 2; m++)
#pragma unroll
            for (int n = 0; n < 2; n++)
#pragma unroll
                for (int r = 0; r < 4; r++) acc[m][n][r] = 0.f;
#pragma unroll
        for (int kk = 0; kk < 4; kk++) {
            acc[0][0] = mfma16(abuf[t][kk][0], w0[kk], acc[0][0]);
            acc[0][1] = mfma16(abuf[t][kk][0], w1[kk], acc[0][1]);
            acc[1][0] = mfma16(abuf[t][kk][1], w0[kk], acc[1][0]);
            acc[1][1] = mfma16(abuf[t][kk][1], w1[kk], acc[1][1]);
        }
#pragma unroll
        for (int m = 0; m < 2; m++) {
#pragma unroll
            for (int r = 0; r < 4; r++) {
                int row_g = R0 + m * 16 + rsub + r;
                float v0 = acc[m][0][r] + bc0;
                float v1 = acc[m][1][r] + bc1;
                if (!isBC) {
                    v0 = (v0 > 20.f) ? v0 : log1pf(__expf(v0));
                    v1 = (v1 > 20.f) ? v1 : log1pf(__expf(v1));
                    dtout[(size_t)row_g * 128 + col0] = (unsigned short)f2bf(v0);
                    dtout[(size_t)row_g * 128 + col1] = (unsigned short)f2bf(v1);
                } else {
                    BCout[(size_t)row_g * 32 + col0] = v0;
                    BCout[(size_t)row_g * 32 + col1] = v1;
                }
            }
        }
    }
}

// ---------------------------------------------------------------- depthwise causal conv + silu (bf16 in/out)
__global__ __launch_bounds__(256) void conv_kernel(const unsigned short* __restrict__ xs_preb,
    const float* __restrict__ cw, const float* __restrict__ cb,
    unsigned short* __restrict__ xsb)
{
    int t = blockIdx.x * 256 + threadIdx.x;   // NN*32
    int n = t >> 5, c4 = t & 31;
    int l = n & (LL - 1);
    const unsigned short* bp = xs_preb + (size_t)n * CC + c4 * 4;
    short4v z4 = { 0, 0, 0, 0 };
    short4v x0 = *(const short4v*)bp;
    short4v x1 = (l >= 1) ? *(const short4v*)(bp - CC) : z4;
    short4v x2 = (l >= 2) ? *(const short4v*)(bp - 2 * CC) : z4;
    short4v x3 = (l >= 3) ? *(const short4v*)(bp - 3 * CC) : z4;
    float4 cbv = *(const float4*)(cb + c4 * 4);
    unsigned short o[4];
#pragma unroll
    for (int j = 0; j < 4; j++) {
        float4 w = *(const float4*)(cw + (c4 * 4 + j) * 4);
        float v = (&cbv.x)[j];
        v = fmaf(b2f((unsigned short)x0[j]), w.w, v);
        v = fmaf(b2f((unsigned short)x1[j]), w.z, v);
        v = fmaf(b2f((unsigned short)x2[j]), w.y, v);
        v = fmaf(b2f((unsigned short)x3[j]), w.x, v);
        v = v / (1.f + __expf(-v));
        o[j] = (unsigned short)f2bf(v);
    }
    short4v s = { (short)o[0], (short)o[1], (short)o[2], (short)o[3] };
    *(short4v*)(xsb + (size_t)t * 4) = s;
}

// ---------------------------------------------------------------- scan phase A: per-chunk (sum_dt, q)
__global__ __launch_bounds__(256) void scan_part_kernel(const float* __restrict__ BCp,
    const unsigned short* __restrict__ dtp, const unsigned short* __restrict__ xsp_,
    const float* __restrict__ Alog, float* __restrict__ Q, float* __restrict__ SDT)
{
    __shared__ float Bs[TCH * 16];
    __shared__ float dts[TCH * 64];
    __shared__ float xss[TCH * 64];
    int b = blockIdx.x;
    int g = b >> 4, ch = (b >> 3) & 1, chunk = b & 7;
    int t0 = chunk * TCH;
    int tid = threadIdx.x;
    for (int i4 = tid; i4 < TCH * 4; i4 += 256) {
        int t = i4 >> 2, j4 = i4 & 3;
        *(float4*)&Bs[t * 16 + j4 * 4] =
            *(const float4*)(BCp + (size_t)(g * LL + t0 + t) * 32 + j4 * 4);
    }
    for (int i4 = tid; i4 < TCH * 16; i4 += 256) {
        int t = i4 >> 4, c4 = i4 & 15;
        size_t off = (size_t)(g * LL + t0 + t) * CC + ch * 64 + c4 * 4;
        short4v dv = *(const short4v*)(dtp + off);
        short4v xv = *(const short4v*)(xsp_ + off);
        *(float4*)&dts[t * 64 + c4 * 4] = make_float4(
            b2f((unsigned short)dv[0]), b2f((unsigned short)dv[1]),
            b2f((unsigned short)dv[2]), b2f((unsigned short)dv[3]));
        *(float4*)&xss[t * 64 + c4 * 4] = make_float4(
            b2f((unsigned short)xv[0]), b2f((unsigned short)xv[1]),
            b2f((unsigned short)xv[2]), b2f((unsigned short)xv[3]));
    }
    int cl = tid >> 2, sp = tid & 3;
    int c = ch * 64 + cl;
    float ae[4];
#pragma unroll
    for (int j = 0; j < 4; j++) ae[j] = -__expf(Alog[c * 16 + sp * 4 + j]);
    __syncthreads();
    float q0 = 0, q1 = 0, q2 = 0, q3 = 0, sdt = 0;
    for (int t = TCH - 1; t >= 0; --t) {
        float dtv = dts[t * 64 + cl];
        float xv  = xss[t * 64 + cl];
        float u = dtv * xv;
        const float* bs = Bs + t * 16 + sp * 4;
        q0 = fmaf(__expf(ae[0] * sdt) * u, bs[0], q0);
        q1 = fmaf(__expf(ae[1] * sdt) * u, bs[1], q1);
        q2 = fmaf(__expf(ae[2] * sdt) * u, bs[2], q2);
        q3 = fmaf(__expf(ae[3] * sdt) * u, bs[3], q3);
        sdt += dtv;
    }
    float4* qp = (float4*)(Q + (((size_t)g * NCHUNK + chunk) * CC + c) * 16 + sp * 4);
    *qp = make_float4(q0, q1, q2, q3);
    if (sp == 0) SDT[((size_t)g * NCHUNK + chunk) * CC + c] = sdt;
}

// ---------------------------------------------------------------- scan phase B: combine chunk states
__global__ __launch_bounds__(256) void scan_combine_kernel(const float* __restrict__ Q,
    const float* __restrict__ SDT, const float* __restrict__ Alog, float* __restrict__ Hin)
{
    int idx = blockIdx.x * 256 + threadIdx.x;   // g*2048 + c*16 + s
    int g = idx >> 11;
    int cs = idx & 2047;
    float ae = -__expf(Alog[cs]);
    float h = 0.f;
#pragma unroll
    for (int k = 0; k < NCHUNK; k++) {
        size_t o = ((size_t)g * NCHUNK + k);
        Hin[o * 2048 + cs] = h;
        float sdt = SDT[o * CC + (cs >> 4)];
        h = fmaf(__expf(ae * sdt), h, Q[o * 2048 + cs]);
    }
}

// ---------------------------------------------------------------- scan phase C: forward with init + y
__global__ __launch_bounds__(256) void scan_final_kernel(const float* __restrict__ BCp,
    const unsigned short* __restrict__ dtp, const unsigned short* __restrict__ xsp_,
    const unsigned short* __restrict__ zb, const float* __restrict__ Alog,
    const float* __restrict__ Dp, const float* __restrict__ Hin,
    unsigned short* __restrict__ y2b)
{
    __shared__ float BCs[TCH * 32];
    __shared__ float dts[TCH * 64];
    __shared__ float xss[TCH * 64];
    int b = blockIdx.x;
    int g = b >> 4, ch = (b >> 3) & 1, chunk = b & 7;
    int t0 = chunk * TCH;
    int tid = threadIdx.x;
    for (int i4 = tid; i4 < TCH * 8; i4 += 256) {
        int t = i4 >> 3, j4 = i4 & 7;
        *(float4*)&BCs[t * 32 + j4 * 4] =
            *(const float4*)(BCp + (size_t)(g * LL + t0 + t) * 32 + j4 * 4);
    }
    for (int i4 = tid; i4 < TCH * 16; i4 += 256) {
        int t = i4 >> 4, c4 = i4 & 15;
        size_t off = (size_t)(g * LL + t0 + t) * CC + ch * 64 + c4 * 4;
        short4v dv = *(const short4v*)(dtp + off);
        short4v xv = *(const short4v*)(xsp_ + off);
        *(float4*)&dts[t * 64 + c4 * 4] = make_float4(
            b2f((unsigned short)dv[0]), b2f((unsigned short)dv[1]),
            b2f((unsigned short)dv[2]), b2f((unsigned short)dv[3]));
        *(float4*)&xss[t * 64 + c4 * 4] = make_float4(
            b2f((unsigned short)xv[0]), b2f((unsigned short)xv[1]),
            b2f((unsigned short)xv[2]), b2f((unsigned short)xv[3]));
    }
    int cl = tid >> 2, sp = tid & 3;
    int c = ch * 64 + cl;
    float ae[4];
#pragma unroll
    for (int j = 0; j < 4; j++) ae[j] = -__expf(Alog[c * 16 + sp * 4 + j]);
    float dpc = Dp[c];
    float4 hv = *(const float4*)(Hin + ((size_t)g * NCHUNK + chunk) * 2048 + c * 16 + sp * 4);
    float h0 = hv.x, h1 = hv.y, h2 = hv.z, h3 = hv.w;
    __syncthreads();
    const unsigned short* zg = zb + (size_t)(g * LL + t0) * CC + c;
    unsigned short* yg = y2b + (size_t)(g * LL + t0) * CC + c;
    for (int t = 0; t < TCH; t++) {
        float dtv = dts[t * 64 + cl];
        float xv  = xss[t * 64 + cl];
        float u = dtv * xv;
        const float* bc = BCs + t * 32 + sp * 4;
        h0 = fmaf(__expf(dtv * ae[0]), h0, u * bc[0]);
        h1 = fmaf(__expf(dtv * ae[1]), h1, u * bc[1]);
        h2 = fmaf(__expf(dtv * ae[2]), h2, u * bc[2]);
        h3 = fmaf(__expf(dtv * ae[3]), h3, u * bc[3]);
        float y = h0 * bc[16] + h1 * bc[17] + h2 * bc[18] + h3 * bc[19];
        y += __shfl_xor(y, 1);
        y += __shfl_xor(y, 2);
        if (sp == 0) {
            float zv = b2f(zg[t * CC]);
            float yo = fmaf(dpc, xv, y);
            yg[t * CC] = (unsigned short)f2bf(yo * (zv / (1.f + __expf(-zv))));
        }
    }
}

// ---------------------------------------------------------------- norm (h1,h2) + combine (bf16 out12)
__global__ __launch_bounds__(256) void norm12_kernel(const float* __restrict__ p1,
    const float* __restrict__ p2, const float* __restrict__ stats,
    const float* g1, const float* be1, const float* g2, const float* be2,
    float* __restrict__ h2out, unsigned short* __restrict__ out12b)
{
    __shared__ float sc[512];
    int tid = threadIdx.x;
    if (tid < 128) {
        int c = tid;
        const float inv = 1.0f / NN;
        float m1 = stats[c] * inv;
        float v1 = fmaxf(stats[128 + c] * inv - m1 * m1, 0.f);
        float i1 = rsqrtf(v1 + 1e-5f);
        sc[c] = g1[c] * i1; sc[128 + c] = be1[c] - m1 * g1[c] * i1;
        float m2 = stats[256 + c] * inv;
        float v2 = fmaxf(stats[384 + c] * inv - m2 * m2, 0.f);
        float i2 = rsqrtf(v2 + 1e-5f);
        sc[256 + c] = g2[c] * i2; sc[384 + c] = be2[c] - m2 * g2[c] * i2;
    }
    __syncthreads();
    size_t idx = (size_t)blockIdx.x * 256 + tid;   // NN*CC/4
    int c4 = (int)(idx & 31);
    float4 s1 = *(float4*)&sc[c4 * 4];
    float4 t1 = *(float4*)&sc[128 + c4 * 4];
    float4 s2 = *(float4*)&sc[256 + c4 * 4];
    float4 t2 = *(float4*)&sc[384 + c4 * 4];
    float4 a = *(const float4*)(p1 + idx * 4);
    float4 b = *(const float4*)(p2 + idx * 4);
    float4 h, o;
    h.x = fmaf(b.x, s2.x, t2.x); o.x = fmaf(a.x, s1.x, t1.x) + h.x;
    h.y = fmaf(b.y, s2.y, t2.y); o.y = fmaf(a.y, s1.y, t1.y) + h.y;
    h.z = fmaf(b.z, s2.z, t2.z); o.z = fmaf(a.z, s1.z, t1.z) + h.z;
    h.w = fmaf(b.w, s2.w, t2.w); o.w = fmaf(a.w, s1.w, t1.w) + h.w;
    *(float4*)(h2out + idx * 4) = h;
    short4v ob = { f2bf(o.x), f2bf(o.y), f2bf(o.z), f2bf(o.w) };
    *(short4v*)(out12b + idx * 4) = ob;
}

// ---------------------------------------------------------------- final norm
__global__ __launch_bounds__(256) void norm3_kernel(const float* __restrict__ p3,
    const float* __restrict__ stats, const float* g3, const float* be3,
    float* __restrict__ outp)
{
    __shared__ float sc[256];
    int tid = threadIdx.x;
    if (tid < 128) {
        int c = tid;
        const float inv = 1.0f / NN;
        float m = stats[512 + c] * inv;
        float v = fmaxf(stats[640 + c] * inv - m * m, 0.f);
        float iv = rsqrtf(v + 1e-5f);
        sc[c] = g3[c] * iv; sc[128 + c] = be3[c] - m * g3[c] * iv;
    }
    __syncthreads();
    size_t idx = (size_t)blockIdx.x * 256 + tid;   // NN*CC/4
    int c4 = (int)(idx & 31);
    float4 s = *(float4*)&sc[c4 * 4];
    float4 t = *(float4*)&sc[128 + c4 * 4];
    float4 a = *(const float4*)(p3 + idx * 4);
    float4 o;
    o.x = fmaf(a.x, s.x, t.x); o.y = fmaf(a.y, s.y, t.y);
    o.z = fmaf(a.z, s.z, t.z); o.w = fmaf(a.w, s.w, t.w);
    *(float4*)(outp + idx * 4) = o;
}

extern "C" void kernel_launch(void* const* d_in, const int* in_sizes, int n_in,
                              void* d_out, int out_size, void* d_ws, size_t ws_size,
                              hipStream_t stream)
{
    (void)in_sizes; (void)n_in; (void)out_size; (void)ws_size;
    const float* x    = (const float*)d_in[0];
    const int*   ei   = (const int*)d_in[1];
    const float* eps  = (const float*)d_in[3];
    const float* gw1  = (const float*)d_in[4];
    const float* gb1  = (const float*)d_in[5];
    const float* gw2  = (const float*)d_in[6];
    const float* gb2  = (const float*)d_in[7];
    const float* ipw  = (const float*)d_in[8];
    const float* cw   = (const float*)d_in[9];
    const float* cb   = (const float*)d_in[10];
    const float* xpw  = (const float*)d_in[11];
    const float* dtw  = (const float*)d_in[12];
    const float* dtb  = (const float*)d_in[13];
    const float* Alog = (const float*)d_in[14];
    const float* Dp   = (const float*)d_in[15];
    const float* opw  = (const float*)d_in[16];
    const float* mw1  = (const float*)d_in[17];
    const float* mb1  = (const float*)d_in[18];
    const float* mw2  = (const float*)d_in[19];
    const float* mb2  = (const float*)d_in[20];
    const float* g1   = (const float*)d_in[21];
    const float* be1  = (const float*)d_in[22];
    const float* g2   = (const float*)d_in[23];
    const float* be2  = (const float*)d_in[24];
    const float* g3   = (const float*)d_in[25];
    const float* be3  = (const float*)d_in[26];

    float* outp = (float*)d_out;                       // final out [N*C]
    float* h2o  = outp + (size_t)NN * CC;              // h2 [N*C]
    float* p1 = outp;
    float* p2 = h2o;

    const size_t M1 = 1u << 20;
    float* ws = (float*)d_ws;
    float*  scr4   = ws;                                  // 4M fl: Q(2M)+Hin(2M), later p3
    float*  BC     = ws + 4 * M1;                         // 1M fl
    unsigned short* xs_preb = (unsigned short*)(ws + 5 * M1);   // 4M bf16
    unsigned short* zb      = (unsigned short*)(ws + 7 * M1);   // 4M bf16
    unsigned short* dtb_buf = (unsigned short*)(ws + 9 * M1);   // 4M bf16
    unsigned short* xb      = (unsigned short*)(ws + 11 * M1);  // 4M bf16
    unsigned short* hgin    = (unsigned short*)(ws + 13 * M1);  // 4M bf16 (later y2b)
    unsigned short* xsb     = (unsigned short*)(ws + 15 * M1);  // 4M bf16
    unsigned short* out12b  = (unsigned short*)(ws + 17 * M1);  // 4M bf16
    float*  stats  = ws + 19 * M1;                        // 768
    int*    cnt    = (int*)(stats + 768);
    int*    baseA  = cnt + NN;
    int*    cursor = baseA + NN + 1;
    int*    perm   = cursor + NN;
    float*  SDT    = (float*)(perm + EE);                 // 131072
    unsigned short* wbase = (unsigned short*)(SDT + 131072);
    unsigned short* gw1b = wbase;                // 16384
    unsigned short* gw2b = wbase + 16384;
    unsigned short* ipwb = wbase + 32768;        // 32768
    unsigned short* wdtb = wbase + 65536;        // 16384
    unsigned short* xpwb = wbase + 81920;        // 4096
    unsigned short* opwb = wbase + 86016;        // 16384
    unsigned short* mw1b = wbase + 102400;       // 32768
    unsigned short* mw2b = wbase + 135168;       // 32768

    float* Qbuf = scr4;
    float* Hin  = scr4 + 2 * M1;
    float* p3   = scr4;
    unsigned short* y2b = hgin;

    hipMemsetAsync(cnt, 0, NN * sizeof(int), stream);
    hipMemsetAsync(stats, 0, 768 * sizeof(float), stream);

    // input + weight bf16 conversion
    wcvt_kernel<<<dim3(NN * CC / 8 / 256), 256, 0, stream>>>(x, xb);
    wcvt_kernel<<<dim3(8), 256, 0, stream>>>(gw1, gw1b);
    wcvt_kernel<<<dim3(8), 256, 0, stream>>>(gw2, gw2b);
    wcvt_kernel<<<dim3(16), 256, 0, stream>>>(ipw, ipwb);
    wcvt_kernel<<<dim3(2), 256, 0, stream>>>(xpw + 8 * 128, xpwb);
    wcvt_kernel<<<dim3(8), 256, 0, stream>>>(opw, opwb);
    wcvt_kernel<<<dim3(16), 256, 0, stream>>>(mw1, mw1b);
    wcvt_kernel<<<dim3(16), 256, 0, stream>>>(mw2, mw2b);
    wdt_kernel<<<dim3(64), 256, 0, stream>>>(dtw, xpw, wdtb);

    // CSR build + gather (emits hgin = (1+eps)x + agg in bf16)
    hist_kernel<<<dim3(EE / 256), 256, 0, stream>>>(ei, cnt);
    scan32k_kernel<<<dim3(1), 1024, 0, stream>>>(cnt, baseA, cursor);
    permute_kernel<<<dim3(EE / 256), 256, 0, stream>>>(ei, cursor, perm);
    gather_kernel<<<dim3(NN / 8), 256, 0, stream>>>(perm, baseA, xb, eps, hgin);

    // GIN MLP fused: p1 = relu(hgin@gw1^T+gb1)@gw2^T + gb2 + x  (stats S1)
    fused2<128><<<dim3(512), 256, 0, stream>>>(
        hgin, gw1b, gb1, gw2b, gb2, xb, p1, stats + 0, stats + 128);

    // in_proj -> xs_preb / zb (bf16)
    rgemm<128, 0, false, 0, false, 2><<<dim3(512, 2), 256, 0, stream>>>(
        xb, ipwb, nullptr, nullptr, nullptr, nullptr, xs_preb, zb, 128, nullptr, nullptr);
    conv_kernel<<<dim3(NN * 32 / 256), 256, 0, stream>>>(xs_preb, cw, cb, xsb);

    // dt (softplus, bf16) + BC (fp32) in one kernel
    dtbc_kernel<<<dim3(512), 320, 0, stream>>>(xsb, wdtb, dtb, xpwb, dtb_buf, BC);

    // chunked selective scan
    scan_part_kernel<<<dim3(GG * 16), 256, 0, stream>>>(BC, dtb_buf, xsb, Alog, Qbuf, SDT);
    scan_combine_kernel<<<dim3(GG * 2048 / 256), 256, 0, stream>>>(Qbuf, SDT, Alog, Hin);
    scan_final_kernel<<<dim3(GG * 16), 256, 0, stream>>>(BC, dtb_buf, xsb, zb, Alog, Dp, Hin, y2b);

    // out_proj: p2 = y2b@opw^T + x (stats S2)
    rgemm<128, 0, false, 1, true, 1><<<dim3(512, 1), 256, 0, stream>>>(
        y2b, opwb, nullptr, xb, p2, nullptr, nullptr, nullptr, 128, stats + 256, stats + 384);

    // norms 1,2 + combine (out12 kept bf16 only)
    norm12_kernel<<<dim3(NN * CC / 4 / 256), 256, 0, stream>>>(
        p1, p2, stats, g1, be1, g2, be2, h2o, out12b);

    // MLP fused: p3 = relu(out12b@mw1^T+mb1)@mw2^T + mb2 + out12b (stats S3)
    fused2<256><<<dim3(512), 256, 0, stream>>>(
        out12b, mw1b, mb1, mw2b, mb2, out12b, p3, stats + 512, stats + 640);

    norm3_kernel<<<dim3(NN * CC / 4 / 256), 256, 0, stream>>>(p3, stats, g3, be3, outp);
}

// Round 9
// 291.069 us; speedup vs baseline: 2.3630x; 1.1058x over previous
//
#include <hip/hip_runtime.h>
#include <hip/hip_bf16.h>

#define NN 32768
#define GG 128
#define LL 256
#define CC 128
#define EE 524288
#define NCHUNK 8
#define TCH 32

typedef __attribute__((ext_vector_type(8))) short short8v;
typedef __attribute__((ext_vector_type(4))) short short4v;
typedef __attribute__((ext_vector_type(4))) float floatx4;

__device__ inline short f2bf(float f) {
    __hip_bfloat16 h = __float2bfloat16(f);
    short s; __builtin_memcpy(&s, &h, 2); return s;
}
__device__ inline float b2f(unsigned short u) {
    unsigned v = ((unsigned)u) << 16; float f; __builtin_memcpy(&f, &v, 4); return f;
}
__device__ inline floatx4 mfma16(short8v a, short8v b, floatx4 c) {
    return __builtin_amdgcn_mfma_f32_16x16x32_bf16(a, b, c, 0, 0, 0);
}
__device__ inline float softplus_f(float v) {
    return (v > 20.f) ? v : __logf(1.f + __expf(v));
}

// ---------------------------------------------------------------- weight prep mega-kernel
// blocks 0-73: fp32->bf16 weight convert (2048 elems/block)
// blocks 74-137: Wdt = dtw @ xpw[:8] (bf16)
// blocks 138-169: zero cnt ; block 170: zero stats
__global__ __launch_bounds__(256)
void wprep_kernel(const float* __restrict__ gw1, const float* __restrict__ gw2,
                  const float* __restrict__ ipw, const float* __restrict__ xpw,
                  const float* __restrict__ opw, const float* __restrict__ mw1,
                  const float* __restrict__ mw2, const float* __restrict__ dtw,
                  unsigned short* __restrict__ wb, int* __restrict__ cnt,
                  float* __restrict__ stats)
{
    int b = blockIdx.x, tid = threadIdx.x;
    if (b < 74) {
        const float* src; int dstoff, lb;
        if (b < 8)       { src = gw1;        dstoff = 0;      lb = b; }
        else if (b < 16) { src = gw2;        dstoff = 16384;  lb = b - 8; }
        else if (b < 32) { src = ipw;        dstoff = 32768;  lb = b - 16; }
        else if (b < 34) { src = xpw + 1024; dstoff = 81920;  lb = b - 32; }
        else if (b < 42) { src = opw;        dstoff = 86016;  lb = b - 34; }
        else if (b < 58) { src = mw1;        dstoff = 102400; lb = b - 42; }
        else             { src = mw2;        dstoff = 135168; lb = b - 58; }
        size_t i = (size_t)lb * 2048 + tid * 8;
        float4 a = *(const float4*)(src + i);
        float4 c = *(const float4*)(src + i + 4);
        short8v s = { f2bf(a.x), f2bf(a.y), f2bf(a.z), f2bf(a.w),
                      f2bf(c.x), f2bf(c.y), f2bf(c.z), f2bf(c.w) };
        *(short8v*)(wb + dstoff + i) = s;
    } else if (b < 138) {
        int i = (b - 74) * 256 + tid;      // 16384
        int d = i >> 7, c = i & 127;
        float s = 0.f;
#pragma unroll
        for (int r = 0; r < 8; r++) s = fmaf(dtw[d * 8 + r], xpw[r * 128 + c], s);
        wb[65536 + i] = (unsigned short)f2bf(s);
    } else if (b < 170) {
        int idx = (b - 138) * 1024 + tid * 4;
        *(int4*)(cnt + idx) = make_int4(0, 0, 0, 0);
    } else {
        stats[tid] = 0.f; stats[256 + tid] = 0.f; stats[512 + tid] = 0.f;
    }
}

// ---------------------------------------------------------------- edge histogram
__global__ __launch_bounds__(256) void hist_kernel(const int* __restrict__ ei,
    int* __restrict__ cnt)
{
    int e = blockIdx.x * 256 + threadIdx.x;
    atomicAdd(&cnt[ei[EE + e]], 1);
}

// ---------------------------------------------------------------- exclusive scan of 32768 counts
__global__ __launch_bounds__(1024) void scan32k_kernel(const int* __restrict__ cnt,
    int* __restrict__ base, int* __restrict__ cursor)
{
    __shared__ int part[1024];
    int tid = threadIdx.x;
    int local[32];
    int s = 0;
#pragma unroll
    for (int j = 0; j < 32; j++) { local[j] = cnt[tid * 32 + j]; s += local[j]; }
    part[tid] = s;
    __syncthreads();
    for (int off = 1; off < 1024; off <<= 1) {
        int v = (tid >= off) ? part[tid - off] : 0;
        __syncthreads();
        part[tid] += v;
        __syncthreads();
    }
    int run = part[tid] - s;
#pragma unroll
    for (int j = 0; j < 32; j++) {
        base[tid * 32 + j] = run;
        cursor[tid * 32 + j] = run;
        run += local[j];
    }
    if (tid == 0) base[NN] = EE;
}

// ---------------------------------------------------------------- permute srcs into dst-sorted order
__global__ __launch_bounds__(256) void permute_kernel(const int* __restrict__ ei,
    int* __restrict__ cursor, int* __restrict__ perm)
{
    int e = blockIdx.x * 256 + threadIdx.x;
    int dst = ei[EE + e];
    int pos = atomicAdd(&cursor[dst], 1);
    perm[pos] = ei[e];
}

// ---------------------------------------------------------------- gather-sum + (1+eps)x, bf16 in/out
__global__ __launch_bounds__(256) void gather_kernel(const int* __restrict__ perm,
    const int* __restrict__ base, const unsigned short* __restrict__ xb,
    const float* __restrict__ epsp, unsigned short* __restrict__ hgin)
{
    int node = blockIdx.x * 8 + (threadIdx.x >> 5);
    int c4 = threadIdx.x & 31;
    int b0 = base[node], b1 = base[node + 1];
    float s0 = 0, s1 = 0, s2 = 0, s3 = 0;
    float t0 = 0, t1 = 0, t2 = 0, t3 = 0;
    int i = b0;
    for (; i + 1 < b1; i += 2) {
        short4v v0 = *(const short4v*)(xb + (size_t)perm[i] * CC + c4 * 4);
        short4v v1 = *(const short4v*)(xb + (size_t)perm[i + 1] * CC + c4 * 4);
        s0 += b2f((unsigned short)v0[0]); s1 += b2f((unsigned short)v0[1]);
        s2 += b2f((unsigned short)v0[2]); s3 += b2f((unsigned short)v0[3]);
        t0 += b2f((unsigned short)v1[0]); t1 += b2f((unsigned short)v1[1]);
        t2 += b2f((unsigned short)v1[2]); t3 += b2f((unsigned short)v1[3]);
    }
    if (i < b1) {
        short4v v0 = *(const short4v*)(xb + (size_t)perm[i] * CC + c4 * 4);
        s0 += b2f((unsigned short)v0[0]); s1 += b2f((unsigned short)v0[1]);
        s2 += b2f((unsigned short)v0[2]); s3 += b2f((unsigned short)v0[3]);
    }
    float e1 = 1.f + epsp[0];
    short4v xv = *(const short4v*)(xb + (size_t)node * CC + c4 * 4);
    float r0 = fmaf(e1, b2f((unsigned short)xv[0]), s0 + t0);
    float r1 = fmaf(e1, b2f((unsigned short)xv[1]), s1 + t1);
    float r2 = fmaf(e1, b2f((unsigned short)xv[2]), s2 + t2);
    float r3 = fmaf(e1, b2f((unsigned short)xv[3]), s3 + t3);
    short4v o = { f2bf(r0), f2bf(r1), f2bf(r2), f2bf(r3) };
    *(short4v*)(hgin + (size_t)node * CC + c4 * 4) = o;
}

// ---------------------------------------------------------------- x -> bf16 copy
__global__ __launch_bounds__(256) void xb_kernel(const float* __restrict__ x,
    unsigned short* __restrict__ xb)
{
    size_t i = (size_t)blockIdx.x * 256 + threadIdx.x;
    float4 a = *(const float4*)(x + i * 8);
    float4 b = *(const float4*)(x + i * 8 + 4);
    short8v s = { f2bf(a.x), f2bf(a.y), f2bf(a.z), f2bf(a.w),
                  f2bf(b.x), f2bf(b.y), f2bf(b.z), f2bf(b.w) };
    *(short8v*)(xb + i * 8) = s;
}

// ---------------------------------------------------------------- single register-GEMM, W hoisted
template<int K, int ACT, bool HAS_BIAS, int RESID, bool STATS, int OUTM>
__global__ __launch_bounds__(256)
void rgemm(const unsigned short* __restrict__ A,
           const unsigned short* __restrict__ Wb,
           const float* __restrict__ bias,
           const unsigned short* __restrict__ residb,
           float* out, float* out_b1,
           unsigned short* outb, unsigned short* outb_b1, int ldo,
           float* ssum, float* ssq)
{
    __shared__ float sred[256];
    const int tid = threadIdx.x;
    const int by = blockIdx.y;
    const int lane = tid & 63;
    const int wc = tid >> 6;
    const int rql = lane & 15;
    const int kseg = (lane >> 4) * 8;
    const int rsub = (lane >> 4) * 4;
    constexpr int NK = K / 32;

    if (STATS) sred[tid] = 0.f;

    int colg[2];
    colg[0] = by * 128 + wc * 32 + rql;
    colg[1] = colg[0] + 16;
    short8v w0[NK], w1[NK];
    {
        const unsigned short* wp0 = Wb + (size_t)colg[0] * K + kseg;
        const unsigned short* wp1 = Wb + (size_t)colg[1] * K + kseg;
#pragma unroll
        for (int kk = 0; kk < NK; kk++) {
            w0[kk] = *(const short8v*)(wp0 + kk * 32);
            w1[kk] = *(const short8v*)(wp1 + kk * 32);
        }
    }
    float bcol[2] = {0.f, 0.f};
    if (HAS_BIAS) { bcol[0] = bias[colg[0]]; bcol[1] = bias[colg[1]]; }
    float ssumr[2] = {0.f, 0.f}, ssqr[2] = {0.f, 0.f};

    short8v abuf[2][NK][2];
    {
        const unsigned short* ap = A + (size_t)(blockIdx.x * 32 + rql) * K + kseg;
#pragma unroll
        for (int kk = 0; kk < NK; kk++) {
            abuf[0][kk][0] = *(const short8v*)(ap + kk * 32);
            abuf[0][kk][1] = *(const short8v*)(ap + 16 * K + kk * 32);
        }
    }
    float* op = by ? out_b1 : out;
    unsigned short* opb = by ? outb_b1 : outb;

#pragma unroll
    for (int t = 0; t < 2; t++) {
        const int R0 = (blockIdx.x + t * 512) * 32;
        if (t == 0) {
            const unsigned short* ap = A + (size_t)((blockIdx.x + 512) * 32 + rql) * K + kseg;
#pragma unroll
            for (int kk = 0; kk < NK; kk++) {
                abuf[1][kk][0] = *(const short8v*)(ap + kk * 32);
                abuf[1][kk][1] = *(const short8v*)(ap + 16 * K + kk * 32);
            }
        }
        __builtin_amdgcn_sched_barrier(0);
        floatx4 acc[2][2];
#pragma unroll
        for (int m = 0; m < 2; m++)
#pragma unroll
            for (int n = 0; n < 2; n++)
#pragma unroll
                for (int r = 0; r < 4; r++) acc[m][n][r] = 0.f;
#pragma unroll
        for (int kk = 0; kk < NK; kk++) {
            acc[0][0] = mfma16(abuf[t][kk][0], w0[kk], acc[0][0]);
            acc[0][1] = mfma16(abuf[t][kk][0], w1[kk], acc[0][1]);
            acc[1][0] = mfma16(abuf[t][kk][1], w0[kk], acc[1][0]);
            acc[1][1] = mfma16(abuf[t][kk][1], w1[kk], acc[1][1]);
        }
#pragma unroll
        for (int m = 0; m < 2; m++) {
#pragma unroll
            for (int r = 0; r < 4; r++) {
                int row_g = R0 + m * 16 + rsub + r;
#pragma unroll
                for (int n = 0; n < 2; n++) {
                    float v = acc[m][n][r] + bcol[n];
                    if (ACT == 1) v = fmaxf(v, 0.f);
                    if (ACT == 2) v = softplus_f(v);
                    if (RESID == 1)
                        v += b2f(residb[(size_t)row_g * CC + colg[n]]);
                    int cl_ = colg[n] - by * 128;
                    if (OUTM & 1) op[(size_t)row_g * ldo + cl_] = v;
                    if (OUTM & 2) opb[(size_t)row_g * ldo + cl_] = (unsigned short)f2bf(v);
                    if (STATS) { ssumr[n] += v; ssqr[n] += v * v; }
                }
            }
        }
    }
    if (STATS) {
        __syncthreads();
#pragma unroll
        for (int n = 0; n < 2; n++) {
            int cl = wc * 32 + n * 16 + rql;
            atomicAdd(&sred[cl], ssumr[n]);
            atomicAdd(&sred[128 + cl], ssqr[n]);
        }
        __syncthreads();
        if (tid < 128) {
            atomicAdd(&ssum[tid], sred[tid]);
            atomicAdd(&ssq[tid], sred[128 + tid]);
        }
    }
}

// ---------------------------------------------------------------- fused 2-layer GEMM (LDS handoff)
template<int KMID>
__global__ __launch_bounds__(256)
void fused2(const unsigned short* __restrict__ A,
            const unsigned short* __restrict__ W1b, const float* __restrict__ b1,
            const unsigned short* __restrict__ W2b, const float* __restrict__ b2,
            const unsigned short* __restrict__ residb,
            float* __restrict__ outp,
            float* ssum, float* ssq)
{
    constexpr int NF1 = KMID / 64;
    constexpr int NK1 = 4;
    constexpr int NK2 = KMID / 32;
    constexpr int LDSW = KMID + 8;
    __shared__ unsigned short lds[2][32 * LDSW];
    __shared__ float sred[256];
    const int tid = threadIdx.x;
    const int lane = tid & 63;
    const int wc = tid >> 6;
    const int rql = lane & 15;
    const int kseg = (lane >> 4) * 8;
    const int rsub = (lane >> 4) * 4;

    sred[tid] = 0.f;

    short8v w1r[NF1][NK1];
    int colg1[NF1];
    float b1c[NF1];
#pragma unroll
    for (int f = 0; f < NF1; f++) {
        colg1[f] = wc * (16 * NF1) + f * 16 + rql;
        const unsigned short* wp = W1b + (size_t)colg1[f] * 128 + kseg;
#pragma unroll
        for (int kk = 0; kk < NK1; kk++) w1r[f][kk] = *(const short8v*)(wp + kk * 32);
        b1c[f] = b1[colg1[f]];
    }
    int colg2[2];
    colg2[0] = wc * 32 + rql;
    colg2[1] = colg2[0] + 16;
    float b2c[2] = { b2[colg2[0]], b2[colg2[1]] };
    float ssumr[2] = {0.f, 0.f}, ssqr[2] = {0.f, 0.f};

    short8v abuf[2][NK1][2];
    {
        const unsigned short* ap = A + (size_t)(blockIdx.x * 32 + rql) * 128 + kseg;
#pragma unroll
        for (int kk = 0; kk < NK1; kk++) {
            abuf[0][kk][0] = *(const short8v*)(ap + kk * 32);
            abuf[0][kk][1] = *(const short8v*)(ap + 16 * 128 + kk * 32);
        }
    }
    __syncthreads();

#pragma unroll
    for (int t = 0; t < 2; t++) {
        const int R0 = (blockIdx.x + t * 512) * 32;
        floatx4 acc1[2][NF1];
#pragma unroll
        for (int m = 0; m < 2; m++)
#pragma unroll
            for (int f = 0; f < NF1; f++)
#pragma unroll
                for (int r = 0; r < 4; r++) acc1[m][f][r] = 0.f;
#pragma unroll
        for (int kk = 0; kk < NK1; kk++)
#pragma unroll
            for (int m = 0; m < 2; m++)
#pragma unroll
                for (int f = 0; f < NF1; f++)
                    acc1[m][f] = mfma16(abuf[t][kk][m], w1r[f][kk], acc1[m][f]);
        unsigned short* L = &lds[t][0];
#pragma unroll
        for (int m = 0; m < 2; m++)
#pragma unroll
            for (int f = 0; f < NF1; f++)
#pragma unroll
                for (int r = 0; r < 4; r++) {
                    float v = fmaxf(acc1[m][f][r] + b1c[f], 0.f);
                    L[(m * 16 + rsub + r) * LDSW + colg1[f]] = (unsigned short)f2bf(v);
                }
        __syncthreads();
        if (t == 0) {
            const unsigned short* ap = A + (size_t)((blockIdx.x + 512) * 32 + rql) * 128 + kseg;
#pragma unroll
            for (int kk = 0; kk < NK1; kk++) {
                abuf[1][kk][0] = *(const short8v*)(ap + kk * 32);
                abuf[1][kk][1] = *(const short8v*)(ap + 16 * 128 + kk * 32);
            }
        }
        short8v w2a[NK2], w2b[NK2];
        {
            const unsigned short* wq0 = W2b + (size_t)colg2[0] * KMID + kseg;
            const unsigned short* wq1 = W2b + (size_t)colg2[1] * KMID + kseg;
#pragma unroll
            for (int kk = 0; kk < NK2; kk++) {
                w2a[kk] = *(const short8v*)(wq0 + kk * 32);
                w2b[kk] = *(const short8v*)(wq1 + kk * 32);
            }
        }
        floatx4 acc2[2][2];
#pragma unroll
        for (int m = 0; m < 2; m++)
#pragma unroll
            for (int n = 0; n < 2; n++)
#pragma unroll
                for (int r = 0; r < 4; r++) acc2[m][n][r] = 0.f;
#pragma unroll
        for (int kk = 0; kk < NK2; kk++) {
            short8v a2lo = *(const short8v*)&L[rql * LDSW + kseg + kk * 32];
            short8v a2hi = *(const short8v*)&L[(rql + 16) * LDSW + kseg + kk * 32];
            acc2[0][0] = mfma16(a2lo, w2a[kk], acc2[0][0]);
            acc2[0][1] = mfma16(a2lo, w2b[kk], acc2[0][1]);
            acc2[1][0] = mfma16(a2hi, w2a[kk], acc2[1][0]);
            acc2[1][1] = mfma16(a2hi, w2b[kk], acc2[1][1]);
        }
#pragma unroll
        for (int m = 0; m < 2; m++) {
#pragma unroll
            for (int r = 0; r < 4; r++) {
                int row_g = R0 + m * 16 + rsub + r;
#pragma unroll
                for (int n = 0; n < 2; n++) {
                    float v = acc2[m][n][r] + b2c[n];
                    v += b2f(residb[(size_t)row_g * CC + colg2[n]]);
                    outp[(size_t)row_g * CC + colg2[n]] = v;
                    ssumr[n] += v; ssqr[n] += v * v;
                }
            }
        }
    }
    __syncthreads();
#pragma unroll
    for (int n = 0; n < 2; n++) {
        atomicAdd(&sred[colg2[n]], ssumr[n]);
        atomicAdd(&sred[128 + colg2[n]], ssqr[n]);
    }
    __syncthreads();
    if (tid < 128) {
        atomicAdd(&ssum[tid], sred[tid]);
        atomicAdd(&ssq[tid], sred[128 + tid]);
    }
}

// ---------------------------------------------------------------- fused Mamba front:
// in_proj (48-row halo tile) -> LDS ; z -> global ; conv+silu -> xsb + LDS ;
// dt = softplus(xs@Wdt+b) -> bf16 ; BC = xs@xpw[8:40]^T -> fp32.
__global__ __launch_bounds__(256)
void mamba_front(const unsigned short* __restrict__ xb,
                 const unsigned short* __restrict__ ipwb,
                 const float* __restrict__ cw, const float* __restrict__ cb,
                 const unsigned short* __restrict__ wdtb, const float* __restrict__ dtbv,
                 const unsigned short* __restrict__ xpwb,
                 unsigned short* __restrict__ xsb, unsigned short* __restrict__ zb,
                 unsigned short* __restrict__ dtout, float* __restrict__ BCout)
{
    __shared__ unsigned short xsL[48 * 136];   // rows R0-16 .. R0+31
    __shared__ unsigned short xcL[32 * 136];   // post-conv rows R0 .. R0+31
    const int tid = threadIdx.x;
    const int lane = tid & 63;
    const int wv = tid >> 6;
    const int rql = lane & 15;
    const int kseg = (lane >> 4) * 8;
    const int rsub = (lane >> 4) * 4;
    const int R0 = blockIdx.x * 32;
    const int RB = R0 - 16;

    // ---- phase 1: in_proj, 48 rows x 64 cols/wave ----
    int coln[4];
#pragma unroll
    for (int n = 0; n < 4; n++) coln[n] = wv * 64 + n * 16 + rql;
    short8v wr[4][4];
#pragma unroll
    for (int n = 0; n < 4; n++) {
        const unsigned short* wp = ipwb + (size_t)coln[n] * 128 + kseg;
#pragma unroll
        for (int kk = 0; kk < 4; kk++) wr[n][kk] = *(const short8v*)(wp + kk * 32);
    }
    int arow[3];
#pragma unroll
    for (int m = 0; m < 3; m++) {
        int r = RB + m * 16 + rql;
        arow[m] = r < 0 ? 0 : r;
    }
    floatx4 acc[3][4];
#pragma unroll
    for (int m = 0; m < 3; m++)
#pragma unroll
        for (int n = 0; n < 4; n++)
#pragma unroll
            for (int r = 0; r < 4; r++) acc[m][n][r] = 0.f;
#pragma unroll
    for (int kb = 0; kb < 4; kb += 2) {
        short8v a2[3][2];
#pragma unroll
        for (int m = 0; m < 3; m++)
#pragma unroll
            for (int j = 0; j < 2; j++)
                a2[m][j] = *(const short8v*)(xb + (size_t)arow[m] * 128 + kseg + (kb + j) * 32);
        __builtin_amdgcn_sched_barrier(0);
#pragma unroll
        for (int j = 0; j < 2; j++)
#pragma unroll
            for (int m = 0; m < 3; m++)
#pragma unroll
                for (int n = 0; n < 4; n++)
                    acc[m][n] = mfma16(a2[m][j], wr[n][kb + j], acc[m][n]);
    }
    if (wv < 2) {   // xs cols -> LDS
#pragma unroll
        for (int m = 0; m < 3; m++)
#pragma unroll
            for (int r = 0; r < 4; r++) {
                int row_l = m * 16 + rsub + r;
#pragma unroll
                for (int n = 0; n < 4; n++)
                    xsL[row_l * 136 + coln[n]] = (unsigned short)f2bf(acc[m][n][r]);
            }
    } else {        // z cols -> global (rows >= R0 only)
#pragma unroll
        for (int m = 1; m < 3; m++)
#pragma unroll
            for (int r = 0; r < 4; r++) {
                int row_g = RB + m * 16 + rsub + r;
#pragma unroll
                for (int n = 0; n < 4; n++)
                    zb[(size_t)row_g * 128 + (coln[n] - 128)] = (unsigned short)f2bf(acc[m][n][r]);
            }
    }
    __syncthreads();

    // ---- phase 2: depthwise causal conv + silu ----
    {
        int r = tid >> 3;
        int c0 = (tid & 7) * 16;
        int l = (R0 + r) & (LL - 1);
        const unsigned short* basep = &xsL[(16 + r) * 136 + c0];
        unsigned short o16[16];
#pragma unroll
        for (int half = 0; half < 2; half++) {
            short8v x0 = *(const short8v*)(basep + half * 8);
            short8v x1 = *(const short8v*)(basep - 136 + half * 8);
            short8v x2 = *(const short8v*)(basep - 272 + half * 8);
            short8v x3 = *(const short8v*)(basep - 408 + half * 8);
#pragma unroll
            for (int j = 0; j < 8; j++) {
                int c = c0 + half * 8 + j;
                float4 w = *(const float4*)(cw + c * 4);
                float v = cb[c];
                v = fmaf(b2f((unsigned short)x0[j]), w.w, v);
                if (l >= 1) v = fmaf(b2f((unsigned short)x1[j]), w.z, v);
                if (l >= 2) v = fmaf(b2f((unsigned short)x2[j]), w.y, v);
                if (l >= 3) v = fmaf(b2f((unsigned short)x3[j]), w.x, v);
                v = v / (1.f + __expf(-v));
                o16[half * 8 + j] = (unsigned short)f2bf(v);
            }
        }
#pragma unroll
        for (int half = 0; half < 2; half++) {
            short8v s;
#pragma unroll
            for (int j = 0; j < 8; j++) s[j] = (short)o16[half * 8 + j];
            *(short8v*)&xcL[r * 136 + c0 + half * 8] = s;
            *(short8v*)(xsb + (size_t)(R0 + r) * 128 + c0 + half * 8) = s;
        }
    }
    __syncthreads();

    // ---- phase 3: dt (all waves) + BC (waves 0,1) ----
    int cold0 = wv * 32 + rql, cold1 = cold0 + 16;
    short8v wd0[4], wd1[4];
    {
        const unsigned short* wp0 = wdtb + (size_t)cold0 * 128 + kseg;
        const unsigned short* wp1 = wdtb + (size_t)cold1 * 128 + kseg;
#pragma unroll
        for (int kk = 0; kk < 4; kk++) {
            wd0[kk] = *(const short8v*)(wp0 + kk * 32);
            wd1[kk] = *(const short8v*)(wp1 + kk * 32);
        }
    }
    float bd0 = dtbv[cold0], bd1 = dtbv[cold1];
    int colb = wv * 16 + rql;   // BC col for waves 0,1
    short8v wbc[4];
    if (wv < 2) {
        const unsigned short* wp = xpwb + (size_t)colb * 128 + kseg;
#pragma unroll
        for (int kk = 0; kk < 4; kk++) wbc[kk] = *(const short8v*)(wp + kk * 32);
    }
    short8v a0[4], a1[4];
#pragma unroll
    for (int kk = 0; kk < 4; kk++) {
        a0[kk] = *(const short8v*)&xcL[rql * 136 + kseg + kk * 32];
        a1[kk] = *(const short8v*)&xcL[(16 + rql) * 136 + kseg + kk * 32];
    }
    floatx4 accd[2][2], accb[2];
#pragma unroll
    for (int m = 0; m < 2; m++) {
#pragma unroll
        for (int n = 0; n < 2; n++)
#pragma unroll
            for (int r = 0; r < 4; r++) accd[m][n][r] = 0.f;
#pragma unroll
        for (int r = 0; r < 4; r++) accb[m][r] = 0.f;
    }
#pragma unroll
    for (int kk = 0; kk < 4; kk++) {
        accd[0][0] = mfma16(a0[kk], wd0[kk], accd[0][0]);
        accd[0][1] = mfma16(a0[kk], wd1[kk], accd[0][1]);
        accd[1][0] = mfma16(a1[kk], wd0[kk], accd[1][0]);
        accd[1][1] = mfma16(a1[kk], wd1[kk], accd[1][1]);
        if (wv < 2) {
            accb[0] = mfma16(a0[kk], wbc[kk], accb[0]);
            accb[1] = mfma16(a1[kk], wbc[kk], accb[1]);
        }
    }
#pragma unroll
    for (int m = 0; m < 2; m++) {
#pragma unroll
        for (int r = 0; r < 4; r++) {
            int row_g = R0 + m * 16 + rsub + r;
            float v0 = softplus_f(accd[m][0][r] + bd0);
            float v1 = softplus_f(accd[m][1][r] + bd1);
            dtout[(size_t)row_g * 128 + cold0] = (unsigned short)f2bf(v0);
            dtout[(size_t)row_g * 128 + cold1] = (unsigned short)f2bf(v1);
            if (wv < 2) BCout[(size_t)row_g * 32 + colb] = accb[m][r];
        }
    }
}

// ---------------------------------------------------------------- scan phase A: per-chunk (sum_dt, q)
__global__ __launch_bounds__(256) void scan_part_kernel(const float* __restrict__ BCp,
    const unsigned short* __restrict__ dtp, const unsigned short* __restrict__ xsp_,
    const float* __restrict__ Alog, float* __restrict__ Q, float* __restrict__ SDT)
{
    __shared__ float Bs[TCH * 16];
    __shared__ float dts[TCH * 64];
    __shared__ float xss[TCH * 64];
    int b = blockIdx.x;
    int g = b >> 4, ch = (b >> 3) & 1, chunk = b & 7;
    int t0 = chunk * TCH;
    int tid = threadIdx.x;
    for (int i4 = tid; i4 < TCH * 4; i4 += 256) {
        int t = i4 >> 2, j4 = i4 & 3;
        *(float4*)&Bs[t * 16 + j4 * 4] =
            *(const float4*)(BCp + (size_t)(g * LL + t0 + t) * 32 + j4 * 4);
    }
    for (int i4 = tid; i4 < TCH * 16; i4 += 256) {
        int t = i4 >> 4, c4 = i4 & 15;
        size_t off = (size_t)(g * LL + t0 + t) * CC + ch * 64 + c4 * 4;
        short4v dv = *(const short4v*)(dtp + off);
        short4v xv = *(const short4v*)(xsp_ + off);
        *(float4*)&dts[t * 64 + c4 * 4] = make_float4(
            b2f((unsigned short)dv[0]), b2f((unsigned short)dv[1]),
            b2f((unsigned short)dv[2]), b2f((unsigned short)dv[3]));
        *(float4*)&xss[t * 64 + c4 * 4] = make_float4(
            b2f((unsigned short)xv[0]), b2f((unsigned short)xv[1]),
            b2f((unsigned short)xv[2]), b2f((unsigned short)xv[3]));
    }
    int cl = tid >> 2, sp = tid & 3;
    int c = ch * 64 + cl;
    float ae[4];
#pragma unroll
    for (int j = 0; j < 4; j++) ae[j] = -__expf(Alog[c * 16 + sp * 4 + j]);
    __syncthreads();
    float q0 = 0, q1 = 0, q2 = 0, q3 = 0, sdt = 0;
    for (int t = TCH - 1; t >= 0; --t) {
        float dtv = dts[t * 64 + cl];
        float xv  = xss[t * 64 + cl];
        float u = dtv * xv;
        const float* bs = Bs + t * 16 + sp * 4;
        q0 = fmaf(__expf(ae[0] * sdt) * u, bs[0], q0);
        q1 = fmaf(__expf(ae[1] * sdt) * u, bs[1], q1);
        q2 = fmaf(__expf(ae[2] * sdt) * u, bs[2], q2);
        q3 = fmaf(__expf(ae[3] * sdt) * u, bs[3], q3);
        sdt += dtv;
    }
    float4* qp = (float4*)(Q + (((size_t)g * NCHUNK + chunk) * CC + c) * 16 + sp * 4);
    *qp = make_float4(q0, q1, q2, q3);
    if (sp == 0) SDT[((size_t)g * NCHUNK + chunk) * CC + c] = sdt;
}

// ---------------------------------------------------------------- scan phase B: combine chunk states
__global__ __launch_bounds__(256) void scan_combine_kernel(const float* __restrict__ Q,
    const float* __restrict__ SDT, const float* __restrict__ Alog, float* __restrict__ Hin)
{
    int idx = blockIdx.x * 256 + threadIdx.x;
    int g = idx >> 11;
    int cs = idx & 2047;
    float ae = -__expf(Alog[cs]);
    float h = 0.f;
#pragma unroll
    for (int k = 0; k < NCHUNK; k++) {
        size_t o = ((size_t)g * NCHUNK + k);
        Hin[o * 2048 + cs] = h;
        float sdt = SDT[o * CC + (cs >> 4)];
        h = fmaf(__expf(ae * sdt), h, Q[o * 2048 + cs]);
    }
}

// ---------------------------------------------------------------- scan phase C: forward with init + y
__global__ __launch_bounds__(256) void scan_final_kernel(const float* __restrict__ BCp,
    const unsigned short* __restrict__ dtp, const unsigned short* __restrict__ xsp_,
    const unsigned short* __restrict__ zb, const float* __restrict__ Alog,
    const float* __restrict__ Dp, const float* __restrict__ Hin,
    unsigned short* __restrict__ y2b)
{
    __shared__ float BCs[TCH * 32];
    __shared__ float dts[TCH * 64];
    __shared__ float xss[TCH * 64];
    int b = blockIdx.x;
    int g = b >> 4, ch = (b >> 3) & 1, chunk = b & 7;
    int t0 = chunk * TCH;
    int tid = threadIdx.x;
    for (int i4 = tid; i4 < TCH * 8; i4 += 256) {
        int t = i4 >> 3, j4 = i4 & 7;
        *(float4*)&BCs[t * 32 + j4 * 4] =
            *(const float4*)(BCp + (size_t)(g * LL + t0 + t) * 32 + j4 * 4);
    }
    for (int i4 = tid; i4 < TCH * 16; i4 += 256) {
        int t = i4 >> 4, c4 = i4 & 15;
        size_t off = (size_t)(g * LL + t0 + t) * CC + ch * 64 + c4 * 4;
        short4v dv = *(const short4v*)(dtp + off);
        short4v xv = *(const short4v*)(xsp_ + off);
        *(float4*)&dts[t * 64 + c4 * 4] = make_float4(
            b2f((unsigned short)dv[0]), b2f((unsigned short)dv[1]),
            b2f((unsigned short)dv[2]), b2f((unsigned short)dv[3]));
        *(float4*)&xss[t * 64 + c4 * 4] = make_float4(
            b2f((unsigned short)xv[0]), b2f((unsigned short)xv[1]),
            b2f((unsigned short)xv[2]), b2f((unsigned short)xv[3]));
    }
    int cl = tid >> 2, sp = tid & 3;
    int c = ch * 64 + cl;
    float ae[4];
#pragma unroll
    for (int j = 0; j < 4; j++) ae[j] = -__expf(Alog[c * 16 + sp * 4 + j]);
    float dpc = Dp[c];
    float4 hv = *(const float4*)(Hin + ((size_t)g * NCHUNK + chunk) * 2048 + c * 16 + sp * 4);
    float h0 = hv.x, h1 = hv.y, h2 = hv.z, h3 = hv.w;
    __syncthreads();
    const unsigned short* zg = zb + (size_t)(g * LL + t0) * CC + c;
    unsigned short* yg = y2b + (size_t)(g * LL + t0) * CC + c;
    for (int t = 0; t < TCH; t++) {
        float dtv = dts[t * 64 + cl];
        float xv  = xss[t * 64 + cl];
        float u = dtv * xv;
        const float* bc = BCs + t * 32 + sp * 4;
        h0 = fmaf(__expf(dtv * ae[0]), h0, u * bc[0]);
        h1 = fmaf(__expf(dtv * ae[1]), h1, u * bc[1]);
        h2 = fmaf(__expf(dtv * ae[2]), h2, u * bc[2]);
        h3 = fmaf(__expf(dtv * ae[3]), h3, u * bc[3]);
        float y = h0 * bc[16] + h1 * bc[17] + h2 * bc[18] + h3 * bc[19];
        y += __shfl_xor(y, 1);
        y += __shfl_xor(y, 2);
        if (sp == 0) {
            float zv = b2f(zg[t * CC]);
            float yo = fmaf(dpc, xv, y);
            yg[t * CC] = (unsigned short)f2bf(yo * (zv / (1.f + __expf(-zv))));
        }
    }
}

// ---------------------------------------------------------------- norm (h1,h2) + combine (bf16 out12)
__global__ __launch_bounds__(256) void norm12_kernel(const float* __restrict__ p1,
    const float* __restrict__ p2, const float* __restrict__ stats,
    const float* g1, const float* be1, const float* g2, const float* be2,
    float* __restrict__ h2out, unsigned short* __restrict__ out12b)
{
    __shared__ float sc[512];
    int tid = threadIdx.x;
    if (tid < 128) {
        int c = tid;
        const float inv = 1.0f / NN;
        float m1 = stats[c] * inv;
        float v1 = fmaxf(stats[128 + c] * inv - m1 * m1, 0.f);
        float i1 = rsqrtf(v1 + 1e-5f);
        sc[c] = g1[c] * i1; sc[128 + c] = be1[c] - m1 * g1[c] * i1;
        float m2 = stats[256 + c] * inv;
        float v2 = fmaxf(stats[384 + c] * inv - m2 * m2, 0.f);
        float i2 = rsqrtf(v2 + 1e-5f);
        sc[256 + c] = g2[c] * i2; sc[384 + c] = be2[c] - m2 * g2[c] * i2;
    }
    __syncthreads();
    size_t idx = (size_t)blockIdx.x * 256 + tid;
    int c4 = (int)(idx & 31);
    float4 s1 = *(float4*)&sc[c4 * 4];
    float4 t1 = *(float4*)&sc[128 + c4 * 4];
    float4 s2 = *(float4*)&sc[256 + c4 * 4];
    float4 t2 = *(float4*)&sc[384 + c4 * 4];
    float4 a = *(const float4*)(p1 + idx * 4);
    float4 b = *(const float4*)(p2 + idx * 4);
    float4 h, o;
    h.x = fmaf(b.x, s2.x, t2.x); o.x = fmaf(a.x, s1.x, t1.x) + h.x;
    h.y = fmaf(b.y, s2.y, t2.y); o.y = fmaf(a.y, s1.y, t1.y) + h.y;
    h.z = fmaf(b.z, s2.z, t2.z); o.z = fmaf(a.z, s1.z, t1.z) + h.z;
    h.w = fmaf(b.w, s2.w, t2.w); o.w = fmaf(a.w, s1.w, t1.w) + h.w;
    *(float4*)(h2out + idx * 4) = h;
    short4v ob = { f2bf(o.x), f2bf(o.y), f2bf(o.z), f2bf(o.w) };
    *(short4v*)(out12b + idx * 4) = ob;
}

// ---------------------------------------------------------------- final norm
__global__ __launch_bounds__(256) void norm3_kernel(const float* __restrict__ p3,
    const float* __restrict__ stats, const float* g3, const float* be3,
    float* __restrict__ outp)
{
    __shared__ float sc[256];
    int tid = threadIdx.x;
    if (tid < 128) {
        int c = tid;
        const float inv = 1.0f / NN;
        float m = stats[512 + c] * inv;
        float v = fmaxf(stats[640 + c] * inv - m * m, 0.f);
        float iv = rsqrtf(v + 1e-5f);
        sc[c] = g3[c] * iv; sc[128 + c] = be3[c] - m * g3[c] * iv;
    }
    __syncthreads();
    size_t idx = (size_t)blockIdx.x * 256 + tid;
    int c4 = (int)(idx & 31);
    float4 s = *(float4*)&sc[c4 * 4];
    float4 t = *(float4*)&sc[128 + c4 * 4];
    float4 a = *(const float4*)(p3 + idx * 4);
    float4 o;
    o.x = fmaf(a.x, s.x, t.x); o.y = fmaf(a.y, s.y, t.y);
    o.z = fmaf(a.z, s.z, t.z); o.w = fmaf(a.w, s.w, t.w);
    *(float4*)(outp + idx * 4) = o;
}

extern "C" void kernel_launch(void* const* d_in, const int* in_sizes, int n_in,
                              void* d_out, int out_size, void* d_ws, size_t ws_size,
                              hipStream_t stream)
{
    (void)in_sizes; (void)n_in; (void)out_size; (void)ws_size;
    const float* x    = (const float*)d_in[0];
    const int*   ei   = (const int*)d_in[1];
    const float* eps  = (const float*)d_in[3];
    const float* gw1  = (const float*)d_in[4];
    const float* gb1  = (const float*)d_in[5];
    const float* gw2  = (const float*)d_in[6];
    const float* gb2  = (const float*)d_in[7];
    const float* ipw  = (const float*)d_in[8];
    const float* cw   = (const float*)d_in[9];
    const float* cb   = (const float*)d_in[10];
    const float* xpw  = (const float*)d_in[11];
    const float* dtw  = (const float*)d_in[12];
    const float* dtb  = (const float*)d_in[13];
    const float* Alog = (const float*)d_in[14];
    const float* Dp   = (const float*)d_in[15];
    const float* opw  = (const float*)d_in[16];
    const float* mw1  = (const float*)d_in[17];
    const float* mb1  = (const float*)d_in[18];
    const float* mw2  = (const float*)d_in[19];
    const float* mb2  = (const float*)d_in[20];
    const float* g1   = (const float*)d_in[21];
    const float* be1  = (const float*)d_in[22];
    const float* g2   = (const float*)d_in[23];
    const float* be2  = (const float*)d_in[24];
    const float* g3   = (const float*)d_in[25];
    const float* be3  = (const float*)d_in[26];

    float* outp = (float*)d_out;
    float* h2o  = outp + (size_t)NN * CC;
    float* p1 = outp;
    float* p2 = h2o;

    const size_t M1 = 1u << 20;
    float* ws = (float*)d_ws;
    float*  scr4   = ws;                                  // Q(2M)+Hin(2M), later p3
    float*  BC     = ws + 4 * M1;                         // 1M fl
    unsigned short* zb      = (unsigned short*)(ws + 7 * M1);   // 4M bf16
    unsigned short* dtb_buf = (unsigned short*)(ws + 9 * M1);   // 4M bf16
    unsigned short* xb      = (unsigned short*)(ws + 11 * M1);  // 4M bf16
    unsigned short* hgin    = (unsigned short*)(ws + 13 * M1);  // 4M bf16 (later y2b)
    unsigned short* xsb     = (unsigned short*)(ws + 15 * M1);  // 4M bf16
    unsigned short* out12b  = (unsigned short*)(ws + 17 * M1);  // 4M bf16
    float*  stats  = ws + 19 * M1;
    int*    cnt    = (int*)(stats + 768);
    int*    baseA  = cnt + NN;
    int*    cursor = baseA + NN + 1;
    int*    perm   = cursor + NN;
    float*  SDT    = (float*)(perm + EE);
    unsigned short* wbase = (unsigned short*)(SDT + 131072);
    unsigned short* gw1b = wbase;
    unsigned short* gw2b = wbase + 16384;
    unsigned short* ipwb = wbase + 32768;
    unsigned short* wdtb = wbase + 65536;
    unsigned short* xpwb = wbase + 81920;
    unsigned short* opwb = wbase + 86016;
    unsigned short* mw1b = wbase + 102400;
    unsigned short* mw2b = wbase + 135168;

    float* Qbuf = scr4;
    float* Hin  = scr4 + 2 * M1;
    float* p3   = scr4;
    unsigned short* y2b = hgin;

    // all weight conversion + Wdt + zero cnt/stats in ONE kernel
    wprep_kernel<<<dim3(171), 256, 0, stream>>>(gw1, gw2, ipw, xpw, opw, mw1, mw2,
                                                dtw, wbase, cnt, stats);
    xb_kernel<<<dim3(NN * CC / 8 / 256), 256, 0, stream>>>(x, xb);

    // CSR build + gather
    hist_kernel<<<dim3(EE / 256), 256, 0, stream>>>(ei, cnt);
    scan32k_kernel<<<dim3(1), 1024, 0, stream>>>(cnt, baseA, cursor);
    permute_kernel<<<dim3(EE / 256), 256, 0, stream>>>(ei, cursor, perm);
    gather_kernel<<<dim3(NN / 8), 256, 0, stream>>>(perm, baseA, xb, eps, hgin);

    // GIN MLP fused
    fused2<128><<<dim3(512), 256, 0, stream>>>(
        hgin, gw1b, gb1, gw2b, gb2, xb, p1, stats + 0, stats + 128);

    // Mamba front: in_proj + conv + dt + BC (one kernel)
    mamba_front<<<dim3(NN / 32), 256, 0, stream>>>(
        xb, ipwb, cw, cb, wdtb, dtb, xpwb, xsb, zb, dtb_buf, BC);

    // chunked selective scan
    scan_part_kernel<<<dim3(GG * 16), 256, 0, stream>>>(BC, dtb_buf, xsb, Alog, Qbuf, SDT);
    scan_combine_kernel<<<dim3(GG * 2048 / 256), 256, 0, stream>>>(Qbuf, SDT, Alog, Hin);
    scan_final_kernel<<<dim3(GG * 16), 256, 0, stream>>>(BC, dtb_buf, xsb, zb, Alog, Dp, Hin, y2b);

    // out_proj: p2 = y2b@opw^T + x (stats S2)
    rgemm<128, 0, false, 1, true, 1><<<dim3(512, 1), 256, 0, stream>>>(
        y2b, opwb, nullptr, xb, p2, nullptr, nullptr, nullptr, 128, stats + 256, stats + 384);

    // norms 1,2 + combine
    norm12_kernel<<<dim3(NN * CC / 4 / 256), 256, 0, stream>>>(
        p1, p2, stats, g1, be1, g2, be2, h2o, out12b);

    // MLP fused
    fused2<256><<<dim3(512), 256, 0, stream>>>(
        out12b, mw1b, mb1, mw2b, mb2, out12b, p3, stats + 512, stats + 640);

    norm3_kernel<<<dim3(NN * CC / 4 / 256), 256, 0, stream>>>(p3, stats, g3, be3, outp);
}

// Round 10
// 278.990 us; speedup vs baseline: 2.4653x; 1.0433x over previous
//
#include <hip/hip_runtime.h>
#include <hip/hip_bf16.h>

#define NN 32768
#define GG 128
#define LL 256
#define CC 128
#define EE 524288
#define NCHUNK 8
#define TCH 32

typedef __attribute__((ext_vector_type(8))) short short8v;
typedef __attribute__((ext_vector_type(4))) short short4v;
typedef __attribute__((ext_vector_type(4))) float floatx4;

__device__ inline short f2bf(float f) {
    __hip_bfloat16 h = __float2bfloat16(f);
    short s; __builtin_memcpy(&s, &h, 2); return s;
}
__device__ inline float b2f(unsigned short u) {
    unsigned v = ((unsigned)u) << 16; float f; __builtin_memcpy(&f, &v, 4); return f;
}
__device__ inline floatx4 mfma16(short8v a, short8v b, floatx4 c) {
    return __builtin_amdgcn_mfma_f32_16x16x32_bf16(a, b, c, 0, 0, 0);
}
__device__ inline float softplus_f(float v) {
    return (v > 20.f) ? v : __logf(1.f + __expf(v));
}

// ---------------------------------------------------------------- weight prep mega-kernel
__global__ __launch_bounds__(256)
void wprep_kernel(const float* __restrict__ gw1, const float* __restrict__ gw2,
                  const float* __restrict__ ipw, const float* __restrict__ xpw,
                  const float* __restrict__ opw, const float* __restrict__ mw1,
                  const float* __restrict__ mw2, const float* __restrict__ dtw,
                  unsigned short* __restrict__ wb, int* __restrict__ cnt,
                  float* __restrict__ stats)
{
    int b = blockIdx.x, tid = threadIdx.x;
    if (b < 74) {
        const float* src; int dstoff, lb;
        if (b < 8)       { src = gw1;        dstoff = 0;      lb = b; }
        else if (b < 16) { src = gw2;        dstoff = 16384;  lb = b - 8; }
        else if (b < 32) { src = ipw;        dstoff = 32768;  lb = b - 16; }
        else if (b < 34) { src = xpw + 1024; dstoff = 81920;  lb = b - 32; }
        else if (b < 42) { src = opw;        dstoff = 86016;  lb = b - 34; }
        else if (b < 58) { src = mw1;        dstoff = 102400; lb = b - 42; }
        else             { src = mw2;        dstoff = 135168; lb = b - 58; }
        size_t i = (size_t)lb * 2048 + tid * 8;
        float4 a = *(const float4*)(src + i);
        float4 c = *(const float4*)(src + i + 4);
        short8v s = { f2bf(a.x), f2bf(a.y), f2bf(a.z), f2bf(a.w),
                      f2bf(c.x), f2bf(c.y), f2bf(c.z), f2bf(c.w) };
        *(short8v*)(wb + dstoff + i) = s;
    } else if (b < 138) {
        int i = (b - 74) * 256 + tid;
        int d = i >> 7, c = i & 127;
        float s = 0.f;
#pragma unroll
        for (int r = 0; r < 8; r++) s = fmaf(dtw[d * 8 + r], xpw[r * 128 + c], s);
        wb[65536 + i] = (unsigned short)f2bf(s);
    } else if (b < 170) {
        int idx = (b - 138) * 1024 + tid * 4;
        *(int4*)(cnt + idx) = make_int4(0, 0, 0, 0);
    } else {
        stats[tid] = 0.f; stats[256 + tid] = 0.f; stats[512 + tid] = 0.f;
    }
}

// ---------------------------------------------------------------- edge histogram
__global__ __launch_bounds__(256) void hist_kernel(const int* __restrict__ ei,
    int* __restrict__ cnt)
{
    int e = blockIdx.x * 256 + threadIdx.x;
    atomicAdd(&cnt[ei[EE + e]], 1);
}

// ---------------------------------------------------------------- exclusive scan of 32768 counts
__global__ __launch_bounds__(1024) void scan32k_kernel(const int* __restrict__ cnt,
    int* __restrict__ base, int* __restrict__ cursor)
{
    __shared__ int part[1024];
    int tid = threadIdx.x;
    int local[32];
    int s = 0;
#pragma unroll
    for (int j = 0; j < 32; j++) { local[j] = cnt[tid * 32 + j]; s += local[j]; }
    part[tid] = s;
    __syncthreads();
    for (int off = 1; off < 1024; off <<= 1) {
        int v = (tid >= off) ? part[tid - off] : 0;
        __syncthreads();
        part[tid] += v;
        __syncthreads();
    }
    int run = part[tid] - s;
#pragma unroll
    for (int j = 0; j < 32; j++) {
        base[tid * 32 + j] = run;
        cursor[tid * 32 + j] = run;
        run += local[j];
    }
    if (tid == 0) base[NN] = EE;
}

// ---------------------------------------------------------------- permute srcs into dst-sorted order
__global__ __launch_bounds__(256) void permute_kernel(const int* __restrict__ ei,
    int* __restrict__ cursor, int* __restrict__ perm)
{
    int e = blockIdx.x * 256 + threadIdx.x;
    int dst = ei[EE + e];
    int pos = atomicAdd(&cursor[dst], 1);
    perm[pos] = ei[e];
}

// ---------------------------------------------------------------- gather-sum + (1+eps)x, bf16 in/out
__global__ __launch_bounds__(256) void gather_kernel(const int* __restrict__ perm,
    const int* __restrict__ base, const unsigned short* __restrict__ xb,
    const float* __restrict__ epsp, unsigned short* __restrict__ hgin)
{
    int node = blockIdx.x * 8 + (threadIdx.x >> 5);
    int c4 = threadIdx.x & 31;
    int b0 = base[node], b1 = base[node + 1];
    float s0 = 0, s1 = 0, s2 = 0, s3 = 0;
    float t0 = 0, t1 = 0, t2 = 0, t3 = 0;
    int i = b0;
    for (; i + 1 < b1; i += 2) {
        short4v v0 = *(const short4v*)(xb + (size_t)perm[i] * CC + c4 * 4);
        short4v v1 = *(const short4v*)(xb + (size_t)perm[i + 1] * CC + c4 * 4);
        s0 += b2f((unsigned short)v0[0]); s1 += b2f((unsigned short)v0[1]);
        s2 += b2f((unsigned short)v0[2]); s3 += b2f((unsigned short)v0[3]);
        t0 += b2f((unsigned short)v1[0]); t1 += b2f((unsigned short)v1[1]);
        t2 += b2f((unsigned short)v1[2]); t3 += b2f((unsigned short)v1[3]);
    }
    if (i < b1) {
        short4v v0 = *(const short4v*)(xb + (size_t)perm[i] * CC + c4 * 4);
        s0 += b2f((unsigned short)v0[0]); s1 += b2f((unsigned short)v0[1]);
        s2 += b2f((unsigned short)v0[2]); s3 += b2f((unsigned short)v0[3]);
    }
    float e1 = 1.f + epsp[0];
    short4v xv = *(const short4v*)(xb + (size_t)node * CC + c4 * 4);
    float r0 = fmaf(e1, b2f((unsigned short)xv[0]), s0 + t0);
    float r1 = fmaf(e1, b2f((unsigned short)xv[1]), s1 + t1);
    float r2 = fmaf(e1, b2f((unsigned short)xv[2]), s2 + t2);
    float r3 = fmaf(e1, b2f((unsigned short)xv[3]), s3 + t3);
    short4v o = { f2bf(r0), f2bf(r1), f2bf(r2), f2bf(r3) };
    *(short4v*)(hgin + (size_t)node * CC + c4 * 4) = o;
}

// ---------------------------------------------------------------- x -> bf16 copy
__global__ __launch_bounds__(256) void xb_kernel(const float* __restrict__ x,
    unsigned short* __restrict__ xb)
{
    size_t i = (size_t)blockIdx.x * 256 + threadIdx.x;
    float4 a = *(const float4*)(x + i * 8);
    float4 b = *(const float4*)(x + i * 8 + 4);
    short8v s = { f2bf(a.x), f2bf(a.y), f2bf(a.z), f2bf(a.w),
                  f2bf(b.x), f2bf(b.y), f2bf(b.z), f2bf(b.w) };
    *(short8v*)(xb + i * 8) = s;
}

// ---------------------------------------------------------------- fused 2-layer GEMM (LDS handoff)
template<int KMID>
__global__ __launch_bounds__(256)
void fused2(const unsigned short* __restrict__ A,
            const unsigned short* __restrict__ W1b, const float* __restrict__ b1,
            const unsigned short* __restrict__ W2b, const float* __restrict__ b2,
            const unsigned short* __restrict__ residb,
            float* __restrict__ outp,
            float* ssum, float* ssq)
{
    constexpr int NF1 = KMID / 64;
    constexpr int NK1 = 4;
    constexpr int NK2 = KMID / 32;
    constexpr int LDSW = KMID + 8;
    __shared__ unsigned short lds[2][32 * LDSW];
    __shared__ float sred[256];
    const int tid = threadIdx.x;
    const int lane = tid & 63;
    const int wc = tid >> 6;
    const int rql = lane & 15;
    const int kseg = (lane >> 4) * 8;
    const int rsub = (lane >> 4) * 4;

    sred[tid] = 0.f;

    short8v w1r[NF1][NK1];
    int colg1[NF1];
    float b1c[NF1];
#pragma unroll
    for (int f = 0; f < NF1; f++) {
        colg1[f] = wc * (16 * NF1) + f * 16 + rql;
        const unsigned short* wp = W1b + (size_t)colg1[f] * 128 + kseg;
#pragma unroll
        for (int kk = 0; kk < NK1; kk++) w1r[f][kk] = *(const short8v*)(wp + kk * 32);
        b1c[f] = b1[colg1[f]];
    }
    int colg2[2];
    colg2[0] = wc * 32 + rql;
    colg2[1] = colg2[0] + 16;
    float b2c[2] = { b2[colg2[0]], b2[colg2[1]] };
    float ssumr[2] = {0.f, 0.f}, ssqr[2] = {0.f, 0.f};

    short8v abuf[2][NK1][2];
    {
        const unsigned short* ap = A + (size_t)(blockIdx.x * 32 + rql) * 128 + kseg;
#pragma unroll
        for (int kk = 0; kk < NK1; kk++) {
            abuf[0][kk][0] = *(const short8v*)(ap + kk * 32);
            abuf[0][kk][1] = *(const short8v*)(ap + 16 * 128 + kk * 32);
        }
    }
    __syncthreads();

#pragma unroll
    for (int t = 0; t < 2; t++) {
        const int R0 = (blockIdx.x + t * 512) * 32;
        floatx4 acc1[2][NF1];
#pragma unroll
        for (int m = 0; m < 2; m++)
#pragma unroll
            for (int f = 0; f < NF1; f++)
#pragma unroll
                for (int r = 0; r < 4; r++) acc1[m][f][r] = 0.f;
#pragma unroll
        for (int kk = 0; kk < NK1; kk++)
#pragma unroll
            for (int m = 0; m < 2; m++)
#pragma unroll
                for (int f = 0; f < NF1; f++)
                    acc1[m][f] = mfma16(abuf[t][kk][m], w1r[f][kk], acc1[m][f]);
        unsigned short* L = &lds[t][0];
#pragma unroll
        for (int m = 0; m < 2; m++)
#pragma unroll
            for (int f = 0; f < NF1; f++)
#pragma unroll
                for (int r = 0; r < 4; r++) {
                    float v = fmaxf(acc1[m][f][r] + b1c[f], 0.f);
                    L[(m * 16 + rsub + r) * LDSW + colg1[f]] = (unsigned short)f2bf(v);
                }
        __syncthreads();
        if (t == 0) {
            const unsigned short* ap = A + (size_t)((blockIdx.x + 512) * 32 + rql) * 128 + kseg;
#pragma unroll
            for (int kk = 0; kk < NK1; kk++) {
                abuf[1][kk][0] = *(const short8v*)(ap + kk * 32);
                abuf[1][kk][1] = *(const short8v*)(ap + 16 * 128 + kk * 32);
            }
        }
        short8v w2a[NK2], w2b[NK2];
        {
            const unsigned short* wq0 = W2b + (size_t)colg2[0] * KMID + kseg;
            const unsigned short* wq1 = W2b + (size_t)colg2[1] * KMID + kseg;
#pragma unroll
            for (int kk = 0; kk < NK2; kk++) {
                w2a[kk] = *(const short8v*)(wq0 + kk * 32);
                w2b[kk] = *(const short8v*)(wq1 + kk * 32);
            }
        }
        floatx4 acc2[2][2];
#pragma unroll
        for (int m = 0; m < 2; m++)
#pragma unroll
            for (int n = 0; n < 2; n++)
#pragma unroll
                for (int r = 0; r < 4; r++) acc2[m][n][r] = 0.f;
#pragma unroll
        for (int kk = 0; kk < NK2; kk++) {
            short8v a2lo = *(const short8v*)&L[rql * LDSW + kseg + kk * 32];
            short8v a2hi = *(const short8v*)&L[(rql + 16) * LDSW + kseg + kk * 32];
            acc2[0][0] = mfma16(a2lo, w2a[kk], acc2[0][0]);
            acc2[0][1] = mfma16(a2lo, w2b[kk], acc2[0][1]);
            acc2[1][0] = mfma16(a2hi, w2a[kk], acc2[1][0]);
            acc2[1][1] = mfma16(a2hi, w2b[kk], acc2[1][1]);
        }
#pragma unroll
        for (int m = 0; m < 2; m++) {
#pragma unroll
            for (int r = 0; r < 4; r++) {
                int row_g = R0 + m * 16 + rsub + r;
#pragma unroll
                for (int n = 0; n < 2; n++) {
                    float v = acc2[m][n][r] + b2c[n];
                    v += b2f(residb[(size_t)row_g * CC + colg2[n]]);
                    outp[(size_t)row_g * CC + colg2[n]] = v;
                    ssumr[n] += v; ssqr[n] += v * v;
                }
            }
        }
    }
    __syncthreads();
#pragma unroll
    for (int n = 0; n < 2; n++) {
        atomicAdd(&sred[colg2[n]], ssumr[n]);
        atomicAdd(&sred[128 + colg2[n]], ssqr[n]);
    }
    __syncthreads();
    if (tid < 128) {
        atomicAdd(&ssum[tid], sred[tid]);
        atomicAdd(&ssq[tid], sred[128 + tid]);
    }
}

// ---------------------------------------------------------------- fused Mamba front (+ scan phase A):
// in_proj (48-row halo) -> LDS ; z -> global ; conv+silu -> xsb + LDS ;
// dt -> bf16 + LDS ; BC -> fp32 + B in LDS ; per-chunk (sdt, q) -> Q/SDT.
__global__ __launch_bounds__(256)
void mamba_front(const unsigned short* __restrict__ xb,
                 const unsigned short* __restrict__ ipwb,
                 const float* __restrict__ cw, const float* __restrict__ cb,
                 const unsigned short* __restrict__ wdtb, const float* __restrict__ dtbv,
                 const unsigned short* __restrict__ xpwb,
                 const float* __restrict__ Alog,
                 unsigned short* __restrict__ xsb, unsigned short* __restrict__ zb,
                 unsigned short* __restrict__ dtout, float* __restrict__ BCout,
                 float* __restrict__ Q, float* __restrict__ SDT)
{
    __shared__ unsigned short xsL[48 * 136];   // phase1 xs (halo); reused as dtL in phase3/4
    __shared__ unsigned short xcL[32 * 136];   // post-conv xs
    __shared__ float BsL[TCH * 16];            // B slice for phase 4
    const int tid = threadIdx.x;
    const int lane = tid & 63;
    const int wv = tid >> 6;
    const int rql = lane & 15;
    const int kseg = (lane >> 4) * 8;
    const int rsub = (lane >> 4) * 4;
    const int R0 = blockIdx.x * 32;
    const int RB = R0 - 16;
    const int g = blockIdx.x >> 3;
    const int chunk = blockIdx.x & 7;

    // ---- phase 1: in_proj, 48 rows x 64 cols/wave ----
    int coln[4];
#pragma unroll
    for (int n = 0; n < 4; n++) coln[n] = wv * 64 + n * 16 + rql;
    short8v wr[4][4];
#pragma unroll
    for (int n = 0; n < 4; n++) {
        const unsigned short* wp = ipwb + (size_t)coln[n] * 128 + kseg;
#pragma unroll
        for (int kk = 0; kk < 4; kk++) wr[n][kk] = *(const short8v*)(wp + kk * 32);
    }
    int arow[3];
#pragma unroll
    for (int m = 0; m < 3; m++) {
        int r = RB + m * 16 + rql;
        arow[m] = r < 0 ? 0 : r;
    }
    floatx4 acc[3][4];
#pragma unroll
    for (int m = 0; m < 3; m++)
#pragma unroll
        for (int n = 0; n < 4; n++)
#pragma unroll
            for (int r = 0; r < 4; r++) acc[m][n][r] = 0.f;
#pragma unroll
    for (int kb = 0; kb < 4; kb += 2) {
        short8v a2[3][2];
#pragma unroll
        for (int m = 0; m < 3; m++)
#pragma unroll
            for (int j = 0; j < 2; j++)
                a2[m][j] = *(const short8v*)(xb + (size_t)arow[m] * 128 + kseg + (kb + j) * 32);
        __builtin_amdgcn_sched_barrier(0);
#pragma unroll
        for (int j = 0; j < 2; j++)
#pragma unroll
            for (int m = 0; m < 3; m++)
#pragma unroll
                for (int n = 0; n < 4; n++)
                    acc[m][n] = mfma16(a2[m][j], wr[n][kb + j], acc[m][n]);
    }
    if (wv < 2) {
#pragma unroll
        for (int m = 0; m < 3; m++)
#pragma unroll
            for (int r = 0; r < 4; r++) {
                int row_l = m * 16 + rsub + r;
#pragma unroll
                for (int n = 0; n < 4; n++)
                    xsL[row_l * 136 + coln[n]] = (unsigned short)f2bf(acc[m][n][r]);
            }
    } else {
#pragma unroll
        for (int m = 1; m < 3; m++)
#pragma unroll
            for (int r = 0; r < 4; r++) {
                int row_g = RB + m * 16 + rsub + r;
#pragma unroll
                for (int n = 0; n < 4; n++)
                    zb[(size_t)row_g * 128 + (coln[n] - 128)] = (unsigned short)f2bf(acc[m][n][r]);
            }
    }
    __syncthreads();

    // ---- phase 2: depthwise causal conv + silu ----
    {
        int r = tid >> 3;
        int c0 = (tid & 7) * 16;
        int l = (R0 + r) & (LL - 1);
        const unsigned short* basep = &xsL[(16 + r) * 136 + c0];
        unsigned short o16[16];
#pragma unroll
        for (int half = 0; half < 2; half++) {
            short8v x0 = *(const short8v*)(basep + half * 8);
            short8v x1 = *(const short8v*)(basep - 136 + half * 8);
            short8v x2 = *(const short8v*)(basep - 272 + half * 8);
            short8v x3 = *(const short8v*)(basep - 408 + half * 8);
#pragma unroll
            for (int j = 0; j < 8; j++) {
                int c = c0 + half * 8 + j;
                float4 w = *(const float4*)(cw + c * 4);
                float v = cb[c];
                v = fmaf(b2f((unsigned short)x0[j]), w.w, v);
                if (l >= 1) v = fmaf(b2f((unsigned short)x1[j]), w.z, v);
                if (l >= 2) v = fmaf(b2f((unsigned short)x2[j]), w.y, v);
                if (l >= 3) v = fmaf(b2f((unsigned short)x3[j]), w.x, v);
                v = v / (1.f + __expf(-v));
                o16[half * 8 + j] = (unsigned short)f2bf(v);
            }
        }
#pragma unroll
        for (int half = 0; half < 2; half++) {
            short8v s;
#pragma unroll
            for (int j = 0; j < 8; j++) s[j] = (short)o16[half * 8 + j];
            *(short8v*)&xcL[r * 136 + c0 + half * 8] = s;
            *(short8v*)(xsb + (size_t)(R0 + r) * 128 + c0 + half * 8) = s;
        }
    }
    __syncthreads();   // xsL now dead -> reuse as dtL

    // ---- phase 3: dt (all waves) + BC (waves 0,1) ----
    unsigned short* dtL = xsL;
    int cold0 = wv * 32 + rql, cold1 = cold0 + 16;
    short8v wd0[4], wd1[4];
    {
        const unsigned short* wp0 = wdtb + (size_t)cold0 * 128 + kseg;
        const unsigned short* wp1 = wdtb + (size_t)cold1 * 128 + kseg;
#pragma unroll
        for (int kk = 0; kk < 4; kk++) {
            wd0[kk] = *(const short8v*)(wp0 + kk * 32);
            wd1[kk] = *(const short8v*)(wp1 + kk * 32);
        }
    }
    float bd0 = dtbv[cold0], bd1 = dtbv[cold1];
    int colb = wv * 16 + rql;
    short8v wbc[4];
    if (wv < 2) {
        const unsigned short* wp = xpwb + (size_t)colb * 128 + kseg;
#pragma unroll
        for (int kk = 0; kk < 4; kk++) wbc[kk] = *(const short8v*)(wp + kk * 32);
    }
    short8v a0[4], a1[4];
#pragma unroll
    for (int kk = 0; kk < 4; kk++) {
        a0[kk] = *(const short8v*)&xcL[rql * 136 + kseg + kk * 32];
        a1[kk] = *(const short8v*)&xcL[(16 + rql) * 136 + kseg + kk * 32];
    }
    floatx4 accd[2][2], accb[2];
#pragma unroll
    for (int m = 0; m < 2; m++) {
#pragma unroll
        for (int n = 0; n < 2; n++)
#pragma unroll
            for (int r = 0; r < 4; r++) accd[m][n][r] = 0.f;
#pragma unroll
        for (int r = 0; r < 4; r++) accb[m][r] = 0.f;
    }
#pragma unroll
    for (int kk = 0; kk < 4; kk++) {
        accd[0][0] = mfma16(a0[kk], wd0[kk], accd[0][0]);
        accd[0][1] = mfma16(a0[kk], wd1[kk], accd[0][1]);
        accd[1][0] = mfma16(a1[kk], wd0[kk], accd[1][0]);
        accd[1][1] = mfma16(a1[kk], wd1[kk], accd[1][1]);
        if (wv < 2) {
            accb[0] = mfma16(a0[kk], wbc[kk], accb[0]);
            accb[1] = mfma16(a1[kk], wbc[kk], accb[1]);
        }
    }
#pragma unroll
    for (int m = 0; m < 2; m++) {
#pragma unroll
        for (int r = 0; r < 4; r++) {
            int tl = m * 16 + rsub + r;
            int row_g = R0 + tl;
            float v0 = softplus_f(accd[m][0][r] + bd0);
            float v1 = softplus_f(accd[m][1][r] + bd1);
            unsigned short u0 = (unsigned short)f2bf(v0);
            unsigned short u1 = (unsigned short)f2bf(v1);
            dtout[(size_t)row_g * 128 + cold0] = u0;
            dtout[(size_t)row_g * 128 + cold1] = u1;
            dtL[tl * 136 + cold0] = u0;
            dtL[tl * 136 + cold1] = u1;
            if (wv < 2) {
                BCout[(size_t)row_g * 32 + colb] = accb[m][r];
                if (wv == 0) BsL[tl * 16 + colb] = accb[m][r];
            }
        }
    }
    __syncthreads();

    // ---- phase 4: per-chunk backward recurrence -> (Q, SDT) ----
    for (int u = tid; u < 512; u += 256) {
        int c = u >> 2, sp = u & 3;
        float ae0 = -__expf(Alog[c * 16 + sp * 4 + 0]);
        float ae1 = -__expf(Alog[c * 16 + sp * 4 + 1]);
        float ae2 = -__expf(Alog[c * 16 + sp * 4 + 2]);
        float ae3 = -__expf(Alog[c * 16 + sp * 4 + 3]);
        float q0 = 0, q1 = 0, q2 = 0, q3 = 0, sdt = 0;
        for (int t = TCH - 1; t >= 0; --t) {
            float dtv = b2f(dtL[t * 136 + c]);
            float xv  = b2f(xcL[t * 136 + c]);
            float uu = dtv * xv;
            const float* bs = &BsL[t * 16 + sp * 4];
            q0 = fmaf(__expf(ae0 * sdt) * uu, bs[0], q0);
            q1 = fmaf(__expf(ae1 * sdt) * uu, bs[1], q1);
            q2 = fmaf(__expf(ae2 * sdt) * uu, bs[2], q2);
            q3 = fmaf(__expf(ae3 * sdt) * uu, bs[3], q3);
            sdt += dtv;
        }
        float4* qp = (float4*)(Q + (((size_t)g * NCHUNK + chunk) * CC + c) * 16 + sp * 4);
        *qp = make_float4(q0, q1, q2, q3);
        if (sp == 0) SDT[((size_t)g * NCHUNK + chunk) * CC + c] = sdt;
    }
}

// ---------------------------------------------------------------- scan phase B: combine chunk states
__global__ __launch_bounds__(256) void scan_combine_kernel(const float* __restrict__ Q,
    const float* __restrict__ SDT, const float* __restrict__ Alog, float* __restrict__ Hin)
{
    int idx = blockIdx.x * 256 + threadIdx.x;
    int g = idx >> 11;
    int cs = idx & 2047;
    float ae = -__expf(Alog[cs]);
    float h = 0.f;
#pragma unroll
    for (int k = 0; k < NCHUNK; k++) {
        size_t o = ((size_t)g * NCHUNK + k);
        Hin[o * 2048 + cs] = h;
        float sdt = SDT[o * CC + (cs >> 4)];
        h = fmaf(__expf(ae * sdt), h, Q[o * 2048 + cs]);
    }
}

// ---------------------------------------------------------------- scan phase C + out_proj fused
// 512 thr/block, block = (g, chunk). Scan -> y in LDS -> y@opw^T + x resid -> p2 (stats S2).
__global__ __launch_bounds__(512)
void scan_out_kernel(const float* __restrict__ BCp,
    const unsigned short* __restrict__ dtp, const unsigned short* __restrict__ xsp_,
    const unsigned short* __restrict__ zb, const float* __restrict__ Alog,
    const float* __restrict__ Dp, const float* __restrict__ Hin,
    const unsigned short* __restrict__ opwb, const unsigned short* __restrict__ xb,
    float* __restrict__ p2, float* ssum, float* ssq)
{
    __shared__ float BCs[TCH * 32];
    __shared__ unsigned short dts[TCH * 136];
    __shared__ unsigned short xss[TCH * 136];
    __shared__ unsigned short yL[TCH * 136];
    __shared__ float sred[256];
    const int b = blockIdx.x;
    const int g = b >> 3, chunk = b & 7;
    const int t0 = chunk * TCH;
    const int tid = threadIdx.x;
    if (tid < 256) sred[tid] = 0.f;
    for (int i4 = tid; i4 < TCH * 8; i4 += 512) {
        int t = i4 >> 3, j4 = i4 & 7;
        *(float4*)&BCs[t * 32 + j4 * 4] =
            *(const float4*)(BCp + (size_t)(g * LL + t0 + t) * 32 + j4 * 4);
    }
    {
        int t = tid >> 4, c8 = tid & 15;
        size_t off = (size_t)(g * LL + t0 + t) * CC + c8 * 8;
        *(short8v*)&dts[t * 136 + c8 * 8] = *(const short8v*)(dtp + off);
        *(short8v*)&xss[t * 136 + c8 * 8] = *(const short8v*)(xsp_ + off);
    }
    const int c = tid >> 2, sp = tid & 3;
    float ae0 = -__expf(Alog[c * 16 + sp * 4 + 0]);
    float ae1 = -__expf(Alog[c * 16 + sp * 4 + 1]);
    float ae2 = -__expf(Alog[c * 16 + sp * 4 + 2]);
    float ae3 = -__expf(Alog[c * 16 + sp * 4 + 3]);
    float dpc = Dp[c];
    float4 hv = *(const float4*)(Hin + ((size_t)g * NCHUNK + chunk) * 2048 + c * 16 + sp * 4);
    float h0 = hv.x, h1 = hv.y, h2 = hv.z, h3 = hv.w;
    __syncthreads();
    const unsigned short* zg = zb + (size_t)(g * LL + t0) * CC + c;
    for (int t = 0; t < TCH; t++) {
        float dtv = b2f(dts[t * 136 + c]);
        float xv  = b2f(xss[t * 136 + c]);
        float u = dtv * xv;
        const float* bc = &BCs[t * 32 + sp * 4];
        h0 = fmaf(__expf(dtv * ae0), h0, u * bc[0]);
        h1 = fmaf(__expf(dtv * ae1), h1, u * bc[1]);
        h2 = fmaf(__expf(dtv * ae2), h2, u * bc[2]);
        h3 = fmaf(__expf(dtv * ae3), h3, u * bc[3]);
        float y = h0 * bc[16] + h1 * bc[17] + h2 * bc[18] + h3 * bc[19];
        y += __shfl_xor(y, 1);
        y += __shfl_xor(y, 2);
        if (sp == 0) {
            float zv = b2f(zg[t * CC]);
            float yo = fmaf(dpc, xv, y);
            yL[t * 136 + c] = (unsigned short)f2bf(yo * (zv / (1.f + __expf(-zv))));
        }
    }
    __syncthreads();

    // ---- out_proj: 8 waves x 16 cols, rows = 32 timesteps ----
    const int lane = tid & 63;
    const int wv = tid >> 6;
    const int rql = lane & 15;
    const int kseg = (lane >> 4) * 8;
    const int rsub = (lane >> 4) * 4;
    const int colg = wv * 16 + rql;
    short8v w[4];
    {
        const unsigned short* wp = opwb + (size_t)colg * 128 + kseg;
#pragma unroll
        for (int kk = 0; kk < 4; kk++) w[kk] = *(const short8v*)(wp + kk * 32);
    }
    floatx4 acc[2];
#pragma unroll
    for (int m = 0; m < 2; m++)
#pragma unroll
        for (int r = 0; r < 4; r++) acc[m][r] = 0.f;
#pragma unroll
    for (int kk = 0; kk < 4; kk++) {
        short8v alo = *(const short8v*)&yL[rql * 136 + kseg + kk * 32];
        short8v ahi = *(const short8v*)&yL[(16 + rql) * 136 + kseg + kk * 32];
        acc[0] = mfma16(alo, w[kk], acc[0]);
        acc[1] = mfma16(ahi, w[kk], acc[1]);
    }
    float sumr = 0.f, sqr = 0.f;
#pragma unroll
    for (int m = 0; m < 2; m++) {
#pragma unroll
        for (int r = 0; r < 4; r++) {
            int row_g = g * LL + t0 + m * 16 + rsub + r;
            float v = acc[m][r] + b2f(xb[(size_t)row_g * CC + colg]);
            p2[(size_t)row_g * CC + colg] = v;
            sumr += v; sqr += v * v;
        }
    }
    sumr += __shfl_xor(sumr, 16); sumr += __shfl_xor(sumr, 32);
    sqr  += __shfl_xor(sqr, 16);  sqr  += __shfl_xor(sqr, 32);
    if ((lane >> 4) == 0) {
        atomicAdd(&sred[colg], sumr);
        atomicAdd(&sred[128 + colg], sqr);
    }
    __syncthreads();
    if (tid < 128) {
        atomicAdd(&ssum[tid], sred[tid]);
        atomicAdd(&ssq[tid], sred[128 + tid]);
    }
}

// ---------------------------------------------------------------- norm (h1,h2) + combine (bf16 out12)
__global__ __launch_bounds__(256) void norm12_kernel(const float* __restrict__ p1,
    const float* __restrict__ p2, const float* __restrict__ stats,
    const float* g1, const float* be1, const float* g2, const float* be2,
    float* __restrict__ h2out, unsigned short* __restrict__ out12b)
{
    __shared__ float sc[512];
    int tid = threadIdx.x;
    if (tid < 128) {
        int c = tid;
        const float inv = 1.0f / NN;
        float m1 = stats[c] * inv;
        float v1 = fmaxf(stats[128 + c] * inv - m1 * m1, 0.f);
        float i1 = rsqrtf(v1 + 1e-5f);
        sc[c] = g1[c] * i1; sc[128 + c] = be1[c] - m1 * g1[c] * i1;
        float m2 = stats[256 + c] * inv;
        float v2 = fmaxf(stats[384 + c] * inv - m2 * m2, 0.f);
        float i2 = rsqrtf(v2 + 1e-5f);
        sc[256 + c] = g2[c] * i2; sc[384 + c] = be2[c] - m2 * g2[c] * i2;
    }
    __syncthreads();
    size_t idx = (size_t)blockIdx.x * 256 + tid;
    int c4 = (int)(idx & 31);
    float4 s1 = *(float4*)&sc[c4 * 4];
    float4 t1 = *(float4*)&sc[128 + c4 * 4];
    float4 s2 = *(float4*)&sc[256 + c4 * 4];
    float4 t2 = *(float4*)&sc[384 + c4 * 4];
    float4 a = *(const float4*)(p1 + idx * 4);
    float4 b = *(const float4*)(p2 + idx * 4);
    float4 h, o;
    h.x = fmaf(b.x, s2.x, t2.x); o.x = fmaf(a.x, s1.x, t1.x) + h.x;
    h.y = fmaf(b.y, s2.y, t2.y); o.y = fmaf(a.y, s1.y, t1.y) + h.y;
    h.z = fmaf(b.z, s2.z, t2.z); o.z = fmaf(a.z, s1.z, t1.z) + h.z;
    h.w = fmaf(b.w, s2.w, t2.w); o.w = fmaf(a.w, s1.w, t1.w) + h.w;
    *(float4*)(h2out + idx * 4) = h;
    short4v ob = { f2bf(o.x), f2bf(o.y), f2bf(o.z), f2bf(o.w) };
    *(short4v*)(out12b + idx * 4) = ob;
}

// ---------------------------------------------------------------- final norm
__global__ __launch_bounds__(256) void norm3_kernel(const float* __restrict__ p3,
    const float* __restrict__ stats, const float* g3, const float* be3,
    float* __restrict__ outp)
{
    __shared__ float sc[256];
    int tid = threadIdx.x;
    if (tid < 128) {
        int c = tid;
        const float inv = 1.0f / NN;
        float m = stats[512 + c] * inv;
        float v = fmaxf(stats[640 + c] * inv - m * m, 0.f);
        float iv = rsqrtf(v + 1e-5f);
        sc[c] = g3[c] * iv; sc[128 + c] = be3[c] - m * g3[c] * iv;
    }
    __syncthreads();
    size_t idx = (size_t)blockIdx.x * 256 + tid;
    int c4 = (int)(idx & 31);
    float4 s = *(float4*)&sc[c4 * 4];
    float4 t = *(float4*)&sc[128 + c4 * 4];
    float4 a = *(const float4*)(p3 + idx * 4);
    float4 o;
    o.x = fmaf(a.x, s.x, t.x); o.y = fmaf(a.y, s.y, t.y);
    o.z = fmaf(a.z, s.z, t.z); o.w = fmaf(a.w, s.w, t.w);
    *(float4*)(outp + idx * 4) = o;
}

extern "C" void kernel_launch(void* const* d_in, const int* in_sizes, int n_in,
                              void* d_out, int out_size, void* d_ws, size_t ws_size,
                              hipStream_t stream)
{
    (void)in_sizes; (void)n_in; (void)out_size; (void)ws_size;
    const float* x    = (const float*)d_in[0];
    const int*   ei   = (const int*)d_in[1];
    const float* eps  = (const float*)d_in[3];
    const float* gw1  = (const float*)d_in[4];
    const float* gb1  = (const float*)d_in[5];
    const float* gw2  = (const float*)d_in[6];
    const float* gb2  = (const float*)d_in[7];
    const float* ipw  = (const float*)d_in[8];
    const float* cw   = (const float*)d_in[9];
    const float* cb   = (const float*)d_in[10];
    const float* xpw  = (const float*)d_in[11];
    const float* dtw  = (const float*)d_in[12];
    const float* dtb  = (const float*)d_in[13];
    const float* Alog = (const float*)d_in[14];
    const float* Dp   = (const float*)d_in[15];
    const float* opw  = (const float*)d_in[16];
    const float* mw1  = (const float*)d_in[17];
    const float* mb1  = (const float*)d_in[18];
    const float* mw2  = (const float*)d_in[19];
    const float* mb2  = (const float*)d_in[20];
    const float* g1   = (const float*)d_in[21];
    const float* be1  = (const float*)d_in[22];
    const float* g2   = (const float*)d_in[23];
    const float* be2  = (const float*)d_in[24];
    const float* g3   = (const float*)d_in[25];
    const float* be3  = (const float*)d_in[26];

    float* outp = (float*)d_out;
    float* h2o  = outp + (size_t)NN * CC;
    float* p1 = outp;
    float* p2 = h2o;

    const size_t M1 = 1u << 20;
    float* ws = (float*)d_ws;
    float*  scr4   = ws;                                  // Q(2M)+Hin(2M), later p3
    float*  BC     = ws + 4 * M1;                         // 1M fl
    unsigned short* zb      = (unsigned short*)(ws + 7 * M1);
    unsigned short* dtb_buf = (unsigned short*)(ws + 9 * M1);
    unsigned short* xb      = (unsigned short*)(ws + 11 * M1);
    unsigned short* hgin    = (unsigned short*)(ws + 13 * M1);
    unsigned short* xsb     = (unsigned short*)(ws + 15 * M1);
    unsigned short* out12b  = (unsigned short*)(ws + 17 * M1);
    float*  stats  = ws + 19 * M1;
    int*    cnt    = (int*)(stats + 768);
    int*    baseA  = cnt + NN;
    int*    cursor = baseA + NN + 1;
    int*    perm   = cursor + NN;
    float*  SDT    = (float*)(perm + EE);
    unsigned short* wbase = (unsigned short*)(SDT + 131072);
    unsigned short* gw1b = wbase;
    unsigned short* gw2b = wbase + 16384;
    unsigned short* ipwb = wbase + 32768;
    unsigned short* wdtb = wbase + 65536;
    unsigned short* xpwb = wbase + 81920;
    unsigned short* opwb = wbase + 86016;
    unsigned short* mw1b = wbase + 102400;
    unsigned short* mw2b = wbase + 135168;

    float* Qbuf = scr4;
    float* Hin  = scr4 + 2 * M1;
    float* p3   = scr4;

    // weight conversion + Wdt + zero cnt/stats in ONE kernel
    wprep_kernel<<<dim3(171), 256, 0, stream>>>(gw1, gw2, ipw, xpw, opw, mw1, mw2,
                                                dtw, wbase, cnt, stats);
    xb_kernel<<<dim3(NN * CC / 8 / 256), 256, 0, stream>>>(x, xb);

    // CSR build + gather
    hist_kernel<<<dim3(EE / 256), 256, 0, stream>>>(ei, cnt);
    scan32k_kernel<<<dim3(1), 1024, 0, stream>>>(cnt, baseA, cursor);
    permute_kernel<<<dim3(EE / 256), 256, 0, stream>>>(ei, cursor, perm);
    gather_kernel<<<dim3(NN / 8), 256, 0, stream>>>(perm, baseA, xb, eps, hgin);

    // GIN MLP fused
    fused2<128><<<dim3(512), 256, 0, stream>>>(
        hgin, gw1b, gb1, gw2b, gb2, xb, p1, stats + 0, stats + 128);

    // Mamba front: in_proj + conv + dt + BC + scan-phase-A (one kernel)
    mamba_front<<<dim3(NN / 32), 256, 0, stream>>>(
        xb, ipwb, cw, cb, wdtb, dtb, xpwb, Alog, xsb, zb, dtb_buf, BC, Qbuf, SDT);

    // scan phase B
    scan_combine_kernel<<<dim3(GG * 2048 / 256), 256, 0, stream>>>(Qbuf, SDT, Alog, Hin);

    // scan phase C + out_proj + resid + stats (one kernel) -> p2
    scan_out_kernel<<<dim3(GG * NCHUNK), 512, 0, stream>>>(
        BC, dtb_buf, xsb, zb, Alog, Dp, Hin, opwb, xb, p2, stats + 256, stats + 384);

    // norms 1,2 + combine
    norm12_kernel<<<dim3(NN * CC / 4 / 256), 256, 0, stream>>>(
        p1, p2, stats, g1, be1, g2, be2, h2o, out12b);

    // MLP fused
    fused2<256><<<dim3(512), 256, 0, stream>>>(
        out12b, mw1b, mb1, mw2b, mb2, out12b, p3, stats + 512, stats + 640);

    norm3_kernel<<<dim3(NN * CC / 4 / 256), 256, 0, stream>>>(p3, stats, g3, be3, outp);
}

// Round 11
// 248.716 us; speedup vs baseline: 2.7654x; 1.1217x over previous
//
#include <hip/hip_runtime.h>
#include <hip/hip_bf16.h>

#define NN 32768
#define GG 128
#define LL 256
#define CC 128
#define EE 524288
#define NCHUNK 8
#define TCH 32

typedef __attribute__((ext_vector_type(8))) short short8v;
typedef __attribute__((ext_vector_type(4))) short short4v;
typedef __attribute__((ext_vector_type(4))) float floatx4;

__device__ inline short f2bf(float f) {
    __hip_bfloat16 h = __float2bfloat16(f);
    short s; __builtin_memcpy(&s, &h, 2); return s;
}
__device__ inline float b2f(unsigned short u) {
    unsigned v = ((unsigned)u) << 16; float f; __builtin_memcpy(&f, &v, 4); return f;
}
__device__ inline floatx4 mfma16(short8v a, short8v b, floatx4 c) {
    return __builtin_amdgcn_mfma_f32_16x16x32_bf16(a, b, c, 0, 0, 0);
}
__device__ inline float softplus_f(float v) {
    return (v > 20.f) ? v : __logf(1.f + __expf(v));
}

// ================================================================ A: weight prep + x->bf16 + zeroing
__global__ __launch_bounds__(256)
void prep_kernel(const float* __restrict__ x,
                 const float* __restrict__ gw1, const float* __restrict__ gw2,
                 const float* __restrict__ ipw, const float* __restrict__ xpw,
                 const float* __restrict__ opw, const float* __restrict__ mw1,
                 const float* __restrict__ mw2, const float* __restrict__ dtw,
                 unsigned short* __restrict__ wb, int* __restrict__ cnt,
                 float* __restrict__ stats, unsigned short* __restrict__ xb)
{
    int b = blockIdx.x, tid = threadIdx.x;
    if (b < 74) {
        const float* src; int dstoff, lb;
        if (b < 8)       { src = gw1;        dstoff = 0;      lb = b; }
        else if (b < 16) { src = gw2;        dstoff = 16384;  lb = b - 8; }
        else if (b < 32) { src = ipw;        dstoff = 32768;  lb = b - 16; }
        else if (b < 34) { src = xpw + 1024; dstoff = 81920;  lb = b - 32; }
        else if (b < 42) { src = opw;        dstoff = 86016;  lb = b - 34; }
        else if (b < 58) { src = mw1;        dstoff = 102400; lb = b - 42; }
        else             { src = mw2;        dstoff = 135168; lb = b - 58; }
        size_t i = (size_t)lb * 2048 + tid * 8;
        float4 a = *(const float4*)(src + i);
        float4 c = *(const float4*)(src + i + 4);
        short8v s = { f2bf(a.x), f2bf(a.y), f2bf(a.z), f2bf(a.w),
                      f2bf(c.x), f2bf(c.y), f2bf(c.z), f2bf(c.w) };
        *(short8v*)(wb + dstoff + i) = s;
    } else if (b < 138) {
        int i = (b - 74) * 256 + tid;
        int d = i >> 7, c = i & 127;
        float s = 0.f;
#pragma unroll
        for (int r = 0; r < 8; r++) s = fmaf(dtw[d * 8 + r], xpw[r * 128 + c], s);
        wb[65536 + i] = (unsigned short)f2bf(s);
    } else if (b < 170) {
        int idx = (b - 138) * 1024 + tid * 4;
        *(int4*)(cnt + idx) = make_int4(0, 0, 0, 0);
    } else if (b == 170) {
        stats[tid] = 0.f; stats[256 + tid] = 0.f; stats[512 + tid] = 0.f;
    } else {
        size_t i = (size_t)(b - 171) * 256 + tid;
        float4 a = *(const float4*)(x + i * 8);
        float4 c = *(const float4*)(x + i * 8 + 4);
        short8v s = { f2bf(a.x), f2bf(a.y), f2bf(a.z), f2bf(a.w),
                      f2bf(c.x), f2bf(c.y), f2bf(c.z), f2bf(c.w) };
        *(short8v*)(xb + i * 8) = s;
    }
}

// ================================================================ B: mamba_front (blocks 0-1023) || hist (1024+)
__global__ __launch_bounds__(256)
void front_hist_kernel(const unsigned short* __restrict__ xb,
                 const unsigned short* __restrict__ ipwb,
                 const float* __restrict__ cw, const float* __restrict__ cb,
                 const unsigned short* __restrict__ wdtb, const float* __restrict__ dtbv,
                 const unsigned short* __restrict__ xpwb,
                 const float* __restrict__ Alog,
                 unsigned short* __restrict__ xsb, unsigned short* __restrict__ zb,
                 unsigned short* __restrict__ dtout, float* __restrict__ BCout,
                 float* __restrict__ Q, float* __restrict__ SDT,
                 const int* __restrict__ ei, int* __restrict__ cnt)
{
    __shared__ __align__(16) unsigned char smem[48 * 136 * 2 + 32 * 136 * 2 + TCH * 16 * 4];
    const int tid = threadIdx.x;
    if (blockIdx.x >= 1024) {   // ---- hist branch ----
        int e = (blockIdx.x - 1024) * 256 + tid;
        atomicAdd(&cnt[ei[EE + e]], 1);
        return;
    }
    unsigned short* xsL = (unsigned short*)smem;              // 48*136
    unsigned short* xcL = xsL + 48 * 136;                     // 32*136
    float* BsL = (float*)(xcL + 32 * 136);                    // TCH*16
    const int lane = tid & 63;
    const int wv = tid >> 6;
    const int rql = lane & 15;
    const int kseg = (lane >> 4) * 8;
    const int rsub = (lane >> 4) * 4;
    const int fb = blockIdx.x;
    const int R0 = fb * 32;
    const int RB = R0 - 16;
    const int g = fb >> 3;
    const int chunk = fb & 7;

    // ---- phase 1: in_proj, 48 rows x 64 cols/wave ----
    int coln[4];
#pragma unroll
    for (int n = 0; n < 4; n++) coln[n] = wv * 64 + n * 16 + rql;
    short8v wr[4][4];
#pragma unroll
    for (int n = 0; n < 4; n++) {
        const unsigned short* wp = ipwb + (size_t)coln[n] * 128 + kseg;
#pragma unroll
        for (int kk = 0; kk < 4; kk++) wr[n][kk] = *(const short8v*)(wp + kk * 32);
    }
    int arow[3];
#pragma unroll
    for (int m = 0; m < 3; m++) {
        int r = RB + m * 16 + rql;
        arow[m] = r < 0 ? 0 : r;
    }
    floatx4 acc[3][4];
#pragma unroll
    for (int m = 0; m < 3; m++)
#pragma unroll
        for (int n = 0; n < 4; n++)
#pragma unroll
            for (int r = 0; r < 4; r++) acc[m][n][r] = 0.f;
#pragma unroll
    for (int kb = 0; kb < 4; kb += 2) {
        short8v a2[3][2];
#pragma unroll
        for (int m = 0; m < 3; m++)
#pragma unroll
            for (int j = 0; j < 2; j++)
                a2[m][j] = *(const short8v*)(xb + (size_t)arow[m] * 128 + kseg + (kb + j) * 32);
        __builtin_amdgcn_sched_barrier(0);
#pragma unroll
        for (int j = 0; j < 2; j++)
#pragma unroll
            for (int m = 0; m < 3; m++)
#pragma unroll
                for (int n = 0; n < 4; n++)
                    acc[m][n] = mfma16(a2[m][j], wr[n][kb + j], acc[m][n]);
    }
    if (wv < 2) {
#pragma unroll
        for (int m = 0; m < 3; m++)
#pragma unroll
            for (int r = 0; r < 4; r++) {
                int row_l = m * 16 + rsub + r;
#pragma unroll
                for (int n = 0; n < 4; n++)
                    xsL[row_l * 136 + coln[n]] = (unsigned short)f2bf(acc[m][n][r]);
            }
    } else {
#pragma unroll
        for (int m = 1; m < 3; m++)
#pragma unroll
            for (int r = 0; r < 4; r++) {
                int row_g = RB + m * 16 + rsub + r;
#pragma unroll
                for (int n = 0; n < 4; n++)
                    zb[(size_t)row_g * 128 + (coln[n] - 128)] = (unsigned short)f2bf(acc[m][n][r]);
            }
    }
    __syncthreads();

    // ---- phase 2: depthwise causal conv + silu ----
    {
        int r = tid >> 3;
        int c0 = (tid & 7) * 16;
        int l = (R0 + r) & (LL - 1);
        const unsigned short* basep = &xsL[(16 + r) * 136 + c0];
        unsigned short o16[16];
#pragma unroll
        for (int half = 0; half < 2; half++) {
            short8v x0 = *(const short8v*)(basep + half * 8);
            short8v x1 = *(const short8v*)(basep - 136 + half * 8);
            short8v x2 = *(const short8v*)(basep - 272 + half * 8);
            short8v x3 = *(const short8v*)(basep - 408 + half * 8);
#pragma unroll
            for (int j = 0; j < 8; j++) {
                int c = c0 + half * 8 + j;
                float4 w = *(const float4*)(cw + c * 4);
                float v = cb[c];
                v = fmaf(b2f((unsigned short)x0[j]), w.w, v);
                if (l >= 1) v = fmaf(b2f((unsigned short)x1[j]), w.z, v);
                if (l >= 2) v = fmaf(b2f((unsigned short)x2[j]), w.y, v);
                if (l >= 3) v = fmaf(b2f((unsigned short)x3[j]), w.x, v);
                v = v / (1.f + __expf(-v));
                o16[half * 8 + j] = (unsigned short)f2bf(v);
            }
        }
#pragma unroll
        for (int half = 0; half < 2; half++) {
            short8v s;
#pragma unroll
            for (int j = 0; j < 8; j++) s[j] = (short)o16[half * 8 + j];
            *(short8v*)&xcL[r * 136 + c0 + half * 8] = s;
            *(short8v*)(xsb + (size_t)(R0 + r) * 128 + c0 + half * 8) = s;
        }
    }
    __syncthreads();   // xsL dead -> reuse as dtL

    // ---- phase 3: dt (all waves) + BC (waves 0,1) ----
    unsigned short* dtL = xsL;
    int cold0 = wv * 32 + rql, cold1 = cold0 + 16;
    short8v wd0[4], wd1[4];
    {
        const unsigned short* wp0 = wdtb + (size_t)cold0 * 128 + kseg;
        const unsigned short* wp1 = wdtb + (size_t)cold1 * 128 + kseg;
#pragma unroll
        for (int kk = 0; kk < 4; kk++) {
            wd0[kk] = *(const short8v*)(wp0 + kk * 32);
            wd1[kk] = *(const short8v*)(wp1 + kk * 32);
        }
    }
    float bd0 = dtbv[cold0], bd1 = dtbv[cold1];
    int colb = wv * 16 + rql;
    short8v wbc[4];
    if (wv < 2) {
        const unsigned short* wp = xpwb + (size_t)colb * 128 + kseg;
#pragma unroll
        for (int kk = 0; kk < 4; kk++) wbc[kk] = *(const short8v*)(wp + kk * 32);
    }
    short8v a0[4], a1[4];
#pragma unroll
    for (int kk = 0; kk < 4; kk++) {
        a0[kk] = *(const short8v*)&xcL[rql * 136 + kseg + kk * 32];
        a1[kk] = *(const short8v*)&xcL[(16 + rql) * 136 + kseg + kk * 32];
    }
    floatx4 accd[2][2], accb[2];
#pragma unroll
    for (int m = 0; m < 2; m++) {
#pragma unroll
        for (int n = 0; n < 2; n++)
#pragma unroll
            for (int r = 0; r < 4; r++) accd[m][n][r] = 0.f;
#pragma unroll
        for (int r = 0; r < 4; r++) accb[m][r] = 0.f;
    }
#pragma unroll
    for (int kk = 0; kk < 4; kk++) {
        accd[0][0] = mfma16(a0[kk], wd0[kk], accd[0][0]);
        accd[0][1] = mfma16(a0[kk], wd1[kk], accd[0][1]);
        accd[1][0] = mfma16(a1[kk], wd0[kk], accd[1][0]);
        accd[1][1] = mfma16(a1[kk], wd1[kk], accd[1][1]);
        if (wv < 2) {
            accb[0] = mfma16(a0[kk], wbc[kk], accb[0]);
            accb[1] = mfma16(a1[kk], wbc[kk], accb[1]);
        }
    }
#pragma unroll
    for (int m = 0; m < 2; m++) {
#pragma unroll
        for (int r = 0; r < 4; r++) {
            int tl = m * 16 + rsub + r;
            int row_g = R0 + tl;
            float v0 = softplus_f(accd[m][0][r] + bd0);
            float v1 = softplus_f(accd[m][1][r] + bd1);
            unsigned short u0 = (unsigned short)f2bf(v0);
            unsigned short u1 = (unsigned short)f2bf(v1);
            dtout[(size_t)row_g * 128 + cold0] = u0;
            dtout[(size_t)row_g * 128 + cold1] = u1;
            dtL[tl * 136 + cold0] = u0;
            dtL[tl * 136 + cold1] = u1;
            if (wv < 2) {
                BCout[(size_t)row_g * 32 + colb] = accb[m][r];
                if (wv == 0) BsL[tl * 16 + colb] = accb[m][r];
            }
        }
    }
    __syncthreads();

    // ---- phase 4: per-chunk backward recurrence -> (Q, SDT) ----
    for (int u = tid; u < 512; u += 256) {
        int c = u >> 2, sp = u & 3;
        float ae0 = -__expf(Alog[c * 16 + sp * 4 + 0]);
        float ae1 = -__expf(Alog[c * 16 + sp * 4 + 1]);
        float ae2 = -__expf(Alog[c * 16 + sp * 4 + 2]);
        float ae3 = -__expf(Alog[c * 16 + sp * 4 + 3]);
        float q0 = 0, q1 = 0, q2 = 0, q3 = 0, sdt = 0;
        for (int t = TCH - 1; t >= 0; --t) {
            float dtv = b2f(dtL[t * 136 + c]);
            float xv  = b2f(xcL[t * 136 + c]);
            float uu = dtv * xv;
            const float* bs = &BsL[t * 16 + sp * 4];
            q0 = fmaf(__expf(ae0 * sdt) * uu, bs[0], q0);
            q1 = fmaf(__expf(ae1 * sdt) * uu, bs[1], q1);
            q2 = fmaf(__expf(ae2 * sdt) * uu, bs[2], q2);
            q3 = fmaf(__expf(ae3 * sdt) * uu, bs[3], q3);
            sdt += dtv;
        }
        float4* qp = (float4*)(Q + (((size_t)g * NCHUNK + chunk) * CC + c) * 16 + sp * 4);
        *qp = make_float4(q0, q1, q2, q3);
        if (sp == 0) SDT[((size_t)g * NCHUNK + chunk) * CC + c] = sdt;
    }
}

// ================================================================ C: scan32k (block 0) || combine (blocks 1-256)
__global__ __launch_bounds__(1024)
void scanB_kernel(const int* __restrict__ cnt, int* __restrict__ base,
                  int* __restrict__ cursor,
                  const float* __restrict__ Q, const float* __restrict__ SDT,
                  const float* __restrict__ Alog, float* __restrict__ Hin)
{
    int tid = threadIdx.x;
    if (blockIdx.x == 0) {
        __shared__ int part[1024];
        int local[32];
        int s = 0;
#pragma unroll
        for (int j = 0; j < 32; j++) { local[j] = cnt[tid * 32 + j]; s += local[j]; }
        part[tid] = s;
        __syncthreads();
        for (int off = 1; off < 1024; off <<= 1) {
            int v = (tid >= off) ? part[tid - off] : 0;
            __syncthreads();
            part[tid] += v;
            __syncthreads();
        }
        int run = part[tid] - s;
#pragma unroll
        for (int j = 0; j < 32; j++) {
            base[tid * 32 + j] = run;
            cursor[tid * 32 + j] = run;
            run += local[j];
        }
        if (tid == 0) base[NN] = EE;
        return;
    }
    int idx = (blockIdx.x - 1) * 1024 + tid;   // g*2048 + c*16 + s
    int g = idx >> 11;
    int cs = idx & 2047;
    float ae = -__expf(Alog[cs]);
    float h = 0.f;
#pragma unroll
    for (int k = 0; k < NCHUNK; k++) {
        size_t o = ((size_t)g * NCHUNK + k);
        Hin[o * 2048 + cs] = h;
        float sdt = SDT[o * CC + (cs >> 4)];
        h = fmaf(__expf(ae * sdt), h, Q[o * 2048 + cs]);
    }
}

// ================================================================ D: permute
__global__ __launch_bounds__(256) void permute_kernel(const int* __restrict__ ei,
    int* __restrict__ cursor, int* __restrict__ perm)
{
    int e = blockIdx.x * 256 + threadIdx.x;
    int dst = ei[EE + e];
    int pos = atomicAdd(&cursor[dst], 1);
    perm[pos] = ei[e];
}

// ================================================================ E: scan_out (blocks 0-1023) || gather (1024+)
__global__ __launch_bounds__(512)
void scanout_gather_kernel(const float* __restrict__ BCp,
    const unsigned short* __restrict__ dtp, const unsigned short* __restrict__ xsp_,
    const unsigned short* __restrict__ zb, const float* __restrict__ Alog,
    const float* __restrict__ Dp, const float* __restrict__ Hin,
    const unsigned short* __restrict__ opwb, const unsigned short* __restrict__ xb,
    float* __restrict__ p2, float* ssum, float* ssq,
    const int* __restrict__ perm, const int* __restrict__ base,
    const float* __restrict__ epsp, unsigned short* __restrict__ hgin)
{
    __shared__ __align__(16) unsigned char smem[31232];
    const int tid = threadIdx.x;
    if (blockIdx.x >= 1024) {   // ---- gather branch (16 nodes/block) ----
        int node = (blockIdx.x - 1024) * 16 + (tid >> 5);
        int c4 = tid & 31;
        int b0 = base[node], b1 = base[node + 1];
        float s0 = 0, s1 = 0, s2 = 0, s3 = 0;
        float t0 = 0, t1 = 0, t2 = 0, t3 = 0;
        int i = b0;
        for (; i + 1 < b1; i += 2) {
            short4v v0 = *(const short4v*)(xb + (size_t)perm[i] * CC + c4 * 4);
            short4v v1 = *(const short4v*)(xb + (size_t)perm[i + 1] * CC + c4 * 4);
            s0 += b2f((unsigned short)v0[0]); s1 += b2f((unsigned short)v0[1]);
            s2 += b2f((unsigned short)v0[2]); s3 += b2f((unsigned short)v0[3]);
            t0 += b2f((unsigned short)v1[0]); t1 += b2f((unsigned short)v1[1]);
            t2 += b2f((unsigned short)v1[2]); t3 += b2f((unsigned short)v1[3]);
        }
        if (i < b1) {
            short4v v0 = *(const short4v*)(xb + (size_t)perm[i] * CC + c4 * 4);
            s0 += b2f((unsigned short)v0[0]); s1 += b2f((unsigned short)v0[1]);
            s2 += b2f((unsigned short)v0[2]); s3 += b2f((unsigned short)v0[3]);
        }
        float e1 = 1.f + epsp[0];
        short4v xv = *(const short4v*)(xb + (size_t)node * CC + c4 * 4);
        float r0 = fmaf(e1, b2f((unsigned short)xv[0]), s0 + t0);
        float r1 = fmaf(e1, b2f((unsigned short)xv[1]), s1 + t1);
        float r2 = fmaf(e1, b2f((unsigned short)xv[2]), s2 + t2);
        float r3 = fmaf(e1, b2f((unsigned short)xv[3]), s3 + t3);
        short4v o = { f2bf(r0), f2bf(r1), f2bf(r2), f2bf(r3) };
        *(short4v*)(hgin + (size_t)node * CC + c4 * 4) = o;
        return;
    }
    // ---- scan phase C + out_proj branch ----
    float* BCs = (float*)smem;                                    // 1024 fl
    unsigned short* dts = (unsigned short*)(smem + 4096);         // 32*136
    unsigned short* xss = (unsigned short*)(smem + 12800);        // 32*136
    unsigned short* yL  = (unsigned short*)(smem + 21504);        // 32*136
    float* sred = (float*)(smem + 30208);                         // 256 fl
    const int b = blockIdx.x;
    const int g = b >> 3, chunk = b & 7;
    const int t0 = chunk * TCH;
    if (tid < 256) sred[tid] = 0.f;
    for (int i4 = tid; i4 < TCH * 8; i4 += 512) {
        int t = i4 >> 3, j4 = i4 & 7;
        *(float4*)&BCs[t * 32 + j4 * 4] =
            *(const float4*)(BCp + (size_t)(g * LL + t0 + t) * 32 + j4 * 4);
    }
    {
        int t = tid >> 4, c8 = tid & 15;
        size_t off = (size_t)(g * LL + t0 + t) * CC + c8 * 8;
        *(short8v*)&dts[t * 136 + c8 * 8] = *(const short8v*)(dtp + off);
        *(short8v*)&xss[t * 136 + c8 * 8] = *(const short8v*)(xsp_ + off);
    }
    const int c = tid >> 2, sp = tid & 3;
    float ae0 = -__expf(Alog[c * 16 + sp * 4 + 0]);
    float ae1 = -__expf(Alog[c * 16 + sp * 4 + 1]);
    float ae2 = -__expf(Alog[c * 16 + sp * 4 + 2]);
    float ae3 = -__expf(Alog[c * 16 + sp * 4 + 3]);
    float dpc = Dp[c];
    float4 hv = *(const float4*)(Hin + ((size_t)g * NCHUNK + chunk) * 2048 + c * 16 + sp * 4);
    float h0 = hv.x, h1 = hv.y, h2 = hv.z, h3 = hv.w;
    __syncthreads();
    const unsigned short* zg = zb + (size_t)(g * LL + t0) * CC + c;
    for (int t = 0; t < TCH; t++) {
        float dtv = b2f(dts[t * 136 + c]);
        float xv  = b2f(xss[t * 136 + c]);
        float u = dtv * xv;
        const float* bc = &BCs[t * 32 + sp * 4];
        h0 = fmaf(__expf(dtv * ae0), h0, u * bc[0]);
        h1 = fmaf(__expf(dtv * ae1), h1, u * bc[1]);
        h2 = fmaf(__expf(dtv * ae2), h2, u * bc[2]);
        h3 = fmaf(__expf(dtv * ae3), h3, u * bc[3]);
        float y = h0 * bc[16] + h1 * bc[17] + h2 * bc[18] + h3 * bc[19];
        y += __shfl_xor(y, 1);
        y += __shfl_xor(y, 2);
        if (sp == 0) {
            float zv = b2f(zg[t * CC]);
            float yo = fmaf(dpc, xv, y);
            yL[t * 136 + c] = (unsigned short)f2bf(yo * (zv / (1.f + __expf(-zv))));
        }
    }
    __syncthreads();

    // ---- out_proj: 8 waves x 16 cols ----
    const int lane = tid & 63;
    const int wv = tid >> 6;
    const int rql = lane & 15;
    const int kseg = (lane >> 4) * 8;
    const int rsub = (lane >> 4) * 4;
    const int colg = wv * 16 + rql;
    short8v w[4];
    {
        const unsigned short* wp = opwb + (size_t)colg * 128 + kseg;
#pragma unroll
        for (int kk = 0; kk < 4; kk++) w[kk] = *(const short8v*)(wp + kk * 32);
    }
    floatx4 acc[2];
#pragma unroll
    for (int m = 0; m < 2; m++)
#pragma unroll
        for (int r = 0; r < 4; r++) acc[m][r] = 0.f;
#pragma unroll
    for (int kk = 0; kk < 4; kk++) {
        short8v alo = *(const short8v*)&yL[rql * 136 + kseg + kk * 32];
        short8v ahi = *(const short8v*)&yL[(16 + rql) * 136 + kseg + kk * 32];
        acc[0] = mfma16(alo, w[kk], acc[0]);
        acc[1] = mfma16(ahi, w[kk], acc[1]);
    }
    float sumr = 0.f, sqr = 0.f;
#pragma unroll
    for (int m = 0; m < 2; m++) {
#pragma unroll
        for (int r = 0; r < 4; r++) {
            int row_g = g * LL + t0 + m * 16 + rsub + r;
            float v = acc[m][r] + b2f(xb[(size_t)row_g * CC + colg]);
            p2[(size_t)row_g * CC + colg] = v;
            sumr += v; sqr += v * v;
        }
    }
    sumr += __shfl_xor(sumr, 16); sumr += __shfl_xor(sumr, 32);
    sqr  += __shfl_xor(sqr, 16);  sqr  += __shfl_xor(sqr, 32);
    if ((lane >> 4) == 0) {
        atomicAdd(&sred[colg], sumr);
        atomicAdd(&sred[128 + colg], sqr);
    }
    __syncthreads();
    if (tid < 128) {
        atomicAdd(&ssum[tid], sred[tid]);
        atomicAdd(&ssq[tid], sred[128 + tid]);
    }
}

// ================================================================ fused 2-layer GEMM (LDS handoff)
template<int KMID>
__global__ __launch_bounds__(256)
void fused2(const unsigned short* __restrict__ A,
            const unsigned short* __restrict__ W1b, const float* __restrict__ b1,
            const unsigned short* __restrict__ W2b, const float* __restrict__ b2,
            const unsigned short* __restrict__ residb,
            float* __restrict__ outp,
            float* ssum, float* ssq)
{
    constexpr int NF1 = KMID / 64;
    constexpr int NK1 = 4;
    constexpr int NK2 = KMID / 32;
    constexpr int LDSW = KMID + 8;
    __shared__ unsigned short lds[2][32 * LDSW];
    __shared__ float sred[256];
    const int tid = threadIdx.x;
    const int lane = tid & 63;
    const int wc = tid >> 6;
    const int rql = lane & 15;
    const int kseg = (lane >> 4) * 8;
    const int rsub = (lane >> 4) * 4;

    sred[tid] = 0.f;

    short8v w1r[NF1][NK1];
    int colg1[NF1];
    float b1c[NF1];
#pragma unroll
    for (int f = 0; f < NF1; f++) {
        colg1[f] = wc * (16 * NF1) + f * 16 + rql;
        const unsigned short* wp = W1b + (size_t)colg1[f] * 128 + kseg;
#pragma unroll
        for (int kk = 0; kk < NK1; kk++) w1r[f][kk] = *(const short8v*)(wp + kk * 32);
        b1c[f] = b1[colg1[f]];
    }
    int colg2[2];
    colg2[0] = wc * 32 + rql;
    colg2[1] = colg2[0] + 16;
    float b2c[2] = { b2[colg2[0]], b2[colg2[1]] };
    float ssumr[2] = {0.f, 0.f}, ssqr[2] = {0.f, 0.f};

    short8v abuf[2][NK1][2];
    {
        const unsigned short* ap = A + (size_t)(blockIdx.x * 32 + rql) * 128 + kseg;
#pragma unroll
        for (int kk = 0; kk < NK1; kk++) {
            abuf[0][kk][0] = *(const short8v*)(ap + kk * 32);
            abuf[0][kk][1] = *(const short8v*)(ap + 16 * 128 + kk * 32);
        }
    }
    __syncthreads();

#pragma unroll
    for (int t = 0; t < 2; t++) {
        const int R0 = (blockIdx.x + t * 512) * 32;
        floatx4 acc1[2][NF1];
#pragma unroll
        for (int m = 0; m < 2; m++)
#pragma unroll
            for (int f = 0; f < NF1; f++)
#pragma unroll
                for (int r = 0; r < 4; r++) acc1[m][f][r] = 0.f;
#pragma unroll
        for (int kk = 0; kk < NK1; kk++)
#pragma unroll
            for (int m = 0; m < 2; m++)
#pragma unroll
                for (int f = 0; f < NF1; f++)
                    acc1[m][f] = mfma16(abuf[t][kk][m], w1r[f][kk], acc1[m][f]);
        unsigned short* L = &lds[t][0];
#pragma unroll
        for (int m = 0; m < 2; m++)
#pragma unroll
            for (int f = 0; f < NF1; f++)
#pragma unroll
                for (int r = 0; r < 4; r++) {
                    float v = fmaxf(acc1[m][f][r] + b1c[f], 0.f);
                    L[(m * 16 + rsub + r) * LDSW + colg1[f]] = (unsigned short)f2bf(v);
                }
        __syncthreads();
        if (t == 0) {
            const unsigned short* ap = A + (size_t)((blockIdx.x + 512) * 32 + rql) * 128 + kseg;
#pragma unroll
            for (int kk = 0; kk < NK1; kk++) {
                abuf[1][kk][0] = *(const short8v*)(ap + kk * 32);
                abuf[1][kk][1] = *(const short8v*)(ap + 16 * 128 + kk * 32);
            }
        }
        short8v w2a[NK2], w2b[NK2];
        {
            const unsigned short* wq0 = W2b + (size_t)colg2[0] * KMID + kseg;
            const unsigned short* wq1 = W2b + (size_t)colg2[1] * KMID + kseg;
#pragma unroll
            for (int kk = 0; kk < NK2; kk++) {
                w2a[kk] = *(const short8v*)(wq0 + kk * 32);
                w2b[kk] = *(const short8v*)(wq1 + kk * 32);
            }
        }
        floatx4 acc2[2][2];
#pragma unroll
        for (int m = 0; m < 2; m++)
#pragma unroll
            for (int n = 0; n < 2; n++)
#pragma unroll
                for (int r = 0; r < 4; r++) acc2[m][n][r] = 0.f;
#pragma unroll
        for (int kk = 0; kk < NK2; kk++) {
            short8v a2lo = *(const short8v*)&L[rql * LDSW + kseg + kk * 32];
            short8v a2hi = *(const short8v*)&L[(rql + 16) * LDSW + kseg + kk * 32];
            acc2[0][0] = mfma16(a2lo, w2a[kk], acc2[0][0]);
            acc2[0][1] = mfma16(a2lo, w2b[kk], acc2[0][1]);
            acc2[1][0] = mfma16(a2hi, w2a[kk], acc2[1][0]);
            acc2[1][1] = mfma16(a2hi, w2b[kk], acc2[1][1]);
        }
#pragma unroll
        for (int m = 0; m < 2; m++) {
#pragma unroll
            for (int r = 0; r < 4; r++) {
                int row_g = R0 + m * 16 + rsub + r;
#pragma unroll
                for (int n = 0; n < 2; n++) {
                    float v = acc2[m][n][r] + b2c[n];
                    v += b2f(residb[(size_t)row_g * CC + colg2[n]]);
                    outp[(size_t)row_g * CC + colg2[n]] = v;
                    ssumr[n] += v; ssqr[n] += v * v;
                }
            }
        }
    }
    __syncthreads();
#pragma unroll
    for (int n = 0; n < 2; n++) {
        atomicAdd(&sred[colg2[n]], ssumr[n]);
        atomicAdd(&sred[128 + colg2[n]], ssqr[n]);
    }
    __syncthreads();
    if (tid < 128) {
        atomicAdd(&ssum[tid], sred[tid]);
        atomicAdd(&ssq[tid], sred[128 + tid]);
    }
}

// ================================================================ norms
__global__ __launch_bounds__(256) void norm12_kernel(const float* __restrict__ p1,
    const float* __restrict__ p2, const float* __restrict__ stats,
    const float* g1, const float* be1, const float* g2, const float* be2,
    float* __restrict__ h2out, unsigned short* __restrict__ out12b)
{
    __shared__ float sc[512];
    int tid = threadIdx.x;
    if (tid < 128) {
        int c = tid;
        const float inv = 1.0f / NN;
        float m1 = stats[c] * inv;
        float v1 = fmaxf(stats[128 + c] * inv - m1 * m1, 0.f);
        float i1 = rsqrtf(v1 + 1e-5f);
        sc[c] = g1[c] * i1; sc[128 + c] = be1[c] - m1 * g1[c] * i1;
        float m2 = stats[256 + c] * inv;
        float v2 = fmaxf(stats[384 + c] * inv - m2 * m2, 0.f);
        float i2 = rsqrtf(v2 + 1e-5f);
        sc[256 + c] = g2[c] * i2; sc[384 + c] = be2[c] - m2 * g2[c] * i2;
    }
    __syncthreads();
    size_t idx = (size_t)blockIdx.x * 256 + tid;
    int c4 = (int)(idx & 31);
    float4 s1 = *(float4*)&sc[c4 * 4];
    float4 t1 = *(float4*)&sc[128 + c4 * 4];
    float4 s2 = *(float4*)&sc[256 + c4 * 4];
    float4 t2 = *(float4*)&sc[384 + c4 * 4];
    float4 a = *(const float4*)(p1 + idx * 4);
    float4 b = *(const float4*)(p2 + idx * 4);
    float4 h, o;
    h.x = fmaf(b.x, s2.x, t2.x); o.x = fmaf(a.x, s1.x, t1.x) + h.x;
    h.y = fmaf(b.y, s2.y, t2.y); o.y = fmaf(a.y, s1.y, t1.y) + h.y;
    h.z = fmaf(b.z, s2.z, t2.z); o.z = fmaf(a.z, s1.z, t1.z) + h.z;
    h.w = fmaf(b.w, s2.w, t2.w); o.w = fmaf(a.w, s1.w, t1.w) + h.w;
    *(float4*)(h2out + idx * 4) = h;
    short4v ob = { f2bf(o.x), f2bf(o.y), f2bf(o.z), f2bf(o.w) };
    *(short4v*)(out12b + idx * 4) = ob;
}

__global__ __launch_bounds__(256) void norm3_kernel(const float* __restrict__ p3,
    const float* __restrict__ stats, const float* g3, const float* be3,
    float* __restrict__ outp)
{
    __shared__ float sc[256];
    int tid = threadIdx.x;
    if (tid < 128) {
        int c = tid;
        const float inv = 1.0f / NN;
        float m = stats[512 + c] * inv;
        float v = fmaxf(stats[640 + c] * inv - m * m, 0.f);
        float iv = rsqrtf(v + 1e-5f);
        sc[c] = g3[c] * iv; sc[128 + c] = be3[c] - m * g3[c] * iv;
    }
    __syncthreads();
    size_t idx = (size_t)blockIdx.x * 256 + tid;
    int c4 = (int)(idx & 31);
    float4 s = *(float4*)&sc[c4 * 4];
    float4 t = *(float4*)&sc[128 + c4 * 4];
    float4 a = *(const float4*)(p3 + idx * 4);
    float4 o;
    o.x = fmaf(a.x, s.x, t.x); o.y = fmaf(a.y, s.y, t.y);
    o.z = fmaf(a.z, s.z, t.z); o.w = fmaf(a.w, s.w, t.w);
    *(float4*)(outp + idx * 4) = o;
}

extern "C" void kernel_launch(void* const* d_in, const int* in_sizes, int n_in,
                              void* d_out, int out_size, void* d_ws, size_t ws_size,
                              hipStream_t stream)
{
    (void)in_sizes; (void)n_in; (void)out_size; (void)ws_size;
    const float* x    = (const float*)d_in[0];
    const int*   ei   = (const int*)d_in[1];
    const float* eps  = (const float*)d_in[3];
    const float* gw1  = (const float*)d_in[4];
    const float* gb1  = (const float*)d_in[5];
    const float* gw2  = (const float*)d_in[6];
    const float* gb2  = (const float*)d_in[7];
    const float* ipw  = (const float*)d_in[8];
    const float* cw   = (const float*)d_in[9];
    const float* cb   = (const float*)d_in[10];
    const float* xpw  = (const float*)d_in[11];
    const float* dtw  = (const float*)d_in[12];
    const float* dtb  = (const float*)d_in[13];
    const float* Alog = (const float*)d_in[14];
    const float* Dp   = (const float*)d_in[15];
    const float* opw  = (const float*)d_in[16];
    const float* mw1  = (const float*)d_in[17];
    const float* mb1  = (const float*)d_in[18];
    const float* mw2  = (const float*)d_in[19];
    const float* mb2  = (const float*)d_in[20];
    const float* g1   = (const float*)d_in[21];
    const float* be1  = (const float*)d_in[22];
    const float* g2   = (const float*)d_in[23];
    const float* be2  = (const float*)d_in[24];
    const float* g3   = (const float*)d_in[25];
    const float* be3  = (const float*)d_in[26];

    float* outp = (float*)d_out;
    float* h2o  = outp + (size_t)NN * CC;
    float* p1 = outp;
    float* p2 = h2o;

    const size_t M1 = 1u << 20;
    float* ws = (float*)d_ws;
    float*  scr4   = ws;                                  // Q(2M)+Hin(2M), later p3
    float*  BC     = ws + 4 * M1;                         // 1M fl
    unsigned short* zb      = (unsigned short*)(ws + 7 * M1);
    unsigned short* dtb_buf = (unsigned short*)(ws + 9 * M1);
    unsigned short* xb      = (unsigned short*)(ws + 11 * M1);
    unsigned short* hgin    = (unsigned short*)(ws + 13 * M1);
    unsigned short* xsb     = (unsigned short*)(ws + 15 * M1);
    unsigned short* out12b  = (unsigned short*)(ws + 17 * M1);
    float*  stats  = ws + 19 * M1;
    int*    cnt    = (int*)(stats + 768);
    int*    baseA  = cnt + NN;
    int*    cursor = baseA + NN + 1;
    int*    perm   = cursor + NN;
    float*  SDT    = (float*)(perm + EE);
    unsigned short* wbase = (unsigned short*)(SDT + 131072);
    unsigned short* gw1b = wbase;
    unsigned short* gw2b = wbase + 16384;
    unsigned short* ipwb = wbase + 32768;
    unsigned short* wdtb = wbase + 65536;
    unsigned short* xpwb = wbase + 81920;
    unsigned short* opwb = wbase + 86016;
    unsigned short* mw1b = wbase + 102400;
    unsigned short* mw2b = wbase + 135168;

    float* Qbuf = scr4;
    float* Hin  = scr4 + 2 * M1;
    float* p3   = scr4;

    // A: weights + x->bf16 + zero cnt/stats
    prep_kernel<<<dim3(171 + 2048), 256, 0, stream>>>(
        x, gw1, gw2, ipw, xpw, opw, mw1, mw2, dtw, wbase, cnt, stats, xb);

    // B: mamba_front (0-1023) || hist (1024-3071)
    front_hist_kernel<<<dim3(3072), 256, 0, stream>>>(
        xb, ipwb, cw, cb, wdtb, dtb, xpwb, Alog, xsb, zb, dtb_buf, BC, Qbuf, SDT,
        ei, cnt);

    // C: scan32k (block 0) || scan-combine (blocks 1-256)
    scanB_kernel<<<dim3(257), 1024, 0, stream>>>(cnt, baseA, cursor, Qbuf, SDT, Alog, Hin);

    // D: permute
    permute_kernel<<<dim3(EE / 256), 256, 0, stream>>>(ei, cursor, perm);

    // E: scan_out (0-1023) || gather (1024-3071)
    scanout_gather_kernel<<<dim3(3072), 512, 0, stream>>>(
        BC, dtb_buf, xsb, zb, Alog, Dp, Hin, opwb, xb, p2, stats + 256, stats + 384,
        perm, baseA, eps, hgin);

    // F: GIN MLP fused -> p1 (stats S1)
    fused2<128><<<dim3(512), 256, 0, stream>>>(
        hgin, gw1b, gb1, gw2b, gb2, xb, p1, stats + 0, stats + 128);

    // G: norms 1,2 + combine
    norm12_kernel<<<dim3(NN * CC / 4 / 256), 256, 0, stream>>>(
        p1, p2, stats, g1, be1, g2, be2, h2o, out12b);

    // H: MLP fused -> p3 (stats S3)
    fused2<256><<<dim3(512), 256, 0, stream>>>(
        out12b, mw1b, mb1, mw2b, mb2, out12b, p3, stats + 512, stats + 640);

    // I: final norm
    norm3_kernel<<<dim3(NN * CC / 4 / 256), 256, 0, stream>>>(p3, stats, g3, be3, outp);
}